// Round 4
// baseline (1923.719 us; speedup 1.0000x reference)
//
#include <hip/hip_runtime.h>
#include <hip/hip_fp16.h>

#define BB 8
#define C 256
#define HH 56
#define WW 56
#define NN 3136      // HH*WW
#define RR 16
#define NT (NN/16)   // 196 pixel-tiles per image
#define PW 58        // padded spatial width/height

typedef _Float16 half8 __attribute__((ext_vector_type(8)));
typedef _Float16 half4v __attribute__((ext_vector_type(4)));
typedef float floatx4 __attribute__((ext_vector_type(4)));

// ---------------------------------------------------------------------------
// 1. attr branch fused: a = adj( concat( relu(W2 relu(W1 x)), x ) )
//    R3: weight reads were 64-line gathers (wadj[o*512+k], o=lane) -> 274us at
//    VALUBusy 20%.  Now reads transposed fp32 copies (w1T[c][r], wadjT[k][o])
//    -> coalesced; fp32 math and accumulation order unchanged.
// ---------------------------------------------------------------------------
__global__ __launch_bounds__(256) void attr_kernel(
    const float* __restrict__ x,
    const float* __restrict__ w1T, const float* __restrict__ b1,
    const float* __restrict__ w2, const float* __restrict__ b2,
    const float* __restrict__ wadjT, const float* __restrict__ badj,
    float* __restrict__ a_out)
{
  __shared__ float xs[C][20];
  __shared__ float a2s[C][20];
  __shared__ float a1s[RR][20];
  const int tile = blockIdx.x;
  const int b = tile / NT;
  const int p0 = (tile % NT) * 16;
  const int t = threadIdx.x;

  {
    const float* xb = x + ((size_t)b * C + t) * NN + p0;
    const float4* xb4 = (const float4*)xb;
    float* row = xs[t];
#pragma unroll
    for (int g = 0; g < 4; ++g) {
      float4 v = xb4[g];
      row[g * 4 + 0] = v.x; row[g * 4 + 1] = v.y;
      row[g * 4 + 2] = v.z; row[g * 4 + 3] = v.w;
    }
  }
  __syncthreads();

  {
    const int r = t & 15, pp = t >> 4;
    float acc = b1[r];
    for (int c = 0; c < C; ++c) acc += w1T[c * 16 + r] * xs[c][pp];
    a1s[r][pp] = fmaxf(acc, 0.f);
  }
  __syncthreads();

  {
    const int o = t;
    float acc[16];
    const float bias = b2[o];
#pragma unroll
    for (int p = 0; p < 16; ++p) acc[p] = bias;
    const float* wr = w2 + o * RR;
    for (int k = 0; k < RR; ++k) {
      const float w = wr[k];
#pragma unroll
      for (int p = 0; p < 16; ++p) acc[p] += w * a1s[k][p];
    }
    float* row = a2s[o];
#pragma unroll
    for (int p = 0; p < 16; ++p) row[p] = fmaxf(acc[p], 0.f);
  }
  __syncthreads();

  {
    const int o = t;
    float acc[16];
    const float bias = badj[o];
#pragma unroll
    for (int p = 0; p < 16; ++p) acc[p] = bias;
    const float* wTa = wadjT + o;            // wadjT[k][o], k in [0,256)
    for (int k = 0; k < C; ++k) {
      const float w = wTa[k * C];
      const float4* ar = (const float4*)a2s[k];
#pragma unroll
      for (int g = 0; g < 4; ++g) {
        float4 v = ar[g];
        acc[g * 4 + 0] += w * v.x; acc[g * 4 + 1] += w * v.y;
        acc[g * 4 + 2] += w * v.z; acc[g * 4 + 3] += w * v.w;
      }
    }
    const float* wTx = wadjT + C * C + o;    // wadjT[256+k][o]
    for (int k = 0; k < C; ++k) {
      const float w = wTx[k * C];
      const float4* xr = (const float4*)xs[k];
#pragma unroll
      for (int g = 0; g < 4; ++g) {
        float4 v = xr[g];
        acc[g * 4 + 0] += w * v.x; acc[g * 4 + 1] += w * v.y;
        acc[g * 4 + 2] += w * v.z; acc[g * 4 + 3] += w * v.w;
      }
    }
    float* op = a_out + ((size_t)b * C + o) * NN + p0;
    float4* op4 = (float4*)op;
#pragma unroll
    for (int g = 0; g < 4; ++g)
      op4[g] = make_float4(acc[g * 4 + 0], acc[g * 4 + 1], acc[g * 4 + 2], acc[g * 4 + 3]);
  }
}

// ---------------------------------------------------------------------------
// 1b. attr weight transposes (fp32): w1T[c][r] = w1[r][c];
//     wadjT[k][o] = wadj[o][k]  (k over 2C)
// ---------------------------------------------------------------------------
__global__ __launch_bounds__(256) void wprep_attr_kernel(
    const float* __restrict__ w1, const float* __restrict__ wadj,
    float* __restrict__ w1T, float* __restrict__ wadjT)
{
  const int i = blockIdx.x * 256 + threadIdx.x;   // 528*256 = 135,168
  if (i < RR * C) {
    const int c = i >> 4, r = i & 15;
    w1T[i] = w1[r * C + c];
  } else {
    const int j = i - RR * C;                     // 2C*C entries
    const int k = j >> 8, o = j & 255;
    wadjT[j] = wadj[(size_t)o * (2 * C) + k];
  }
}

// ---------------------------------------------------------------------------
// 2a. conv weight prep: w1h[tap][o][c] = tw1[o][c][tap] (fp16)
//     w2h[tap][o][c] = tw2[o][c][8-tap]  (convT spatial flip folded in)
// ---------------------------------------------------------------------------
__global__ __launch_bounds__(256) void wprep_kernel(
    const float* __restrict__ tw1, const float* __restrict__ tw2,
    _Float16* __restrict__ w1h, _Float16* __restrict__ w2h)
{
  const int i = blockIdx.x * 256 + threadIdx.x;   // over 9*256*256
  const int tap = i >> 16;
  const int rem = i & 65535;
  const int o = rem >> 8;
  const int c = rem & 255;
  w1h[i] = (_Float16)tw1[((size_t)o * C + c) * 9 + tap];
  w2h[i] = (_Float16)tw2[((size_t)o * C + c) * 9 + (8 - tap)];
}

// ---------------------------------------------------------------------------
// 2a'. 1x1 weight prep: 7 C*C fp32 matrices -> fp16, same [o][c] layout.
//      Order: qa,ka,va, qt,kt,vt, ow
// ---------------------------------------------------------------------------
__global__ __launch_bounds__(256) void wprep_qkv_kernel(
    const float* __restrict__ m0, const float* __restrict__ m1,
    const float* __restrict__ m2, const float* __restrict__ m3,
    const float* __restrict__ m4, const float* __restrict__ m5,
    const float* __restrict__ m6, _Float16* __restrict__ Whall)
{
  const int i = blockIdx.x * 256 + threadIdx.x;   // over 7*65536
  const int mat = i >> 16, rem = i & 65535;
  const float* s;
  switch (mat) {
    case 0: s = m0; break; case 1: s = m1; break; case 2: s = m2; break;
    case 3: s = m3; break; case 4: s = m4; break; case 5: s = m5; break;
    default: s = m6; break;
  }
  Whall[i] = (_Float16)s[rem];
}

// ---------------------------------------------------------------------------
// 2b. zero the pad border of both padded-NHWC fp16 buffers
// ---------------------------------------------------------------------------
__global__ __launch_bounds__(256) void padzero_kernel(
    _Float16* __restrict__ buf1, _Float16* __restrict__ buf2)
{
  const int bid = blockIdx.x;                 // 2 * BB * PW
  _Float16* buf = (bid < BB * PW) ? buf1 : buf2;
  const int rb = bid % (BB * PW);
  const int b = rb / PW, r = rb % PW;
  _Float16* row = buf + ((size_t)b * PW + r) * PW * C;
  const float4 z = make_float4(0.f, 0.f, 0.f, 0.f);
  if (r == 0 || r == PW - 1) {
    for (int i = threadIdx.x; i < PW * C / 8; i += 256) ((float4*)row)[i] = z;
  } else {
    const int i = threadIdx.x;
    if (i < 32) ((float4*)row)[i] = z;                       // col 0
    else if (i < 64) ((float4*)(row + (PW - 1) * C))[i - 32] = z;  // col 57
  }
}

// ---------------------------------------------------------------------------
// 2c. hn (fp32 NCHW) -> hnpad (fp16 padded NHWC) interior, via LDS transpose
// ---------------------------------------------------------------------------
__global__ __launch_bounds__(256) void hnprep_kernel(
    const float* __restrict__ hn, _Float16* __restrict__ hnpad)
{
  __shared__ float xs[C][17];
  const int tile = blockIdx.x;
  const int b = tile / NT;
  const int p0 = (tile % NT) * 16;
  const int t = threadIdx.x;
  {
    const float4* sb = (const float4*)(hn + ((size_t)b * C + t) * NN + p0);
    float* row = xs[t];
#pragma unroll
    for (int g = 0; g < 4; ++g) {
      float4 v = sb[g];
      row[g * 4 + 0] = v.x; row[g * 4 + 1] = v.y;
      row[g * 4 + 2] = v.z; row[g * 4 + 3] = v.w;
    }
  }
  __syncthreads();
  const int p = t >> 4, c0 = (t & 15) * 16;
  const int pg = p0 + p;
  const int h = pg / WW, w = pg % WW;
  __align__(16) _Float16 tmp[16];
#pragma unroll
  for (int j = 0; j < 16; ++j) tmp[j] = (_Float16)xs[c0 + j][p];
  _Float16* dst = hnpad + (((size_t)b * PW + h + 1) * PW + w + 1) * C + c0;
  ((uint4*)dst)[0] = ((uint4*)tmp)[0];
  ((uint4*)dst)[1] = ((uint4*)tmp)[1];
}

// ---------------------------------------------------------------------------
// 2d. conv3x3 as 9-tap MFMA GEMM.  XCD-swizzled (b = bid & 7).
// ---------------------------------------------------------------------------
__global__ __launch_bounds__(256) void conv_mfma_kernel(
    const _Float16* __restrict__ inpad, const _Float16* __restrict__ wh,
    const float* __restrict__ bias, const float* __restrict__ amul,
    _Float16* __restrict__ out_h, float* __restrict__ out_f, int mode)
{
  const int bid = blockIdx.x;          // BB*56*2
  const int b = bid & 7;               // XCD-aligned batch
  const int rest = bid >> 3;           // 0..111
  const int ohalf = rest & 1;
  const int h = rest >> 1;
  const int t = threadIdx.x;
  const int wave = t >> 6, lane = t & 63;
  const int col = lane & 15, quad = lane >> 4;
  const int o_base = ohalf * 128 + wave * 32;

  floatx4 acc[2][4];
#pragma unroll
  for (int mt = 0; mt < 2; ++mt)
#pragma unroll
    for (int nt = 0; nt < 4; ++nt) acc[mt][nt] = (floatx4){0.f, 0.f, 0.f, 0.f};

  const _Float16* inb = inpad + (size_t)b * PW * PW * C;

  for (int tap = 0; tap < 9; ++tap) {
    const int dy = tap / 3;
    const int dx = tap - dy * 3;
    const _Float16* wtap = wh + (size_t)tap * C * C + quad * 8;
    const _Float16* inrow = inb + ((size_t)(h + dy) * PW + dx + col) * C + quad * 8;
    for (int kc = 0; kc < 8; ++kc) {
      const int c0 = kc * 32;
      const half8 A0 = *(const half8*)(wtap + (size_t)(o_base + col) * C + c0);
      const half8 A1 = *(const half8*)(wtap + (size_t)(o_base + 16 + col) * C + c0);
#pragma unroll
      for (int nt = 0; nt < 4; ++nt) {
        const half8 Bv = *(const half8*)(inrow + (size_t)(nt * 16) * C + c0);
        acc[0][nt] = __builtin_amdgcn_mfma_f32_16x16x32_f16(A0, Bv, acc[0][nt], 0, 0, 0);
        acc[1][nt] = __builtin_amdgcn_mfma_f32_16x16x32_f16(A1, Bv, acc[1][nt], 0, 0, 0);
      }
    }
  }

#pragma unroll
  for (int mt = 0; mt < 2; ++mt) {
    const int o = o_base + mt * 16 + quad * 4;
    const float* bp = bias + o;
    const float b0 = bp[0], b1_ = bp[1], b2_ = bp[2], b3 = bp[3];
    if (mode == 0) {
#pragma unroll
      for (int nt = 0; nt < 4; ++nt) {
        const int wpx = nt * 16 + col;
        if (wpx < WW) {
          __align__(8) _Float16 hv[4];
          hv[0] = (_Float16)fmaxf(acc[mt][nt][0] + b0, 0.f);
          hv[1] = (_Float16)fmaxf(acc[mt][nt][1] + b1_, 0.f);
          hv[2] = (_Float16)fmaxf(acc[mt][nt][2] + b2_, 0.f);
          hv[3] = (_Float16)fmaxf(acc[mt][nt][3] + b3, 0.f);
          _Float16* dst = out_h + (((size_t)b * PW + h + 1) * PW + wpx + 1) * C + o;
          *(uint2*)dst = *(uint2*)hv;
        }
      }
    } else {
#pragma unroll
      for (int nt = 0; nt < 4; ++nt) {
        const int wpx = nt * 16 + col;
        if (wpx < WW) {
          const int p = h * WW + wpx;
          const float bb[4] = {b0, b1_, b2_, b3};
#pragma unroll
          for (int r = 0; r < 4; ++r) {
            const size_t idx = ((size_t)(b * C + o + r)) * NN + p;
            out_f[idx] = (acc[mt][nt][r] + bb[r]) * amul[idx];
          }
        }
      }
    }
  }
}

// ---------------------------------------------------------------------------
// helper: 16B MFMA fragment from LDS as two ds_read_b64 (8B-aligned layouts)
// ---------------------------------------------------------------------------
__device__ inline half8 ld_frag(const _Float16* p) {
  union { half8 h8; half4v h4[2]; } u;
  u.h4[0] = *(const half4v*)p;
  u.h4[1] = *(const half4v*)(p + 4);
  return u.h8;
}

// ---------------------------------------------------------------------------
// 3. qkv as MFMA GEMM.  A = fp16 weights [s][o][c], B = src tile staged in
//    LDS as fp16 [px][ch], one pass for Q,K,V.
// ---------------------------------------------------------------------------
__global__ __launch_bounds__(256) void qkv_mfma_kernel(
    const float* __restrict__ src, const _Float16* __restrict__ Wh,
    const float* __restrict__ bq, const float* __restrict__ bk,
    const float* __restrict__ bv,
    __half* __restrict__ Q, __half* __restrict__ K, __half* __restrict__ Vt)
{
  __shared__ _Float16 Ss[32][264];     // [px][ch]  16,896 B
  const int bid = blockIdx.x;          // 784
  const int b = bid & 7;
  const int p0 = (bid >> 3) * 32;
  const int t = threadIdx.x;
  const int w = t >> 6, lane = t & 63;
  const int col = lane & 15, quad = lane >> 4;

  // stage src tile: fp32 [C][N] -> fp16 LDS [px][ch] (thread t = channel t)
  {
    const float4* sp = (const float4*)(src + ((size_t)b * C + t) * NN + p0);
    float v[32];
#pragma unroll
    for (int g = 0; g < 8; ++g) {
      const float4 f = sp[g];
      v[g * 4 + 0] = f.x; v[g * 4 + 1] = f.y;
      v[g * 4 + 2] = f.z; v[g * 4 + 3] = f.w;
    }
#pragma unroll
    for (int px = 0; px < 32; ++px) Ss[px][t] = (_Float16)v[px];
  }
  __syncthreads();

  floatx4 acc[12][2];
#pragma unroll
  for (int i = 0; i < 12; ++i)
#pragma unroll
    for (int nt = 0; nt < 2; ++nt) acc[i][nt] = (floatx4){0.f, 0.f, 0.f, 0.f};

  for (int k0 = 0; k0 < 256; k0 += 32) {
    half8 bf[2];
    bf[0] = ld_frag(&Ss[col][k0 + quad * 8]);
    bf[1] = ld_frag(&Ss[16 + col][k0 + quad * 8]);
#pragma unroll
    for (int i = 0; i < 12; ++i) {
      const int mtg = w * 12 + i;      // 0..47: [0,16)=Q, [16,32)=K, [32,48)=V
      const half8 af = *(const half8*)(Wh + (size_t)mtg * 4096 + col * 256 + k0 + quad * 8);
      acc[i][0] = __builtin_amdgcn_mfma_f32_16x16x32_f16(af, bf[0], acc[i][0], 0, 0, 0);
      acc[i][1] = __builtin_amdgcn_mfma_f32_16x16x32_f16(af, bf[1], acc[i][1], 0, 0, 0);
    }
  }

#pragma unroll
  for (int i = 0; i < 12; ++i) {
    const int mtg = w * 12 + i;
    const int s = mtg >> 4;
    const int crow = (mtg & 15) * 16 + quad * 4;    // c_out base of this lane
    const float* bp = (s == 0 ? bq : (s == 1 ? bk : bv)) + crow;
    const float4 b4 = *(const float4*)bp;
    const float bb[4] = {b4.x, b4.y, b4.z, b4.w};
#pragma unroll
    for (int nt = 0; nt < 2; ++nt) {
      const int px = p0 + nt * 16 + col;
      if (s == 2) {
#pragma unroll
        for (int r = 0; r < 4; ++r)
          Vt[((size_t)(b * C) + crow + r) * NN + px] =
              __float2half((acc[i][nt][r] + bb[r]) * 0.5f);
      } else {
        __half* dst = (s == 0 ? Q : K) + ((size_t)(b * NN) + px) * C + crow;
        __align__(8) __half hv[4];
#pragma unroll
        for (int r = 0; r < 4; ++r) hv[r] = __float2half(acc[i][nt][r] + bb[r]);
        *(uint2*)dst = *(uint2*)hv;
      }
    }
  }
}

// ---------------------------------------------------------------------------
// 4. Shared-LDS flash attention v7.  R3 post-mortem: flash6's reg-staging
//    arrays (guarded unroll) were demoted to LDS scratch (+71.7 KB,
//    LDS_Block_Size 157,696) -> 1 block/CU, 1.75 waves/SIMD, latency-bound.
//    Now: QBLK=64 (4 waves, 256 thr), grid 392, exact 8-chunk/thread staging
//    (no guards -> kr/vr stay VGPR), LDS 79,360 B -> 2 blocks/CU (8 waves),
//    cross-block overlap of stage+barrier with compute.
// ---------------------------------------------------------------------------
__global__ __launch_bounds__(256, 2) void flash7_kernel(
    const __half* __restrict__ Qg, const __half* __restrict__ Kg,
    const __half* __restrict__ Vtg, __half* __restrict__ O16, int accumulate)
{
  __shared__ _Float16 Ks[64][264];     // [key][ch]   33,792 B (16B-aligned rows)
  __shared__ _Float16 Vs[256][72];     // [ch][key]   36,864 B (16B-aligned rows)
  __shared__ _Float16 Pb[4][16][68];   // per-wave P   8,704 B

  const int bid = blockIdx.x;          // 8 * 49 = 392
  const int b = bid & 7;               // XCD-aligned batch
  const int q0 = (bid >> 3) * 64;      // 49 q-tiles of 64 rows
  const int t = threadIdx.x;           // 0..255
  const int w = t >> 6;                // wave 0..3
  const int lane = t & 63;
  const int col = lane & 15;
  const int quad = lane >> 4;

  const _Float16* Kb = (const _Float16*)Kg + (size_t)(b * NN) * C;
  const _Float16* Vb = (const _Float16*)Vtg + (size_t)(b * C) * NN;

  // Q fragments for this wave's 16 rows (regs for all 49 iters)
  const _Float16* Qp = (const _Float16*)Qg +
      ((size_t)(b * NN) + q0 + w * 16 + col) * C + quad * 8;
  half8 Qf[8];
#pragma unroll
  for (int s = 0; s < 8; ++s) Qf[s] = *(const half8*)(Qp + s * 32);

  floatx4 Ov[16];
#pragma unroll
  for (int n = 0; n < 16; ++n) Ov[n] = (floatx4){0.f, 0.f, 0.f, 0.f};
  float m[4] = {-1e30f, -1e30f, -1e30f, -1e30f};
  float l[4] = {0.f, 0.f, 0.f, 0.f};

  // staging regs: K tile 64x256 fp16 = 2048 16B-chunks = 8/thread.  V same.
  uint4 kr[8], vr[8];
  const int kkey = t >> 5, koff = t & 31;        // K: chunk i = j*256+t
  const int vch0 = t >> 3, voff = t & 7;         // V: chunk i = j*256+t

#pragma unroll
  for (int j = 0; j < 8; ++j)
    kr[j] = *(const uint4*)(Kb + (size_t)(j * 8 + kkey) * C + koff * 8);
#pragma unroll
  for (int j = 0; j < 8; ++j)
    vr[j] = *(const uint4*)(Vb + (size_t)(j * 32 + vch0) * NN + voff * 8);

  for (int kb = 0; kb < 49; ++kb) {
    __syncthreads();                   // prev iter's LDS reads complete
#pragma unroll
    for (int j = 0; j < 8; ++j)
      *(uint4*)&Ks[j * 8 + kkey][koff * 8] = kr[j];
#pragma unroll
    for (int j = 0; j < 8; ++j)
      *(uint4*)&Vs[j * 32 + vch0][voff * 8] = vr[j];
    __syncthreads();                   // tile visible to all waves

    if (kb + 1 < 49) {                 // prefetch next tile under compute
      const int key0 = (kb + 1) * 64;
#pragma unroll
      for (int j = 0; j < 8; ++j)
        kr[j] = *(const uint4*)(Kb + (size_t)(key0 + j * 8 + kkey) * C + koff * 8);
#pragma unroll
      for (int j = 0; j < 8; ++j)
        vr[j] = *(const uint4*)(Vb + (size_t)(j * 32 + vch0) * NN + key0 + voff * 8);
    }

    // ---- S = Q K^T * scale, 16q x 64k (K from LDS) ------------------------
    floatx4 Sv[4];
#pragma unroll
    for (int nt = 0; nt < 4; ++nt) {
      floatx4 acc = (floatx4){0.f, 0.f, 0.f, 0.f};
#pragma unroll
      for (int s = 0; s < 8; ++s) {
        const half8 bf = *(const half8*)&Ks[nt * 16 + col][s * 32 + quad * 8];
        acc = __builtin_amdgcn_mfma_f32_16x16x32_f16(Qf[s], bf, acc, 0, 0, 0);
      }
      Sv[nt] = acc * 0.0625f;   // 1/sqrt(256)
    }

    // ---- online softmax ---------------------------------------------------
    float f[4];
    bool grow = false;
#pragma unroll
    for (int r = 0; r < 4; ++r) {
      float v = fmaxf(fmaxf(Sv[0][r], Sv[1][r]), fmaxf(Sv[2][r], Sv[3][r]));
      v = fmaxf(v, __shfl_xor(v, 1));
      v = fmaxf(v, __shfl_xor(v, 2));
      v = fmaxf(v, __shfl_xor(v, 4));
      v = fmaxf(v, __shfl_xor(v, 8));
      const float mn = fmaxf(m[r], v);
      f[r] = __expf(m[r] - mn);
      grow = grow || (v > m[r]);
      m[r] = mn;
    }
    float rowsum[4] = {0.f, 0.f, 0.f, 0.f};
#pragma unroll
    for (int nt = 0; nt < 4; ++nt) {
#pragma unroll
      for (int r = 0; r < 4; ++r) {
        const float p = __expf(Sv[nt][r] - m[r]);
        Sv[nt][r] = p;
        rowsum[r] += p;
      }
    }
#pragma unroll
    for (int r = 0; r < 4; ++r) {
      float s = rowsum[r];
      s += __shfl_xor(s, 1);
      s += __shfl_xor(s, 2);
      s += __shfl_xor(s, 4);
      s += __shfl_xor(s, 8);
      l[r] = l[r] * f[r] + s;
    }

    // ---- P -> per-wave LDS scratch -> A-fragment layout --------------------
#pragma unroll
    for (int nt = 0; nt < 4; ++nt)
#pragma unroll
      for (int r = 0; r < 4; ++r)
        Pb[w][quad * 4 + r][nt * 16 + col] = (_Float16)Sv[nt][r];

    if (__any(grow)) {          // T13: skip rescale when max did not grow
      const floatx4 fv = {f[0], f[1], f[2], f[3]};
#pragma unroll
      for (int n = 0; n < 16; ++n) Ov[n] *= fv;
    }

    const half8 pa0 = ld_frag(&Pb[w][col][quad * 8]);
    const half8 pa1 = ld_frag(&Pb[w][col][32 + quad * 8]);

    // ---- O += P V  (V^T fragments from LDS) -------------------------------
#pragma unroll
    for (int nt2 = 0; nt2 < 16; ++nt2) {
      const half8 bv0 = *(const half8*)&Vs[nt2 * 16 + col][quad * 8];
      const half8 bv1 = *(const half8*)&Vs[nt2 * 16 + col][32 + quad * 8];
      Ov[nt2] = __builtin_amdgcn_mfma_f32_16x16x32_f16(pa0, bv0, Ov[nt2], 0, 0, 0);
      Ov[nt2] = __builtin_amdgcn_mfma_f32_16x16x32_f16(pa1, bv1, Ov[nt2], 0, 0, 0);
    }
  }

  float inv[4];
#pragma unroll
  for (int r = 0; r < 4; ++r) inv[r] = 1.f / l[r];
#pragma unroll
  for (int nt2 = 0; nt2 < 16; ++nt2) {
#pragma unroll
    for (int r = 0; r < 4; ++r) {
      const float val = Ov[nt2][r] * inv[r];
      __half* dst = O16 + ((size_t)(b * NN) + q0 + w * 16 + quad * 4 + r) * C +
                    nt2 * 16 + col;
      if (accumulate) *dst = __float2half(val + __half2float(*dst));
      else *dst = __float2half(val);
    }
  }
}

// ---------------------------------------------------------------------------
// 5. out 1x1 conv + residual as MFMA GEMM.
// ---------------------------------------------------------------------------
__global__ __launch_bounds__(256) void outconv_mfma_kernel(
    const __half* __restrict__ O16, const _Float16* __restrict__ owh,
    const float* __restrict__ ob, const float* __restrict__ x,
    float* __restrict__ o)
{
  const int bid = blockIdx.x;          // 392
  const int b = bid & 7;
  const int p0 = (bid >> 3) * 64;
  const int t = threadIdx.x;
  const int w = t >> 6, lane = t & 63;
  const int col = lane & 15, quad = lane >> 4;

  floatx4 acc[4][4];
#pragma unroll
  for (int mt = 0; mt < 4; ++mt)
#pragma unroll
    for (int nt = 0; nt < 4; ++nt) acc[mt][nt] = (floatx4){0.f, 0.f, 0.f, 0.f};

  const _Float16* Ob = (const _Float16*)O16 + (size_t)(b * NN) * C;

  for (int k0 = 0; k0 < 256; k0 += 32) {
    half8 bf[4];
#pragma unroll
    for (int nt = 0; nt < 4; ++nt)
      bf[nt] = *(const half8*)(Ob + (size_t)(p0 + nt * 16 + col) * C + k0 + quad * 8);
#pragma unroll
    for (int mt = 0; mt < 4; ++mt) {
      const int crow = w * 64 + mt * 16 + col;
      const half8 af = *(const half8*)(owh + (size_t)crow * 256 + k0 + quad * 8);
#pragma unroll
      for (int nt = 0; nt < 4; ++nt)
        acc[mt][nt] = __builtin_amdgcn_mfma_f32_16x16x32_f16(af, bf[nt], acc[mt][nt], 0, 0, 0);
    }
  }

#pragma unroll
  for (int mt = 0; mt < 4; ++mt) {
    const int c0 = w * 64 + mt * 16 + quad * 4;
    const float4 b4 = *(const float4*)(ob + c0);
    const float bb[4] = {b4.x, b4.y, b4.z, b4.w};
#pragma unroll
    for (int nt = 0; nt < 4; ++nt) {
      const int px = p0 + nt * 16 + col;
#pragma unroll
      for (int r = 0; r < 4; ++r) {
        const size_t idx = ((size_t)(b * C) + c0 + r) * NN + px;
        o[idx] = acc[mt][nt][r] + bb[r] + x[idx];
      }
    }
  }
}

// ---------------------------------------------------------------------------
// 6. BN stats
// ---------------------------------------------------------------------------
__global__ __launch_bounds__(256) void stats_kernel(
    const float* __restrict__ o, float* __restrict__ stats)
{
  const int c = blockIdx.x, t = threadIdx.x;
  float s = 0.f, sq = 0.f;
  for (int b = 0; b < BB; ++b) {
    const float* p = o + ((size_t)b * C + c) * NN;
    for (int idx = t; idx < NN; idx += 256) {
      const float v = p[idx];
      s += v; sq += v * v;
    }
  }
#pragma unroll
  for (int off = 32; off >= 1; off >>= 1) {
    s += __shfl_xor(s, off);
    sq += __shfl_xor(sq, off);
  }
  __shared__ float red[8];
  const int wv = t >> 6;
  if ((t & 63) == 0) { red[wv] = s; red[4 + wv] = sq; }
  __syncthreads();
  if (t == 0) {
    s = red[0] + red[1] + red[2] + red[3];
    sq = red[4] + red[5] + red[6] + red[7];
    stats[c] = s;
    stats[C + c] = sq;
  }
}

// ---------------------------------------------------------------------------
// 7. BN normalize -> d_out
// ---------------------------------------------------------------------------
__global__ __launch_bounds__(256) void bn_kernel(
    const float* __restrict__ o, const float* __restrict__ stats,
    const float* __restrict__ g, const float* __restrict__ bta,
    float* __restrict__ out)
{
  const size_t idx = (size_t)blockIdx.x * 256 + threadIdx.x;
  const float inv_n = 1.f / (float)(BB * NN);
  float4 v = ((const float4*)o)[idx];
  const int c = (int)((idx * 4 / NN) % C);
  const float mean = stats[c] * inv_n;
  const float var = stats[C + c] * inv_n - mean * mean;
  const float sc = rsqrtf(var + 1e-5f) * g[c];
  const float sh = bta[c] - mean * sc;
  v.x = v.x * sc + sh; v.y = v.y * sc + sh;
  v.z = v.z * sc + sh; v.w = v.w * sc + sh;
  ((float4*)out)[idx] = v;
}

// ---------------------------------------------------------------------------
extern "C" void kernel_launch(void* const* d_in, const int* in_sizes, int n_in,
                              void* d_out, int out_size, void* d_ws, size_t ws_size,
                              hipStream_t stream)
{
  const float* x    = (const float*)d_in[0];
  const float* hn   = (const float*)d_in[1];
  const float* w1   = (const float*)d_in[2];  const float* b1   = (const float*)d_in[3];
  const float* w2   = (const float*)d_in[4];  const float* b2   = (const float*)d_in[5];
  const float* wadj = (const float*)d_in[6];  const float* badj = (const float*)d_in[7];
  const float* tw1  = (const float*)d_in[8];  const float* tb1  = (const float*)d_in[9];
  const float* tw2  = (const float*)d_in[10]; const float* tb2  = (const float*)d_in[11];
  const float* qaw  = (const float*)d_in[12]; const float* qab  = (const float*)d_in[13];
  const float* kaw  = (const float*)d_in[14]; const float* kab  = (const float*)d_in[15];
  const float* vaw  = (const float*)d_in[16]; const float* vab  = (const float*)d_in[17];
  const float* qtw  = (const float*)d_in[18]; const float* qtb  = (const float*)d_in[19];
  const float* ktw  = (const float*)d_in[20]; const float* ktb  = (const float*)d_in[21];
  const float* vtw  = (const float*)d_in[22]; const float* vtb  = (const float*)d_in[23];
  const float* ow   = (const float*)d_in[24]; const float* obias= (const float*)d_in[25];
  const float* bng  = (const float*)d_in[26]; const float* bnb  = (const float*)d_in[27];

  // workspace plan (peak ~91.9 MB; 115.6 MB proven):
  //   [a 25.69][tt 25.69][hnpad 13.79+slk][t1pad 13.79+slk][w1h 1.18][w2h 1.18]
  //   Q/K/Vt (38.5) alias hnpad.. after convs; O16 (12.85) aliases a after qkv#1.
  //   [stats 4KB][Whall 0.92MB][w1T 16KB][wadjT 512KB] appended at the end.
  char* ws = (char*)d_ws;
  const size_t TENS  = (size_t)BB * C * NN * sizeof(float);        // 25,690,112
  const size_t HTENS = (size_t)BB * NN * C * sizeof(__half);       // 12,845,056
  const size_t PADT  = (size_t)BB * PW * PW * C * sizeof(_Float16) // 13,778,944
                       + 16384;                                    // OOB-read slack
  const size_t WT    = (size_t)9 * C * C * sizeof(_Float16);       // 1,179,648
  float*    a     = (float*)(ws);
  float*    tt    = (float*)(ws + TENS);
  _Float16* hnpad = (_Float16*)(ws + 2 * TENS);
  _Float16* t1pad = (_Float16*)(ws + 2 * TENS + PADT);
  _Float16* w1h   = (_Float16*)(ws + 2 * TENS + 2 * PADT);
  _Float16* w2h   = (_Float16*)(ws + 2 * TENS + 2 * PADT + WT);
  __half*   Q     = (__half*)(ws + 2 * TENS);            // aliases hnpad (dead)
  __half*   K     = (__half*)(ws + 2 * TENS + HTENS);
  __half*   Vt    = (__half*)(ws + 2 * TENS + 2 * HTENS);
  float*    stats = (float*)(ws + 2 * TENS + 3 * HTENS);
  _Float16* Whall = (_Float16*)(ws + 2 * TENS + 3 * HTENS + 4096); // 7*65536 fp16
  float*    w1T   = (float*)(ws + 2 * TENS + 3 * HTENS + 4096 + 7 * 65536 * 2);
  float*    wadjT = w1T + RR * C;                        // 2C*C fp32
  __half*   O16   = (__half*)a;    // a dead after qkv#1 reads it

  const int PIX_TILES = BB * NT;           // 1568
  const int CONV_BLKS = BB * HH * 2;       // 896
  const int FLASH_BLKS = BB * (NN / 64);   // 392 (4 waves x 16 q-rows each)
  const int QKV_BLKS = BB * (NN / 32);     // 784
  const int OUT_BLKS = BB * (NN / 64);     // 392

  wprep_kernel<<<9 * C * C / 256, 256, 0, stream>>>(tw1, tw2, w1h, w2h);
  wprep_qkv_kernel<<<7 * C * C / 256, 256, 0, stream>>>(
      qaw, kaw, vaw, qtw, ktw, vtw, ow, Whall);
  wprep_attr_kernel<<<(RR * C + 2 * C * C) / 256, 256, 0, stream>>>(
      w1, wadj, w1T, wadjT);
  padzero_kernel<<<2 * BB * PW, 256, 0, stream>>>(hnpad, t1pad);
  hnprep_kernel<<<PIX_TILES, 256, 0, stream>>>(hn, hnpad);
  attr_kernel<<<PIX_TILES, 256, 0, stream>>>(x, w1T, b1, w2, b2, wadjT, badj, a);
  conv_mfma_kernel<<<CONV_BLKS, 256, 0, stream>>>(hnpad, w1h, tb1, nullptr, t1pad, nullptr, 0);
  conv_mfma_kernel<<<CONV_BLKS, 256, 0, stream>>>(t1pad, w2h, tb2, a, nullptr, tt, 1);

  qkv_mfma_kernel<<<QKV_BLKS, 256, 0, stream>>>(a, Whall, qab, kab, vab, Q, K, Vt);
  flash7_kernel<<<FLASH_BLKS, 256, 0, stream>>>(Q, K, Vt, O16, 0);
  qkv_mfma_kernel<<<QKV_BLKS, 256, 0, stream>>>(tt, Whall + 3 * 65536, qtb, ktb, vtb, Q, K, Vt);
  flash7_kernel<<<FLASH_BLKS, 256, 0, stream>>>(Q, K, Vt, O16, 1);

  float* o = tt;      // tt dead after qkv#2
  outconv_mfma_kernel<<<OUT_BLKS, 256, 0, stream>>>(O16, Whall + 6 * 65536, obias, x, o);
  stats_kernel<<<C, 256, 0, stream>>>(o, stats);
  bn_kernel<<<(BB * C * NN / 4) / 256, 256, 0, stream>>>(o, stats, bng, bnb, (float*)d_out);
}

// Round 5
// 1504.018 us; speedup vs baseline: 1.2791x; 1.2791x over previous
//
#include <hip/hip_runtime.h>
#include <hip/hip_fp16.h>

#define BB 8
#define C 256
#define HH 56
#define WW 56
#define NN 3136      // HH*WW
#define RR 16
#define NT (NN/16)   // 196 pixel-tiles per image
#define PW 58        // padded spatial width/height

typedef _Float16 half8 __attribute__((ext_vector_type(8)));
typedef _Float16 half4v __attribute__((ext_vector_type(4)));
typedef float floatx4 __attribute__((ext_vector_type(4)));

#define AS1 __attribute__((address_space(1)))
#define AS3 __attribute__((address_space(3)))

// async 16B global->LDS DMA (no VGPR staging, wave-uniform LDS base + lane*16)
__device__ __forceinline__ void gload16(const _Float16* gsrc, _Float16* ldst) {
  __builtin_amdgcn_global_load_lds((const AS1 unsigned int*)(const void*)gsrc,
                                   (AS3 unsigned int*)(void*)ldst, 16, 0, 0);
}

// ---------------------------------------------------------------------------
// 1. attr branch fused: a = adj( concat( relu(W2 relu(W1 x)), x ) )
//    Transposed fp32 weights (w1T[c][r], wadjT[k][o]) -> coalesced reads.
// ---------------------------------------------------------------------------
__global__ __launch_bounds__(256) void attr_kernel(
    const float* __restrict__ x,
    const float* __restrict__ w1T, const float* __restrict__ b1,
    const float* __restrict__ w2, const float* __restrict__ b2,
    const float* __restrict__ wadjT, const float* __restrict__ badj,
    float* __restrict__ a_out)
{
  __shared__ float xs[C][20];
  __shared__ float a2s[C][20];
  __shared__ float a1s[RR][20];
  const int tile = blockIdx.x;
  const int b = tile / NT;
  const int p0 = (tile % NT) * 16;
  const int t = threadIdx.x;

  {
    const float* xb = x + ((size_t)b * C + t) * NN + p0;
    const float4* xb4 = (const float4*)xb;
    float* row = xs[t];
#pragma unroll
    for (int g = 0; g < 4; ++g) {
      float4 v = xb4[g];
      row[g * 4 + 0] = v.x; row[g * 4 + 1] = v.y;
      row[g * 4 + 2] = v.z; row[g * 4 + 3] = v.w;
    }
  }
  __syncthreads();

  {
    const int r = t & 15, pp = t >> 4;
    float acc = b1[r];
    for (int c = 0; c < C; ++c) acc += w1T[c * 16 + r] * xs[c][pp];
    a1s[r][pp] = fmaxf(acc, 0.f);
  }
  __syncthreads();

  {
    const int o = t;
    float acc[16];
    const float bias = b2[o];
#pragma unroll
    for (int p = 0; p < 16; ++p) acc[p] = bias;
    const float* wr = w2 + o * RR;
    for (int k = 0; k < RR; ++k) {
      const float w = wr[k];
#pragma unroll
      for (int p = 0; p < 16; ++p) acc[p] += w * a1s[k][p];
    }
    float* row = a2s[o];
#pragma unroll
    for (int p = 0; p < 16; ++p) row[p] = fmaxf(acc[p], 0.f);
  }
  __syncthreads();

  {
    const int o = t;
    float acc[16];
    const float bias = badj[o];
#pragma unroll
    for (int p = 0; p < 16; ++p) acc[p] = bias;
    const float* wTa = wadjT + o;            // wadjT[k][o], k in [0,256)
    for (int k = 0; k < C; ++k) {
      const float w = wTa[k * C];
      const float4* ar = (const float4*)a2s[k];
#pragma unroll
      for (int g = 0; g < 4; ++g) {
        float4 v = ar[g];
        acc[g * 4 + 0] += w * v.x; acc[g * 4 + 1] += w * v.y;
        acc[g * 4 + 2] += w * v.z; acc[g * 4 + 3] += w * v.w;
      }
    }
    const float* wTx = wadjT + C * C + o;    // wadjT[256+k][o]
    for (int k = 0; k < C; ++k) {
      const float w = wTx[k * C];
      const float4* xr = (const float4*)xs[k];
#pragma unroll
      for (int g = 0; g < 4; ++g) {
        float4 v = xr[g];
        acc[g * 4 + 0] += w * v.x; acc[g * 4 + 1] += w * v.y;
        acc[g * 4 + 2] += w * v.z; acc[g * 4 + 3] += w * v.w;
      }
    }
    float* op = a_out + ((size_t)b * C + o) * NN + p0;
    float4* op4 = (float4*)op;
#pragma unroll
    for (int g = 0; g < 4; ++g)
      op4[g] = make_float4(acc[g * 4 + 0], acc[g * 4 + 1], acc[g * 4 + 2], acc[g * 4 + 3]);
  }
}

// ---------------------------------------------------------------------------
// 1b. attr weight transposes (fp32)
// ---------------------------------------------------------------------------
__global__ __launch_bounds__(256) void wprep_attr_kernel(
    const float* __restrict__ w1, const float* __restrict__ wadj,
    float* __restrict__ w1T, float* __restrict__ wadjT)
{
  const int i = blockIdx.x * 256 + threadIdx.x;   // 528*256 = 135,168
  if (i < RR * C) {
    const int c = i >> 4, r = i & 15;
    w1T[i] = w1[r * C + c];
  } else {
    const int j = i - RR * C;                     // 2C*C entries
    const int k = j >> 8, o = j & 255;
    wadjT[j] = wadj[(size_t)o * (2 * C) + k];
  }
}

// ---------------------------------------------------------------------------
// 2a. conv weight prep
// ---------------------------------------------------------------------------
__global__ __launch_bounds__(256) void wprep_kernel(
    const float* __restrict__ tw1, const float* __restrict__ tw2,
    _Float16* __restrict__ w1h, _Float16* __restrict__ w2h)
{
  const int i = blockIdx.x * 256 + threadIdx.x;   // over 9*256*256
  const int tap = i >> 16;
  const int rem = i & 65535;
  const int o = rem >> 8;
  const int c = rem & 255;
  w1h[i] = (_Float16)tw1[((size_t)o * C + c) * 9 + tap];
  w2h[i] = (_Float16)tw2[((size_t)o * C + c) * 9 + (8 - tap)];
}

// ---------------------------------------------------------------------------
// 2a'. 1x1 weight prep: 7 C*C fp32 -> fp16 [o][c].  Order: qa,ka,va,qt,kt,vt,ow
// ---------------------------------------------------------------------------
__global__ __launch_bounds__(256) void wprep_qkv_kernel(
    const float* __restrict__ m0, const float* __restrict__ m1,
    const float* __restrict__ m2, const float* __restrict__ m3,
    const float* __restrict__ m4, const float* __restrict__ m5,
    const float* __restrict__ m6, _Float16* __restrict__ Whall)
{
  const int i = blockIdx.x * 256 + threadIdx.x;   // over 7*65536
  const int mat = i >> 16, rem = i & 65535;
  const float* s;
  switch (mat) {
    case 0: s = m0; break; case 1: s = m1; break; case 2: s = m2; break;
    case 3: s = m3; break; case 4: s = m4; break; case 5: s = m5; break;
    default: s = m6; break;
  }
  Whall[i] = (_Float16)s[rem];
}

// ---------------------------------------------------------------------------
// 2b. zero the pad border of both padded-NHWC fp16 buffers
// ---------------------------------------------------------------------------
__global__ __launch_bounds__(256) void padzero_kernel(
    _Float16* __restrict__ buf1, _Float16* __restrict__ buf2)
{
  const int bid = blockIdx.x;                 // 2 * BB * PW
  _Float16* buf = (bid < BB * PW) ? buf1 : buf2;
  const int rb = bid % (BB * PW);
  const int b = rb / PW, r = rb % PW;
  _Float16* row = buf + ((size_t)b * PW + r) * PW * C;
  const float4 z = make_float4(0.f, 0.f, 0.f, 0.f);
  if (r == 0 || r == PW - 1) {
    for (int i = threadIdx.x; i < PW * C / 8; i += 256) ((float4*)row)[i] = z;
  } else {
    const int i = threadIdx.x;
    if (i < 32) ((float4*)row)[i] = z;                       // col 0
    else if (i < 64) ((float4*)(row + (PW - 1) * C))[i - 32] = z;  // col 57
  }
}

// ---------------------------------------------------------------------------
// 2c. hn (fp32 NCHW) -> hnpad (fp16 padded NHWC) interior, via LDS transpose
// ---------------------------------------------------------------------------
__global__ __launch_bounds__(256) void hnprep_kernel(
    const float* __restrict__ hn, _Float16* __restrict__ hnpad)
{
  __shared__ float xs[C][17];
  const int tile = blockIdx.x;
  const int b = tile / NT;
  const int p0 = (tile % NT) * 16;
  const int t = threadIdx.x;
  {
    const float4* sb = (const float4*)(hn + ((size_t)b * C + t) * NN + p0);
    float* row = xs[t];
#pragma unroll
    for (int g = 0; g < 4; ++g) {
      float4 v = sb[g];
      row[g * 4 + 0] = v.x; row[g * 4 + 1] = v.y;
      row[g * 4 + 2] = v.z; row[g * 4 + 3] = v.w;
    }
  }
  __syncthreads();
  const int p = t >> 4, c0 = (t & 15) * 16;
  const int pg = p0 + p;
  const int h = pg / WW, w = pg % WW;
  __align__(16) _Float16 tmp[16];
#pragma unroll
  for (int j = 0; j < 16; ++j) tmp[j] = (_Float16)xs[c0 + j][p];
  _Float16* dst = hnpad + (((size_t)b * PW + h + 1) * PW + w + 1) * C + c0;
  ((uint4*)dst)[0] = ((uint4*)tmp)[0];
  ((uint4*)dst)[1] = ((uint4*)tmp)[1];
}

// ---------------------------------------------------------------------------
// 2d. conv3x3 as 9-tap MFMA GEMM.  XCD-swizzled (b = bid & 7).
// ---------------------------------------------------------------------------
__global__ __launch_bounds__(256) void conv_mfma_kernel(
    const _Float16* __restrict__ inpad, const _Float16* __restrict__ wh,
    const float* __restrict__ bias, const float* __restrict__ amul,
    _Float16* __restrict__ out_h, float* __restrict__ out_f, int mode)
{
  const int bid = blockIdx.x;          // BB*56*2
  const int b = bid & 7;               // XCD-aligned batch
  const int rest = bid >> 3;           // 0..111
  const int ohalf = rest & 1;
  const int h = rest >> 1;
  const int t = threadIdx.x;
  const int wave = t >> 6, lane = t & 63;
  const int col = lane & 15, quad = lane >> 4;
  const int o_base = ohalf * 128 + wave * 32;

  floatx4 acc[2][4];
#pragma unroll
  for (int mt = 0; mt < 2; ++mt)
#pragma unroll
    for (int nt = 0; nt < 4; ++nt) acc[mt][nt] = (floatx4){0.f, 0.f, 0.f, 0.f};

  const _Float16* inb = inpad + (size_t)b * PW * PW * C;

  for (int tap = 0; tap < 9; ++tap) {
    const int dy = tap / 3;
    const int dx = tap - dy * 3;
    const _Float16* wtap = wh + (size_t)tap * C * C + quad * 8;
    const _Float16* inrow = inb + ((size_t)(h + dy) * PW + dx + col) * C + quad * 8;
    for (int kc = 0; kc < 8; ++kc) {
      const int c0 = kc * 32;
      const half8 A0 = *(const half8*)(wtap + (size_t)(o_base + col) * C + c0);
      const half8 A1 = *(const half8*)(wtap + (size_t)(o_base + 16 + col) * C + c0);
#pragma unroll
      for (int nt = 0; nt < 4; ++nt) {
        const half8 Bv = *(const half8*)(inrow + (size_t)(nt * 16) * C + c0);
        acc[0][nt] = __builtin_amdgcn_mfma_f32_16x16x32_f16(A0, Bv, acc[0][nt], 0, 0, 0);
        acc[1][nt] = __builtin_amdgcn_mfma_f32_16x16x32_f16(A1, Bv, acc[1][nt], 0, 0, 0);
      }
    }
  }

#pragma unroll
  for (int mt = 0; mt < 2; ++mt) {
    const int o = o_base + mt * 16 + quad * 4;
    const float* bp = bias + o;
    const float b0 = bp[0], b1_ = bp[1], b2_ = bp[2], b3 = bp[3];
    if (mode == 0) {
#pragma unroll
      for (int nt = 0; nt < 4; ++nt) {
        const int wpx = nt * 16 + col;
        if (wpx < WW) {
          __align__(8) _Float16 hv[4];
          hv[0] = (_Float16)fmaxf(acc[mt][nt][0] + b0, 0.f);
          hv[1] = (_Float16)fmaxf(acc[mt][nt][1] + b1_, 0.f);
          hv[2] = (_Float16)fmaxf(acc[mt][nt][2] + b2_, 0.f);
          hv[3] = (_Float16)fmaxf(acc[mt][nt][3] + b3, 0.f);
          _Float16* dst = out_h + (((size_t)b * PW + h + 1) * PW + wpx + 1) * C + o;
          *(uint2*)dst = *(uint2*)hv;
        }
      }
    } else {
#pragma unroll
      for (int nt = 0; nt < 4; ++nt) {
        const int wpx = nt * 16 + col;
        if (wpx < WW) {
          const int p = h * WW + wpx;
          const float bb[4] = {b0, b1_, b2_, b3};
#pragma unroll
          for (int r = 0; r < 4; ++r) {
            const size_t idx = ((size_t)(b * C + o + r)) * NN + p;
            out_f[idx] = (acc[mt][nt][r] + bb[r]) * amul[idx];
          }
        }
      }
    }
  }
}

// ---------------------------------------------------------------------------
// helper: 16B MFMA fragment from LDS as two ds_read_b64 (8B-aligned layouts)
// ---------------------------------------------------------------------------
__device__ inline half8 ld_frag(const _Float16* p) {
  union { half8 h8; half4v h4[2]; } u;
  u.h4[0] = *(const half4v*)p;
  u.h4[1] = *(const half4v*)(p + 4);
  return u.h8;
}

// ---------------------------------------------------------------------------
// 3. qkv as MFMA GEMM.  A = fp16 weights [s][o][c], B = src tile staged in
//    LDS as fp16 [px][ch], one pass for Q,K,V.
// ---------------------------------------------------------------------------
__global__ __launch_bounds__(256) void qkv_mfma_kernel(
    const float* __restrict__ src, const _Float16* __restrict__ Wh,
    const float* __restrict__ bq, const float* __restrict__ bk,
    const float* __restrict__ bv,
    __half* __restrict__ Q, __half* __restrict__ K, __half* __restrict__ Vt)
{
  __shared__ _Float16 Ss[32][264];     // [px][ch]  16,896 B
  const int bid = blockIdx.x;          // 784
  const int b = bid & 7;
  const int p0 = (bid >> 3) * 32;
  const int t = threadIdx.x;
  const int w = t >> 6, lane = t & 63;
  const int col = lane & 15, quad = lane >> 4;

  // stage src tile: fp32 [C][N] -> fp16 LDS [px][ch] (thread t = channel t)
  {
    const float4* sp = (const float4*)(src + ((size_t)b * C + t) * NN + p0);
    float v[32];
#pragma unroll
    for (int g = 0; g < 8; ++g) {
      const float4 f = sp[g];
      v[g * 4 + 0] = f.x; v[g * 4 + 1] = f.y;
      v[g * 4 + 2] = f.z; v[g * 4 + 3] = f.w;
    }
#pragma unroll
    for (int px = 0; px < 32; ++px) Ss[px][t] = (_Float16)v[px];
  }
  __syncthreads();

  floatx4 acc[12][2];
#pragma unroll
  for (int i = 0; i < 12; ++i)
#pragma unroll
    for (int nt = 0; nt < 2; ++nt) acc[i][nt] = (floatx4){0.f, 0.f, 0.f, 0.f};

  for (int k0 = 0; k0 < 256; k0 += 32) {
    half8 bf[2];
    bf[0] = ld_frag(&Ss[col][k0 + quad * 8]);
    bf[1] = ld_frag(&Ss[16 + col][k0 + quad * 8]);
#pragma unroll
    for (int i = 0; i < 12; ++i) {
      const int mtg = w * 12 + i;      // 0..47: [0,16)=Q, [16,32)=K, [32,48)=V
      const half8 af = *(const half8*)(Wh + (size_t)mtg * 4096 + col * 256 + k0 + quad * 8);
      acc[i][0] = __builtin_amdgcn_mfma_f32_16x16x32_f16(af, bf[0], acc[i][0], 0, 0, 0);
      acc[i][1] = __builtin_amdgcn_mfma_f32_16x16x32_f16(af, bf[1], acc[i][1], 0, 0, 0);
    }
  }

#pragma unroll
  for (int i = 0; i < 12; ++i) {
    const int mtg = w * 12 + i;
    const int s = mtg >> 4;
    const int crow = (mtg & 15) * 16 + quad * 4;    // c_out base of this lane
    const float* bp = (s == 0 ? bq : (s == 1 ? bk : bv)) + crow;
    const float4 b4 = *(const float4*)bp;
    const float bb[4] = {b4.x, b4.y, b4.z, b4.w};
#pragma unroll
    for (int nt = 0; nt < 2; ++nt) {
      const int px = p0 + nt * 16 + col;
      if (s == 2) {
#pragma unroll
        for (int r = 0; r < 4; ++r)
          Vt[((size_t)(b * C) + crow + r) * NN + px] =
              __float2half((acc[i][nt][r] + bb[r]) * 0.5f);
      } else {
        __half* dst = (s == 0 ? Q : K) + ((size_t)(b * NN) + px) * C + crow;
        __align__(8) __half hv[4];
#pragma unroll
        for (int r = 0; r < 4; ++r) hv[r] = __float2half(acc[i][nt][r] + bb[r]);
        *(uint2*)dst = *(uint2*)hv;
      }
    }
  }
}

// ---------------------------------------------------------------------------
// 4. Flash v8: global_load_lds staging (T21 both-sides XOR swizzle).
//    R4 post-mortem: flash7's reg staging (kr/vr, 64 VGPRs) spilled to
//    scratch -> 0.92 GB HBM writes/dispatch (WRITE_SIZE counter).  DMA
//    staging uses ZERO VGPRs: linear LDS tiles (K 32KB, V 32KB), global
//    source pre-swizzled by chunk cir^(row&7), reads XOR the same pattern
//    (involution) -> conflict-free.  P scratch stride 76 (152B) makes the
//    16 u16 P-writes 2-way max (was 4-way at stride 68 -> 1.97e7 conflicts).
//    LDS 75.3 KB -> 2 blocks/CU; cross-block overlap of stage vs compute.
// ---------------------------------------------------------------------------
__global__ __launch_bounds__(256) void flash8_kernel(
    const __half* __restrict__ Qg, const __half* __restrict__ Kg,
    const __half* __restrict__ Vtg, __half* __restrict__ O16, int accumulate)
{
  __shared__ _Float16 Ks[64 * 256];    // [key][ch] linear  32,768 B
  __shared__ _Float16 Vs[256 * 64];    // [ch][key] linear  32,768 B
  __shared__ _Float16 Pb[4][16][76];   // per-wave P         9,728 B

  const int bid = blockIdx.x;          // 8 * 49 = 392
  const int b = bid & 7;               // XCD-aligned batch
  const int q0 = (bid >> 3) * 64;      // 49 q-tiles of 64 rows
  const int t = threadIdx.x;           // 0..255
  const int w = t >> 6;                // wave 0..3
  const int lane = t & 63;
  const int col = lane & 15;
  const int quad = lane >> 4;

  const _Float16* Kb = (const _Float16*)Kg + (size_t)(b * NN) * C;
  const _Float16* Vb = (const _Float16*)Vtg + (size_t)(b * C) * NN;

  // Q fragments for this wave's 16 rows (regs for all 49 iters)
  const _Float16* Qp = (const _Float16*)Qg +
      ((size_t)(b * NN) + q0 + w * 16 + col) * C + quad * 8;
  half8 Qf[8];
#pragma unroll
  for (int s = 0; s < 8; ++s) Qf[s] = *(const half8*)(Qp + s * 32);

  floatx4 Ov[16];
#pragma unroll
  for (int n = 0; n < 16; ++n) Ov[n] = (floatx4){0.f, 0.f, 0.f, 0.f};
  float m[4] = {-1e30f, -1e30f, -1e30f, -1e30f};
  float l[4] = {0.f, 0.f, 0.f, 0.f};

  for (int kb = 0; kb < 49; ++kb) {
    const int key0 = kb * 64;
    __syncthreads();                   // all waves done reading prev tile

    // ---- DMA stage K,V (per wave: 8+8 x 1KB global_load_lds) --------------
    // K: chunk c (16B) at lds slot c holds global chunk (c&31)^(row&7),
    //    row = c>>5.  V: row stride 8 chunks, cir = c&7, row = c>>3.
#pragma unroll
    for (int i = 0; i < 8; ++i) {
      const int c = w * 512 + i * 64 + lane;
      const int krow = c >> 5, kcir = c & 31;
      gload16(Kb + (size_t)(key0 + krow) * C + ((kcir ^ (krow & 7)) * 8),
              Ks + (size_t)(w * 512 + i * 64) * 8);
    }
#pragma unroll
    for (int i = 0; i < 8; ++i) {
      const int c = w * 512 + i * 64 + lane;
      const int vch = c >> 3, vcir = c & 7;
      gload16(Vb + (size_t)vch * NN + key0 + ((vcir ^ (vch & 7)) * 8),
              Vs + (size_t)(w * 512 + i * 64) * 8);
    }
    asm volatile("s_waitcnt vmcnt(0)" ::: "memory");
    __syncthreads();                   // tile visible to all waves

    // ---- S = Q K^T * scale, 16q x 64k (K from LDS, swizzled read) ---------
    floatx4 Sv[4];
#pragma unroll
    for (int nt = 0; nt < 4; ++nt) {
      floatx4 acc = (floatx4){0.f, 0.f, 0.f, 0.f};
      const int krow = nt * 16 + col;
      const char* kbase = (const char*)Ks + krow * 512;
      const int kx = (krow & 7) << 4;
#pragma unroll
      for (int s = 0; s < 8; ++s) {
        const half8 bf = *(const half8*)(kbase + ((s * 64 + quad * 16) ^ kx));
        acc = __builtin_amdgcn_mfma_f32_16x16x32_f16(Qf[s], bf, acc, 0, 0, 0);
      }
      Sv[nt] = acc * 0.0625f;   // 1/sqrt(256)
    }

    // ---- online softmax ---------------------------------------------------
    float f[4];
    bool grow = false;
#pragma unroll
    for (int r = 0; r < 4; ++r) {
      float v = fmaxf(fmaxf(Sv[0][r], Sv[1][r]), fmaxf(Sv[2][r], Sv[3][r]));
      v = fmaxf(v, __shfl_xor(v, 1));
      v = fmaxf(v, __shfl_xor(v, 2));
      v = fmaxf(v, __shfl_xor(v, 4));
      v = fmaxf(v, __shfl_xor(v, 8));
      const float mn = fmaxf(m[r], v);
      f[r] = __expf(m[r] - mn);
      grow = grow || (v > m[r]);
      m[r] = mn;
    }
    float rowsum[4] = {0.f, 0.f, 0.f, 0.f};
#pragma unroll
    for (int nt = 0; nt < 4; ++nt) {
#pragma unroll
      for (int r = 0; r < 4; ++r) {
        const float p = __expf(Sv[nt][r] - m[r]);
        Sv[nt][r] = p;
        rowsum[r] += p;
      }
    }
#pragma unroll
    for (int r = 0; r < 4; ++r) {
      float s = rowsum[r];
      s += __shfl_xor(s, 1);
      s += __shfl_xor(s, 2);
      s += __shfl_xor(s, 4);
      s += __shfl_xor(s, 8);
      l[r] = l[r] * f[r] + s;
    }

    // ---- P -> per-wave LDS scratch -> A-fragment layout --------------------
#pragma unroll
    for (int nt = 0; nt < 4; ++nt)
#pragma unroll
      for (int r = 0; r < 4; ++r)
        Pb[w][quad * 4 + r][nt * 16 + col] = (_Float16)Sv[nt][r];

    if (__any(grow)) {          // T13: skip rescale when max did not grow
      const floatx4 fv = {f[0], f[1], f[2], f[3]};
#pragma unroll
      for (int n = 0; n < 16; ++n) Ov[n] *= fv;
    }

    const half8 pa0 = ld_frag(&Pb[w][col][quad * 8]);
    const half8 pa1 = ld_frag(&Pb[w][col][32 + quad * 8]);

    // ---- O += P V  (V from LDS, swizzled read) ----------------------------
#pragma unroll
    for (int nt2 = 0; nt2 < 16; ++nt2) {
      const int vrow = nt2 * 16 + col;
      const char* vbase = (const char*)Vs + vrow * 128;
      const int vx = (vrow & 7) << 4;
      const half8 bv0 = *(const half8*)(vbase + ((quad * 16) ^ vx));
      const half8 bv1 = *(const half8*)(vbase + ((64 + quad * 16) ^ vx));
      Ov[nt2] = __builtin_amdgcn_mfma_f32_16x16x32_f16(pa0, bv0, Ov[nt2], 0, 0, 0);
      Ov[nt2] = __builtin_amdgcn_mfma_f32_16x16x32_f16(pa1, bv1, Ov[nt2], 0, 0, 0);
    }
  }

  float inv[4];
#pragma unroll
  for (int r = 0; r < 4; ++r) inv[r] = 1.f / l[r];
#pragma unroll
  for (int nt2 = 0; nt2 < 16; ++nt2) {
#pragma unroll
    for (int r = 0; r < 4; ++r) {
      const float val = Ov[nt2][r] * inv[r];
      __half* dst = O16 + ((size_t)(b * NN) + q0 + w * 16 + quad * 4 + r) * C +
                    nt2 * 16 + col;
      if (accumulate) *dst = __float2half(val + __half2float(*dst));
      else *dst = __float2half(val);
    }
  }
}

// ---------------------------------------------------------------------------
// 5. out 1x1 conv + residual as MFMA GEMM.
// ---------------------------------------------------------------------------
__global__ __launch_bounds__(256) void outconv_mfma_kernel(
    const __half* __restrict__ O16, const _Float16* __restrict__ owh,
    const float* __restrict__ ob, const float* __restrict__ x,
    float* __restrict__ o)
{
  const int bid = blockIdx.x;          // 392
  const int b = bid & 7;
  const int p0 = (bid >> 3) * 64;
  const int t = threadIdx.x;
  const int w = t >> 6, lane = t & 63;
  const int col = lane & 15, quad = lane >> 4;

  floatx4 acc[4][4];
#pragma unroll
  for (int mt = 0; mt < 4; ++mt)
#pragma unroll
    for (int nt = 0; nt < 4; ++nt) acc[mt][nt] = (floatx4){0.f, 0.f, 0.f, 0.f};

  const _Float16* Ob = (const _Float16*)O16 + (size_t)(b * NN) * C;

  for (int k0 = 0; k0 < 256; k0 += 32) {
    half8 bf[4];
#pragma unroll
    for (int nt = 0; nt < 4; ++nt)
      bf[nt] = *(const half8*)(Ob + (size_t)(p0 + nt * 16 + col) * C + k0 + quad * 8);
#pragma unroll
    for (int mt = 0; mt < 4; ++mt) {
      const int crow = w * 64 + mt * 16 + col;
      const half8 af = *(const half8*)(owh + (size_t)crow * 256 + k0 + quad * 8);
#pragma unroll
      for (int nt = 0; nt < 4; ++nt)
        acc[mt][nt] = __builtin_amdgcn_mfma_f32_16x16x32_f16(af, bf[nt], acc[mt][nt], 0, 0, 0);
    }
  }

#pragma unroll
  for (int mt = 0; mt < 4; ++mt) {
    const int c0 = w * 64 + mt * 16 + quad * 4;
    const float4 b4 = *(const float4*)(ob + c0);
    const float bb[4] = {b4.x, b4.y, b4.z, b4.w};
#pragma unroll
    for (int nt = 0; nt < 4; ++nt) {
      const int px = p0 + nt * 16 + col;
#pragma unroll
      for (int r = 0; r < 4; ++r) {
        const size_t idx = ((size_t)(b * C) + c0 + r) * NN + px;
        o[idx] = acc[mt][nt][r] + bb[r] + x[idx];
      }
    }
  }
}

// ---------------------------------------------------------------------------
// 6. BN stats
// ---------------------------------------------------------------------------
__global__ __launch_bounds__(256) void stats_kernel(
    const float* __restrict__ o, float* __restrict__ stats)
{
  const int c = blockIdx.x, t = threadIdx.x;
  float s = 0.f, sq = 0.f;
  for (int b = 0; b < BB; ++b) {
    const float* p = o + ((size_t)b * C + c) * NN;
    for (int idx = t; idx < NN; idx += 256) {
      const float v = p[idx];
      s += v; sq += v * v;
    }
  }
#pragma unroll
  for (int off = 32; off >= 1; off >>= 1) {
    s += __shfl_xor(s, off);
    sq += __shfl_xor(sq, off);
  }
  __shared__ float red[8];
  const int wv = t >> 6;
  if ((t & 63) == 0) { red[wv] = s; red[4 + wv] = sq; }
  __syncthreads();
  if (t == 0) {
    s = red[0] + red[1] + red[2] + red[3];
    sq = red[4] + red[5] + red[6] + red[7];
    stats[c] = s;
    stats[C + c] = sq;
  }
}

// ---------------------------------------------------------------------------
// 7. BN normalize -> d_out
// ---------------------------------------------------------------------------
__global__ __launch_bounds__(256) void bn_kernel(
    const float* __restrict__ o, const float* __restrict__ stats,
    const float* __restrict__ g, const float* __restrict__ bta,
    float* __restrict__ out)
{
  const size_t idx = (size_t)blockIdx.x * 256 + threadIdx.x;
  const float inv_n = 1.f / (float)(BB * NN);
  float4 v = ((const float4*)o)[idx];
  const int c = (int)((idx * 4 / NN) % C);
  const float mean = stats[c] * inv_n;
  const float var = stats[C + c] * inv_n - mean * mean;
  const float sc = rsqrtf(var + 1e-5f) * g[c];
  const float sh = bta[c] - mean * sc;
  v.x = v.x * sc + sh; v.y = v.y * sc + sh;
  v.z = v.z * sc + sh; v.w = v.w * sc + sh;
  ((float4*)out)[idx] = v;
}

// ---------------------------------------------------------------------------
extern "C" void kernel_launch(void* const* d_in, const int* in_sizes, int n_in,
                              void* d_out, int out_size, void* d_ws, size_t ws_size,
                              hipStream_t stream)
{
  const float* x    = (const float*)d_in[0];
  const float* hn   = (const float*)d_in[1];
  const float* w1   = (const float*)d_in[2];  const float* b1   = (const float*)d_in[3];
  const float* w2   = (const float*)d_in[4];  const float* b2   = (const float*)d_in[5];
  const float* wadj = (const float*)d_in[6];  const float* badj = (const float*)d_in[7];
  const float* tw1  = (const float*)d_in[8];  const float* tb1  = (const float*)d_in[9];
  const float* tw2  = (const float*)d_in[10]; const float* tb2  = (const float*)d_in[11];
  const float* qaw  = (const float*)d_in[12]; const float* qab  = (const float*)d_in[13];
  const float* kaw  = (const float*)d_in[14]; const float* kab  = (const float*)d_in[15];
  const float* vaw  = (const float*)d_in[16]; const float* vab  = (const float*)d_in[17];
  const float* qtw  = (const float*)d_in[18]; const float* qtb  = (const float*)d_in[19];
  const float* ktw  = (const float*)d_in[20]; const float* ktb  = (const float*)d_in[21];
  const float* vtw  = (const float*)d_in[22]; const float* vtb  = (const float*)d_in[23];
  const float* ow   = (const float*)d_in[24]; const float* obias= (const float*)d_in[25];
  const float* bng  = (const float*)d_in[26]; const float* bnb  = (const float*)d_in[27];

  char* ws = (char*)d_ws;
  const size_t TENS  = (size_t)BB * C * NN * sizeof(float);        // 25,690,112
  const size_t HTENS = (size_t)BB * NN * C * sizeof(__half);       // 12,845,056
  const size_t PADT  = (size_t)BB * PW * PW * C * sizeof(_Float16) // 13,778,944
                       + 16384;                                    // OOB-read slack
  const size_t WT    = (size_t)9 * C * C * sizeof(_Float16);       // 1,179,648
  float*    a     = (float*)(ws);
  float*    tt    = (float*)(ws + TENS);
  _Float16* hnpad = (_Float16*)(ws + 2 * TENS);
  _Float16* t1pad = (_Float16*)(ws + 2 * TENS + PADT);
  _Float16* w1h   = (_Float16*)(ws + 2 * TENS + 2 * PADT);
  _Float16* w2h   = (_Float16*)(ws + 2 * TENS + 2 * PADT + WT);
  __half*   Q     = (__half*)(ws + 2 * TENS);            // aliases hnpad (dead)
  __half*   K     = (__half*)(ws + 2 * TENS + HTENS);
  __half*   Vt    = (__half*)(ws + 2 * TENS + 2 * HTENS);
  float*    stats = (float*)(ws + 2 * TENS + 3 * HTENS);
  _Float16* Whall = (_Float16*)(ws + 2 * TENS + 3 * HTENS + 4096); // 7*65536 fp16
  float*    w1T   = (float*)(ws + 2 * TENS + 3 * HTENS + 4096 + 7 * 65536 * 2);
  float*    wadjT = w1T + RR * C;                        // 2C*C fp32
  __half*   O16   = (__half*)a;    // a dead after qkv#1 reads it

  const int PIX_TILES = BB * NT;           // 1568
  const int CONV_BLKS = BB * HH * 2;       // 896
  const int FLASH_BLKS = BB * (NN / 64);   // 392 (4 waves x 16 q-rows each)
  const int QKV_BLKS = BB * (NN / 32);     // 784
  const int OUT_BLKS = BB * (NN / 64);     // 392

  wprep_kernel<<<9 * C * C / 256, 256, 0, stream>>>(tw1, tw2, w1h, w2h);
  wprep_qkv_kernel<<<7 * C * C / 256, 256, 0, stream>>>(
      qaw, kaw, vaw, qtw, ktw, vtw, ow, Whall);
  wprep_attr_kernel<<<(RR * C + 2 * C * C) / 256, 256, 0, stream>>>(
      w1, wadj, w1T, wadjT);
  padzero_kernel<<<2 * BB * PW, 256, 0, stream>>>(hnpad, t1pad);
  hnprep_kernel<<<PIX_TILES, 256, 0, stream>>>(hn, hnpad);
  attr_kernel<<<PIX_TILES, 256, 0, stream>>>(x, w1T, b1, w2, b2, wadjT, badj, a);
  conv_mfma_kernel<<<CONV_BLKS, 256, 0, stream>>>(hnpad, w1h, tb1, nullptr, t1pad, nullptr, 0);
  conv_mfma_kernel<<<CONV_BLKS, 256, 0, stream>>>(t1pad, w2h, tb2, a, nullptr, tt, 1);

  qkv_mfma_kernel<<<QKV_BLKS, 256, 0, stream>>>(a, Whall, qab, kab, vab, Q, K, Vt);
  flash8_kernel<<<FLASH_BLKS, 256, 0, stream>>>(Q, K, Vt, O16, 0);
  qkv_mfma_kernel<<<QKV_BLKS, 256, 0, stream>>>(tt, Whall + 3 * 65536, qtb, ktb, vtb, Q, K, Vt);
  flash8_kernel<<<FLASH_BLKS, 256, 0, stream>>>(Q, K, Vt, O16, 1);

  float* o = tt;      // tt dead after qkv#2
  outconv_mfma_kernel<<<OUT_BLKS, 256, 0, stream>>>(O16, Whall + 6 * 65536, obias, x, o);
  stats_kernel<<<C, 256, 0, stream>>>(o, stats);
  bn_kernel<<<(BB * C * NN / 4) / 256, 256, 0, stream>>>(o, stats, bng, bnb, (float*)d_out);
}

// Round 6
// 1441.642 us; speedup vs baseline: 1.3344x; 1.0433x over previous
//
#include <hip/hip_runtime.h>
#include <hip/hip_fp16.h>

#define BB 8
#define C 256
#define HH 56
#define WW 56
#define NN 3136      // HH*WW
#define RR 16
#define NT (NN/16)   // 196 pixel-tiles per image
#define PW 58        // padded spatial width/height

typedef _Float16 half8 __attribute__((ext_vector_type(8)));
typedef _Float16 half4v __attribute__((ext_vector_type(4)));
typedef float floatx4 __attribute__((ext_vector_type(4)));

#define AS1 __attribute__((address_space(1)))
#define AS3 __attribute__((address_space(3)))

// async 16B global->LDS DMA (no VGPR staging, wave-uniform LDS base + lane*16)
__device__ __forceinline__ void gload16(const _Float16* gsrc, _Float16* ldst) {
  __builtin_amdgcn_global_load_lds((const AS1 unsigned int*)(const void*)gsrc,
                                   (AS3 unsigned int*)(void*)ldst, 16, 0, 0);
}

// ---------------------------------------------------------------------------
// 1. attr branch fused: a = adj( concat( relu(W2 relu(W1 x)), x ) )
//    Transposed fp32 weights (w1T[c][r], wadjT[k][o]) -> coalesced reads.
// ---------------------------------------------------------------------------
__global__ __launch_bounds__(256) void attr_kernel(
    const float* __restrict__ x,
    const float* __restrict__ w1T, const float* __restrict__ b1,
    const float* __restrict__ w2, const float* __restrict__ b2,
    const float* __restrict__ wadjT, const float* __restrict__ badj,
    float* __restrict__ a_out)
{
  __shared__ float xs[C][20];
  __shared__ float a2s[C][20];
  __shared__ float a1s[RR][20];
  const int tile = blockIdx.x;
  const int b = tile / NT;
  const int p0 = (tile % NT) * 16;
  const int t = threadIdx.x;

  {
    const float* xb = x + ((size_t)b * C + t) * NN + p0;
    const float4* xb4 = (const float4*)xb;
    float* row = xs[t];
#pragma unroll
    for (int g = 0; g < 4; ++g) {
      float4 v = xb4[g];
      row[g * 4 + 0] = v.x; row[g * 4 + 1] = v.y;
      row[g * 4 + 2] = v.z; row[g * 4 + 3] = v.w;
    }
  }
  __syncthreads();

  {
    const int r = t & 15, pp = t >> 4;
    float acc = b1[r];
    for (int c = 0; c < C; ++c) acc += w1T[c * 16 + r] * xs[c][pp];
    a1s[r][pp] = fmaxf(acc, 0.f);
  }
  __syncthreads();

  {
    const int o = t;
    float acc[16];
    const float bias = b2[o];
#pragma unroll
    for (int p = 0; p < 16; ++p) acc[p] = bias;
    const float* wr = w2 + o * RR;
    for (int k = 0; k < RR; ++k) {
      const float w = wr[k];
#pragma unroll
      for (int p = 0; p < 16; ++p) acc[p] += w * a1s[k][p];
    }
    float* row = a2s[o];
#pragma unroll
    for (int p = 0; p < 16; ++p) row[p] = fmaxf(acc[p], 0.f);
  }
  __syncthreads();

  {
    const int o = t;
    float acc[16];
    const float bias = badj[o];
#pragma unroll
    for (int p = 0; p < 16; ++p) acc[p] = bias;
    const float* wTa = wadjT + o;            // wadjT[k][o], k in [0,256)
    for (int k = 0; k < C; ++k) {
      const float w = wTa[k * C];
      const float4* ar = (const float4*)a2s[k];
#pragma unroll
      for (int g = 0; g < 4; ++g) {
        float4 v = ar[g];
        acc[g * 4 + 0] += w * v.x; acc[g * 4 + 1] += w * v.y;
        acc[g * 4 + 2] += w * v.z; acc[g * 4 + 3] += w * v.w;
      }
    }
    const float* wTx = wadjT + C * C + o;    // wadjT[256+k][o]
    for (int k = 0; k < C; ++k) {
      const float w = wTx[k * C];
      const float4* xr = (const float4*)xs[k];
#pragma unroll
      for (int g = 0; g < 4; ++g) {
        float4 v = xr[g];
        acc[g * 4 + 0] += w * v.x; acc[g * 4 + 1] += w * v.y;
        acc[g * 4 + 2] += w * v.z; acc[g * 4 + 3] += w * v.w;
      }
    }
    float* op = a_out + ((size_t)b * C + o) * NN + p0;
    float4* op4 = (float4*)op;
#pragma unroll
    for (int g = 0; g < 4; ++g)
      op4[g] = make_float4(acc[g * 4 + 0], acc[g * 4 + 1], acc[g * 4 + 2], acc[g * 4 + 3]);
  }
}

// ---------------------------------------------------------------------------
// 1b. attr weight transposes (fp32)
// ---------------------------------------------------------------------------
__global__ __launch_bounds__(256) void wprep_attr_kernel(
    const float* __restrict__ w1, const float* __restrict__ wadj,
    float* __restrict__ w1T, float* __restrict__ wadjT)
{
  const int i = blockIdx.x * 256 + threadIdx.x;   // 528*256 = 135,168
  if (i < RR * C) {
    const int c = i >> 4, r = i & 15;
    w1T[i] = w1[r * C + c];
  } else {
    const int j = i - RR * C;                     // 2C*C entries
    const int k = j >> 8, o = j & 255;
    wadjT[j] = wadj[(size_t)o * (2 * C) + k];
  }
}

// ---------------------------------------------------------------------------
// 2a. conv weight prep
// ---------------------------------------------------------------------------
__global__ __launch_bounds__(256) void wprep_kernel(
    const float* __restrict__ tw1, const float* __restrict__ tw2,
    _Float16* __restrict__ w1h, _Float16* __restrict__ w2h)
{
  const int i = blockIdx.x * 256 + threadIdx.x;   // over 9*256*256
  const int tap = i >> 16;
  const int rem = i & 65535;
  const int o = rem >> 8;
  const int c = rem & 255;
  w1h[i] = (_Float16)tw1[((size_t)o * C + c) * 9 + tap];
  w2h[i] = (_Float16)tw2[((size_t)o * C + c) * 9 + (8 - tap)];
}

// ---------------------------------------------------------------------------
// 2a'. 1x1 weight prep: 7 C*C fp32 -> fp16 [o][c].  Order: qa,ka,va,qt,kt,vt,ow
// ---------------------------------------------------------------------------
__global__ __launch_bounds__(256) void wprep_qkv_kernel(
    const float* __restrict__ m0, const float* __restrict__ m1,
    const float* __restrict__ m2, const float* __restrict__ m3,
    const float* __restrict__ m4, const float* __restrict__ m5,
    const float* __restrict__ m6, _Float16* __restrict__ Whall)
{
  const int i = blockIdx.x * 256 + threadIdx.x;   // over 7*65536
  const int mat = i >> 16, rem = i & 65535;
  const float* s;
  switch (mat) {
    case 0: s = m0; break; case 1: s = m1; break; case 2: s = m2; break;
    case 3: s = m3; break; case 4: s = m4; break; case 5: s = m5; break;
    default: s = m6; break;
  }
  Whall[i] = (_Float16)s[rem];
}

// ---------------------------------------------------------------------------
// 2b. zero the pad border of both padded-NHWC fp16 buffers
// ---------------------------------------------------------------------------
__global__ __launch_bounds__(256) void padzero_kernel(
    _Float16* __restrict__ buf1, _Float16* __restrict__ buf2)
{
  const int bid = blockIdx.x;                 // 2 * BB * PW
  _Float16* buf = (bid < BB * PW) ? buf1 : buf2;
  const int rb = bid % (BB * PW);
  const int b = rb / PW, r = rb % PW;
  _Float16* row = buf + ((size_t)b * PW + r) * PW * C;
  const float4 z = make_float4(0.f, 0.f, 0.f, 0.f);
  if (r == 0 || r == PW - 1) {
    for (int i = threadIdx.x; i < PW * C / 8; i += 256) ((float4*)row)[i] = z;
  } else {
    const int i = threadIdx.x;
    if (i < 32) ((float4*)row)[i] = z;                       // col 0
    else if (i < 64) ((float4*)(row + (PW - 1) * C))[i - 32] = z;  // col 57
  }
}

// ---------------------------------------------------------------------------
// 2c. hn (fp32 NCHW) -> hnpad (fp16 padded NHWC) interior, via LDS transpose
// ---------------------------------------------------------------------------
__global__ __launch_bounds__(256) void hnprep_kernel(
    const float* __restrict__ hn, _Float16* __restrict__ hnpad)
{
  __shared__ float xs[C][17];
  const int tile = blockIdx.x;
  const int b = tile / NT;
  const int p0 = (tile % NT) * 16;
  const int t = threadIdx.x;
  {
    const float4* sb = (const float4*)(hn + ((size_t)b * C + t) * NN + p0);
    float* row = xs[t];
#pragma unroll
    for (int g = 0; g < 4; ++g) {
      float4 v = sb[g];
      row[g * 4 + 0] = v.x; row[g * 4 + 1] = v.y;
      row[g * 4 + 2] = v.z; row[g * 4 + 3] = v.w;
    }
  }
  __syncthreads();
  const int p = t >> 4, c0 = (t & 15) * 16;
  const int pg = p0 + p;
  const int h = pg / WW, w = pg % WW;
  __align__(16) _Float16 tmp[16];
#pragma unroll
  for (int j = 0; j < 16; ++j) tmp[j] = (_Float16)xs[c0 + j][p];
  _Float16* dst = hnpad + (((size_t)b * PW + h + 1) * PW + w + 1) * C + c0;
  ((uint4*)dst)[0] = ((uint4*)tmp)[0];
  ((uint4*)dst)[1] = ((uint4*)tmp)[1];
}

// ---------------------------------------------------------------------------
// 2d. conv3x3 as 9-tap MFMA GEMM.  XCD-swizzled (b = bid & 7).
// ---------------------------------------------------------------------------
__global__ __launch_bounds__(256) void conv_mfma_kernel(
    const _Float16* __restrict__ inpad, const _Float16* __restrict__ wh,
    const float* __restrict__ bias, const float* __restrict__ amul,
    _Float16* __restrict__ out_h, float* __restrict__ out_f, int mode)
{
  const int bid = blockIdx.x;          // BB*56*2
  const int b = bid & 7;               // XCD-aligned batch
  const int rest = bid >> 3;           // 0..111
  const int ohalf = rest & 1;
  const int h = rest >> 1;
  const int t = threadIdx.x;
  const int wave = t >> 6, lane = t & 63;
  const int col = lane & 15, quad = lane >> 4;
  const int o_base = ohalf * 128 + wave * 32;

  floatx4 acc[2][4];
#pragma unroll
  for (int mt = 0; mt < 2; ++mt)
#pragma unroll
    for (int nt = 0; nt < 4; ++nt) acc[mt][nt] = (floatx4){0.f, 0.f, 0.f, 0.f};

  const _Float16* inb = inpad + (size_t)b * PW * PW * C;

  for (int tap = 0; tap < 9; ++tap) {
    const int dy = tap / 3;
    const int dx = tap - dy * 3;
    const _Float16* wtap = wh + (size_t)tap * C * C + quad * 8;
    const _Float16* inrow = inb + ((size_t)(h + dy) * PW + dx + col) * C + quad * 8;
    for (int kc = 0; kc < 8; ++kc) {
      const int c0 = kc * 32;
      const half8 A0 = *(const half8*)(wtap + (size_t)(o_base + col) * C + c0);
      const half8 A1 = *(const half8*)(wtap + (size_t)(o_base + 16 + col) * C + c0);
#pragma unroll
      for (int nt = 0; nt < 4; ++nt) {
        const half8 Bv = *(const half8*)(inrow + (size_t)(nt * 16) * C + c0);
        acc[0][nt] = __builtin_amdgcn_mfma_f32_16x16x32_f16(A0, Bv, acc[0][nt], 0, 0, 0);
        acc[1][nt] = __builtin_amdgcn_mfma_f32_16x16x32_f16(A1, Bv, acc[1][nt], 0, 0, 0);
      }
    }
  }

#pragma unroll
  for (int mt = 0; mt < 2; ++mt) {
    const int o = o_base + mt * 16 + quad * 4;
    const float* bp = bias + o;
    const float b0 = bp[0], b1_ = bp[1], b2_ = bp[2], b3 = bp[3];
    if (mode == 0) {
#pragma unroll
      for (int nt = 0; nt < 4; ++nt) {
        const int wpx = nt * 16 + col;
        if (wpx < WW) {
          __align__(8) _Float16 hv[4];
          hv[0] = (_Float16)fmaxf(acc[mt][nt][0] + b0, 0.f);
          hv[1] = (_Float16)fmaxf(acc[mt][nt][1] + b1_, 0.f);
          hv[2] = (_Float16)fmaxf(acc[mt][nt][2] + b2_, 0.f);
          hv[3] = (_Float16)fmaxf(acc[mt][nt][3] + b3, 0.f);
          _Float16* dst = out_h + (((size_t)b * PW + h + 1) * PW + wpx + 1) * C + o;
          *(uint2*)dst = *(uint2*)hv;
        }
      }
    } else {
#pragma unroll
      for (int nt = 0; nt < 4; ++nt) {
        const int wpx = nt * 16 + col;
        if (wpx < WW) {
          const int p = h * WW + wpx;
          const float bb[4] = {b0, b1_, b2_, b3};
#pragma unroll
          for (int r = 0; r < 4; ++r) {
            const size_t idx = ((size_t)(b * C + o + r)) * NN + p;
            out_f[idx] = (acc[mt][nt][r] + bb[r]) * amul[idx];
          }
        }
      }
    }
  }
}

// ---------------------------------------------------------------------------
// helper: 16B MFMA fragment from LDS as two ds_read_b64 (8B-aligned layouts)
// ---------------------------------------------------------------------------
__device__ inline half8 ld_frag(const _Float16* p) {
  union { half8 h8; half4v h4[2]; } u;
  u.h4[0] = *(const half4v*)p;
  u.h4[1] = *(const half4v*)(p + 4);
  return u.h8;
}

// ---------------------------------------------------------------------------
// 3. qkv as MFMA GEMM.  A = fp16 weights [s][o][c], B = src tile staged in
//    LDS as fp16 [px][ch], one pass for Q,K,V.
// ---------------------------------------------------------------------------
__global__ __launch_bounds__(256) void qkv_mfma_kernel(
    const float* __restrict__ src, const _Float16* __restrict__ Wh,
    const float* __restrict__ bq, const float* __restrict__ bk,
    const float* __restrict__ bv,
    __half* __restrict__ Q, __half* __restrict__ K, __half* __restrict__ Vt)
{
  __shared__ _Float16 Ss[32][264];     // [px][ch]  16,896 B
  const int bid = blockIdx.x;          // 784
  const int b = bid & 7;
  const int p0 = (bid >> 3) * 32;
  const int t = threadIdx.x;
  const int w = t >> 6, lane = t & 63;
  const int col = lane & 15, quad = lane >> 4;

  // stage src tile: fp32 [C][N] -> fp16 LDS [px][ch] (thread t = channel t)
  {
    const float4* sp = (const float4*)(src + ((size_t)b * C + t) * NN + p0);
    float v[32];
#pragma unroll
    for (int g = 0; g < 8; ++g) {
      const float4 f = sp[g];
      v[g * 4 + 0] = f.x; v[g * 4 + 1] = f.y;
      v[g * 4 + 2] = f.z; v[g * 4 + 3] = f.w;
    }
#pragma unroll
    for (int px = 0; px < 32; ++px) Ss[px][t] = (_Float16)v[px];
  }
  __syncthreads();

  floatx4 acc[12][2];
#pragma unroll
  for (int i = 0; i < 12; ++i)
#pragma unroll
    for (int nt = 0; nt < 2; ++nt) acc[i][nt] = (floatx4){0.f, 0.f, 0.f, 0.f};

  for (int k0 = 0; k0 < 256; k0 += 32) {
    half8 bf[2];
    bf[0] = ld_frag(&Ss[col][k0 + quad * 8]);
    bf[1] = ld_frag(&Ss[16 + col][k0 + quad * 8]);
#pragma unroll
    for (int i = 0; i < 12; ++i) {
      const int mtg = w * 12 + i;      // 0..47: [0,16)=Q, [16,32)=K, [32,48)=V
      const half8 af = *(const half8*)(Wh + (size_t)mtg * 4096 + col * 256 + k0 + quad * 8);
      acc[i][0] = __builtin_amdgcn_mfma_f32_16x16x32_f16(af, bf[0], acc[i][0], 0, 0, 0);
      acc[i][1] = __builtin_amdgcn_mfma_f32_16x16x32_f16(af, bf[1], acc[i][1], 0, 0, 0);
    }
  }

#pragma unroll
  for (int i = 0; i < 12; ++i) {
    const int mtg = w * 12 + i;
    const int s = mtg >> 4;
    const int crow = (mtg & 15) * 16 + quad * 4;    // c_out base of this lane
    const float* bp = (s == 0 ? bq : (s == 1 ? bk : bv)) + crow;
    const float4 b4 = *(const float4*)bp;
    const float bb[4] = {b4.x, b4.y, b4.z, b4.w};
#pragma unroll
    for (int nt = 0; nt < 2; ++nt) {
      const int px = p0 + nt * 16 + col;
      if (s == 2) {
#pragma unroll
        for (int r = 0; r < 4; ++r)
          Vt[((size_t)(b * C) + crow + r) * NN + px] =
              __float2half((acc[i][nt][r] + bb[r]) * 0.5f);
      } else {
        __half* dst = (s == 0 ? Q : K) + ((size_t)(b * NN) + px) * C + crow;
        __align__(8) __half hv[4];
#pragma unroll
        for (int r = 0; r < 4; ++r) hv[r] = __float2half(acc[i][nt][r] + bb[r]);
        *(uint2*)dst = *(uint2*)hv;
      }
    }
  }
}

// ---------------------------------------------------------------------------
// 4. Flash v9: 32 q-rows/wave + double-buffered DMA staging.
//    R5 post-mortem: flash8 was bound by LDS operand bandwidth (every wave
//    re-read the full 64KB K+V tile per iter -> 256KB/block/iter at ~85B/cyc)
//    plus a fully serial stage (issue->vmcnt0->barrier, no overlap).
//    Now: each wave owns 2 m-tiles (32 q-rows) so every K/V B-fragment feeds
//    2 MFMAs (same LDS bytes, 2x FLOP); K/V double-buffered (150.5KB LDS,
//    1 block/CU) with next-tile global_load_lds issued before compute and
//    drained after -> stage hides under compute.  QBLK=128, grid 200.
//    Last q-tile has 64 valid rows: waves 2,3 compute garbage (safe OOB
//    within workspace), wave-uniform guard skips their stores.
// ---------------------------------------------------------------------------
__global__ __launch_bounds__(256) void flash9_kernel(
    const __half* __restrict__ Qg, const __half* __restrict__ Kg,
    const __half* __restrict__ Vtg, __half* __restrict__ O16, int accumulate)
{
  __shared__ _Float16 Ks[2][64 * 256];   // [buf][key][ch] linear  65,536 B
  __shared__ _Float16 Vs[2][256 * 64];   // [buf][ch][key] linear  65,536 B
  __shared__ _Float16 Pb[4][32][76];     // per-wave P             19,456 B

  const int bid = blockIdx.x;            // 8 * 25 = 200
  const int b = bid & 7;                 // XCD-aligned batch
  const int q0 = (bid >> 3) * 128;       // 25 q-tiles of 128 rows
  const int t = threadIdx.x;             // 0..255
  const int w = t >> 6;                  // wave 0..3
  const int lane = t & 63;
  const int col = lane & 15;
  const int quad = lane >> 4;
  const bool valid = (q0 + w * 32) < NN; // wave-uniform store guard

  const _Float16* Kb = (const _Float16*)Kg + (size_t)(b * NN) * C;
  const _Float16* Vb = (const _Float16*)Vtg + (size_t)(b * C) * NN;

  // Q fragments: 2 m-tiles x 16 rows (held in regs for all 49 iters)
  half8 Qf[2][8];
#pragma unroll
  for (int mt = 0; mt < 2; ++mt) {
    const _Float16* Qp = (const _Float16*)Qg +
        ((size_t)(b * NN) + q0 + w * 32 + mt * 16 + col) * C + quad * 8;
#pragma unroll
    for (int s = 0; s < 8; ++s) Qf[mt][s] = *(const half8*)(Qp + s * 32);
  }

  floatx4 Ov[2][16];
#pragma unroll
  for (int mt = 0; mt < 2; ++mt)
#pragma unroll
    for (int n = 0; n < 16; ++n) Ov[mt][n] = (floatx4){0.f, 0.f, 0.f, 0.f};
  float m[2][4], l[2][4];
#pragma unroll
  for (int mt = 0; mt < 2; ++mt)
#pragma unroll
    for (int r = 0; r < 4; ++r) { m[mt][r] = -1e30f; l[mt][r] = 0.f; }

  // ---- DMA stage of one K/V tile into buffer `buf` (T21 swizzle) ----------
  auto stage = [&](int buf, int key0) {
#pragma unroll
    for (int i = 0; i < 8; ++i) {
      const int c = w * 512 + i * 64 + lane;
      const int krow = c >> 5, kcir = c & 31;
      gload16(Kb + (size_t)(key0 + krow) * C + ((kcir ^ (krow & 7)) * 8),
              &Ks[buf][(size_t)(w * 512 + i * 64) * 8]);
    }
#pragma unroll
    for (int i = 0; i < 8; ++i) {
      const int c = w * 512 + i * 64 + lane;
      const int vch = c >> 3, vcir = c & 7;
      gload16(Vb + (size_t)vch * NN + key0 + ((vcir ^ (vch & 7)) * 8),
              &Vs[buf][(size_t)(w * 512 + i * 64) * 8]);
    }
  };

  // prologue: stage tile 0 into buf 0
  stage(0, 0);
  asm volatile("s_waitcnt vmcnt(0)" ::: "memory");
  __syncthreads();

  for (int kb = 0; kb < 49; ++kb) {
    const int cur = kb & 1;
    if (kb + 1 < 49) stage(cur ^ 1, (kb + 1) * 64);   // overlap with compute

    const _Float16* Kc = Ks[cur];
    const _Float16* Vc = Vs[cur];

    // ---- S = Q K^T * scale, 2x(16q) x 64k (K from LDS, swizzled read) -----
    floatx4 Sv[2][4];
#pragma unroll
    for (int nt = 0; nt < 4; ++nt) {
      const int krow = nt * 16 + col;
      const char* kbase = (const char*)Kc + krow * 512;
      const int kx = (krow & 7) << 4;
      floatx4 a0 = (floatx4){0.f, 0.f, 0.f, 0.f};
      floatx4 a1 = (floatx4){0.f, 0.f, 0.f, 0.f};
#pragma unroll
      for (int s = 0; s < 8; ++s) {
        const half8 bf = *(const half8*)(kbase + ((s * 64 + quad * 16) ^ kx));
        a0 = __builtin_amdgcn_mfma_f32_16x16x32_f16(Qf[0][s], bf, a0, 0, 0, 0);
        a1 = __builtin_amdgcn_mfma_f32_16x16x32_f16(Qf[1][s], bf, a1, 0, 0, 0);
      }
      Sv[0][nt] = a0 * 0.0625f;   // 1/sqrt(256)
      Sv[1][nt] = a1 * 0.0625f;
    }

    // ---- online softmax (per m-tile) --------------------------------------
#pragma unroll
    for (int mt = 0; mt < 2; ++mt) {
      float f[4];
      bool grow = false;
#pragma unroll
      for (int r = 0; r < 4; ++r) {
        float v = fmaxf(fmaxf(Sv[mt][0][r], Sv[mt][1][r]),
                        fmaxf(Sv[mt][2][r], Sv[mt][3][r]));
        v = fmaxf(v, __shfl_xor(v, 1));
        v = fmaxf(v, __shfl_xor(v, 2));
        v = fmaxf(v, __shfl_xor(v, 4));
        v = fmaxf(v, __shfl_xor(v, 8));
        const float mn = fmaxf(m[mt][r], v);
        f[r] = __expf(m[mt][r] - mn);
        grow = grow || (v > m[mt][r]);
        m[mt][r] = mn;
      }
      float rowsum[4] = {0.f, 0.f, 0.f, 0.f};
#pragma unroll
      for (int nt = 0; nt < 4; ++nt) {
#pragma unroll
        for (int r = 0; r < 4; ++r) {
          const float p = __expf(Sv[mt][nt][r] - m[mt][r]);
          Sv[mt][nt][r] = p;
          rowsum[r] += p;
        }
      }
#pragma unroll
      for (int r = 0; r < 4; ++r) {
        float s = rowsum[r];
        s += __shfl_xor(s, 1);
        s += __shfl_xor(s, 2);
        s += __shfl_xor(s, 4);
        s += __shfl_xor(s, 8);
        l[mt][r] = l[mt][r] * f[r] + s;
      }

      // P -> per-wave LDS scratch (acc layout)
#pragma unroll
      for (int nt = 0; nt < 4; ++nt)
#pragma unroll
        for (int r = 0; r < 4; ++r)
          Pb[w][mt * 16 + quad * 4 + r][nt * 16 + col] = (_Float16)Sv[mt][nt][r];

      if (__any(grow)) {        // T13: skip rescale when max did not grow
        const floatx4 fv = {f[0], f[1], f[2], f[3]};
#pragma unroll
        for (int n = 0; n < 16; ++n) Ov[mt][n] *= fv;
      }
    }

    // P A-fragments: [mt][ks]  (ks = key slice of 32)
    half8 pa[2][2];
#pragma unroll
    for (int mt = 0; mt < 2; ++mt) {
      pa[mt][0] = ld_frag(&Pb[w][mt * 16 + col][quad * 8]);
      pa[mt][1] = ld_frag(&Pb[w][mt * 16 + col][32 + quad * 8]);
    }

    // ---- O += P V  (V from LDS, swizzled read; each B feeds both m-tiles) -
#pragma unroll
    for (int nt2 = 0; nt2 < 16; ++nt2) {
      const int vrow = nt2 * 16 + col;
      const char* vbase = (const char*)Vc + vrow * 128;
      const int vx = (vrow & 7) << 4;
      const half8 bv0 = *(const half8*)(vbase + ((quad * 16) ^ vx));
      const half8 bv1 = *(const half8*)(vbase + ((64 + quad * 16) ^ vx));
      Ov[0][nt2] = __builtin_amdgcn_mfma_f32_16x16x32_f16(pa[0][0], bv0, Ov[0][nt2], 0, 0, 0);
      Ov[0][nt2] = __builtin_amdgcn_mfma_f32_16x16x32_f16(pa[0][1], bv1, Ov[0][nt2], 0, 0, 0);
      Ov[1][nt2] = __builtin_amdgcn_mfma_f32_16x16x32_f16(pa[1][0], bv0, Ov[1][nt2], 0, 0, 0);
      Ov[1][nt2] = __builtin_amdgcn_mfma_f32_16x16x32_f16(pa[1][1], bv1, Ov[1][nt2], 0, 0, 0);
    }

    asm volatile("s_waitcnt vmcnt(0)" ::: "memory");  // next tile landed
    __syncthreads();                                   // visible to all waves
  }

  if (valid) {
#pragma unroll
    for (int mt = 0; mt < 2; ++mt) {
      float inv[4];
#pragma unroll
      for (int r = 0; r < 4; ++r) inv[r] = 1.f / l[mt][r];
#pragma unroll
      for (int nt2 = 0; nt2 < 16; ++nt2) {
#pragma unroll
        for (int r = 0; r < 4; ++r) {
          const float val = Ov[mt][nt2][r] * inv[r];
          __half* dst = O16 + ((size_t)(b * NN) + q0 + w * 32 + mt * 16 +
                               quad * 4 + r) * C + nt2 * 16 + col;
          if (accumulate) *dst = __float2half(val + __half2float(*dst));
          else *dst = __float2half(val);
        }
      }
    }
  }
}

// ---------------------------------------------------------------------------
// 5. out 1x1 conv + residual as MFMA GEMM.
// ---------------------------------------------------------------------------
__global__ __launch_bounds__(256) void outconv_mfma_kernel(
    const __half* __restrict__ O16, const _Float16* __restrict__ owh,
    const float* __restrict__ ob, const float* __restrict__ x,
    float* __restrict__ o)
{
  const int bid = blockIdx.x;          // 392
  const int b = bid & 7;
  const int p0 = (bid >> 3) * 64;
  const int t = threadIdx.x;
  const int w = t >> 6, lane = t & 63;
  const int col = lane & 15, quad = lane >> 4;

  floatx4 acc[4][4];
#pragma unroll
  for (int mt = 0; mt < 4; ++mt)
#pragma unroll
    for (int nt = 0; nt < 4; ++nt) acc[mt][nt] = (floatx4){0.f, 0.f, 0.f, 0.f};

  const _Float16* Ob = (const _Float16*)O16 + (size_t)(b * NN) * C;

  for (int k0 = 0; k0 < 256; k0 += 32) {
    half8 bf[4];
#pragma unroll
    for (int nt = 0; nt < 4; ++nt)
      bf[nt] = *(const half8*)(Ob + (size_t)(p0 + nt * 16 + col) * C + k0 + quad * 8);
#pragma unroll
    for (int mt = 0; mt < 4; ++mt) {
      const int crow = w * 64 + mt * 16 + col;
      const half8 af = *(const half8*)(owh + (size_t)crow * 256 + k0 + quad * 8);
#pragma unroll
      for (int nt = 0; nt < 4; ++nt)
        acc[mt][nt] = __builtin_amdgcn_mfma_f32_16x16x32_f16(af, bf[nt], acc[mt][nt], 0, 0, 0);
    }
  }

#pragma unroll
  for (int mt = 0; mt < 4; ++mt) {
    const int c0 = w * 64 + mt * 16 + quad * 4;
    const float4 b4 = *(const float4*)(ob + c0);
    const float bb[4] = {b4.x, b4.y, b4.z, b4.w};
#pragma unroll
    for (int nt = 0; nt < 4; ++nt) {
      const int px = p0 + nt * 16 + col;
#pragma unroll
      for (int r = 0; r < 4; ++r) {
        const size_t idx = ((size_t)(b * C) + c0 + r) * NN + px;
        o[idx] = acc[mt][nt][r] + bb[r] + x[idx];
      }
    }
  }
}

// ---------------------------------------------------------------------------
// 6. BN stats
// ---------------------------------------------------------------------------
__global__ __launch_bounds__(256) void stats_kernel(
    const float* __restrict__ o, float* __restrict__ stats)
{
  const int c = blockIdx.x, t = threadIdx.x;
  float s = 0.f, sq = 0.f;
  for (int b = 0; b < BB; ++b) {
    const float* p = o + ((size_t)b * C + c) * NN;
    for (int idx = t; idx < NN; idx += 256) {
      const float v = p[idx];
      s += v; sq += v * v;
    }
  }
#pragma unroll
  for (int off = 32; off >= 1; off >>= 1) {
    s += __shfl_xor(s, off);
    sq += __shfl_xor(sq, off);
  }
  __shared__ float red[8];
  const int wv = t >> 6;
  if ((t & 63) == 0) { red[wv] = s; red[4 + wv] = sq; }
  __syncthreads();
  if (t == 0) {
    s = red[0] + red[1] + red[2] + red[3];
    sq = red[4] + red[5] + red[6] + red[7];
    stats[c] = s;
    stats[C + c] = sq;
  }
}

// ---------------------------------------------------------------------------
// 7. BN normalize -> d_out
// ---------------------------------------------------------------------------
__global__ __launch_bounds__(256) void bn_kernel(
    const float* __restrict__ o, const float* __restrict__ stats,
    const float* __restrict__ g, const float* __restrict__ bta,
    float* __restrict__ out)
{
  const size_t idx = (size_t)blockIdx.x * 256 + threadIdx.x;
  const float inv_n = 1.f / (float)(BB * NN);
  float4 v = ((const float4*)o)[idx];
  const int c = (int)((idx * 4 / NN) % C);
  const float mean = stats[c] * inv_n;
  const float var = stats[C + c] * inv_n - mean * mean;
  const float sc = rsqrtf(var + 1e-5f) * g[c];
  const float sh = bta[c] - mean * sc;
  v.x = v.x * sc + sh; v.y = v.y * sc + sh;
  v.z = v.z * sc + sh; v.w = v.w * sc + sh;
  ((float4*)out)[idx] = v;
}

// ---------------------------------------------------------------------------
extern "C" void kernel_launch(void* const* d_in, const int* in_sizes, int n_in,
                              void* d_out, int out_size, void* d_ws, size_t ws_size,
                              hipStream_t stream)
{
  const float* x    = (const float*)d_in[0];
  const float* hn   = (const float*)d_in[1];
  const float* w1   = (const float*)d_in[2];  const float* b1   = (const float*)d_in[3];
  const float* w2   = (const float*)d_in[4];  const float* b2   = (const float*)d_in[5];
  const float* wadj = (const float*)d_in[6];  const float* badj = (const float*)d_in[7];
  const float* tw1  = (const float*)d_in[8];  const float* tb1  = (const float*)d_in[9];
  const float* tw2  = (const float*)d_in[10]; const float* tb2  = (const float*)d_in[11];
  const float* qaw  = (const float*)d_in[12]; const float* qab  = (const float*)d_in[13];
  const float* kaw  = (const float*)d_in[14]; const float* kab  = (const float*)d_in[15];
  const float* vaw  = (const float*)d_in[16]; const float* vab  = (const float*)d_in[17];
  const float* qtw  = (const float*)d_in[18]; const float* qtb  = (const float*)d_in[19];
  const float* ktw  = (const float*)d_in[20]; const float* ktb  = (const float*)d_in[21];
  const float* vtw  = (const float*)d_in[22]; const float* vtb  = (const float*)d_in[23];
  const float* ow   = (const float*)d_in[24]; const float* obias= (const float*)d_in[25];
  const float* bng  = (const float*)d_in[26]; const float* bnb  = (const float*)d_in[27];

  char* ws = (char*)d_ws;
  const size_t TENS  = (size_t)BB * C * NN * sizeof(float);        // 25,690,112
  const size_t HTENS = (size_t)BB * NN * C * sizeof(__half);       // 12,845,056
  const size_t PADT  = (size_t)BB * PW * PW * C * sizeof(_Float16) // 13,778,944
                       + 16384;                                    // OOB-read slack
  const size_t WT    = (size_t)9 * C * C * sizeof(_Float16);       // 1,179,648
  float*    a     = (float*)(ws);
  float*    tt    = (float*)(ws + TENS);
  _Float16* hnpad = (_Float16*)(ws + 2 * TENS);
  _Float16* t1pad = (_Float16*)(ws + 2 * TENS + PADT);
  _Float16* w1h   = (_Float16*)(ws + 2 * TENS + 2 * PADT);
  _Float16* w2h   = (_Float16*)(ws + 2 * TENS + 2 * PADT + WT);
  __half*   Q     = (__half*)(ws + 2 * TENS);            // aliases hnpad (dead)
  __half*   K     = (__half*)(ws + 2 * TENS + HTENS);
  __half*   Vt    = (__half*)(ws + 2 * TENS + 2 * HTENS);
  float*    stats = (float*)(ws + 2 * TENS + 3 * HTENS);
  _Float16* Whall = (_Float16*)(ws + 2 * TENS + 3 * HTENS + 4096); // 7*65536 fp16
  float*    w1T   = (float*)(ws + 2 * TENS + 3 * HTENS + 4096 + 7 * 65536 * 2);
  float*    wadjT = w1T + RR * C;                        // 2C*C fp32
  __half*   O16   = (__half*)a;    // a dead after qkv#1 reads it

  const int PIX_TILES = BB * NT;           // 1568
  const int CONV_BLKS = BB * HH * 2;       // 896
  const int FLASH_BLKS = BB * 25;          // 200 (4 waves x 32 q-rows, QBLK=128)
  const int QKV_BLKS = BB * (NN / 32);     // 784
  const int OUT_BLKS = BB * (NN / 64);     // 392

  wprep_kernel<<<9 * C * C / 256, 256, 0, stream>>>(tw1, tw2, w1h, w2h);
  wprep_qkv_kernel<<<7 * C * C / 256, 256, 0, stream>>>(
      qaw, kaw, vaw, qtw, ktw, vtw, ow, Whall);
  wprep_attr_kernel<<<(RR * C + 2 * C * C) / 256, 256, 0, stream>>>(
      w1, wadj, w1T, wadjT);
  padzero_kernel<<<2 * BB * PW, 256, 0, stream>>>(hnpad, t1pad);
  hnprep_kernel<<<PIX_TILES, 256, 0, stream>>>(hn, hnpad);
  attr_kernel<<<PIX_TILES, 256, 0, stream>>>(x, w1T, b1, w2, b2, wadjT, badj, a);
  conv_mfma_kernel<<<CONV_BLKS, 256, 0, stream>>>(hnpad, w1h, tb1, nullptr, t1pad, nullptr, 0);
  conv_mfma_kernel<<<CONV_BLKS, 256, 0, stream>>>(t1pad, w2h, tb2, a, nullptr, tt, 1);

  qkv_mfma_kernel<<<QKV_BLKS, 256, 0, stream>>>(a, Whall, qab, kab, vab, Q, K, Vt);
  flash9_kernel<<<FLASH_BLKS, 256, 0, stream>>>(Q, K, Vt, O16, 0);
  qkv_mfma_kernel<<<QKV_BLKS, 256, 0, stream>>>(tt, Whall + 3 * 65536, qtb, ktb, vtb, Q, K, Vt);
  flash9_kernel<<<FLASH_BLKS, 256, 0, stream>>>(Q, K, Vt, O16, 1);

  float* o = tt;      // tt dead after qkv#2
  outconv_mfma_kernel<<<OUT_BLKS, 256, 0, stream>>>(O16, Whall + 6 * 65536, obias, x, o);
  stats_kernel<<<C, 256, 0, stream>>>(o, stats);
  bn_kernel<<<(BB * C * NN / 4) / 256, 256, 0, stream>>>(o, stats, bng, bnb, (float*)d_out);
}

// Round 7
// 1285.475 us; speedup vs baseline: 1.4965x; 1.1215x over previous
//
#include <hip/hip_runtime.h>
#include <hip/hip_fp16.h>

#define BB 8
#define C 256
#define HH 56
#define WW 56
#define NN 3136      // HH*WW
#define RR 16
#define NT (NN/16)   // 196 pixel-tiles per image
#define PW 58        // padded spatial width/height

typedef _Float16 half8 __attribute__((ext_vector_type(8)));
typedef _Float16 half4v __attribute__((ext_vector_type(4)));
typedef float floatx4 __attribute__((ext_vector_type(4)));

#define AS1 __attribute__((address_space(1)))
#define AS3 __attribute__((address_space(3)))

// async 16B global->LDS DMA (no VGPR staging, wave-uniform LDS base + lane*16)
__device__ __forceinline__ void gload16(const _Float16* gsrc, _Float16* ldst) {
  __builtin_amdgcn_global_load_lds((const AS1 unsigned int*)(const void*)gsrc,
                                   (AS3 unsigned int*)(void*)ldst, 16, 0, 0);
}

// ---------------------------------------------------------------------------
// 1. attr branch fused: a = adj( concat( relu(W2 relu(W1 x)), x ) )
//    Transposed fp32 weights (w1T[c][r], wadjT[k][o]) -> coalesced reads.
// ---------------------------------------------------------------------------
__global__ __launch_bounds__(256) void attr_kernel(
    const float* __restrict__ x,
    const float* __restrict__ w1T, const float* __restrict__ b1,
    const float* __restrict__ w2, const float* __restrict__ b2,
    const float* __restrict__ wadjT, const float* __restrict__ badj,
    float* __restrict__ a_out)
{
  __shared__ float xs[C][20];
  __shared__ float a2s[C][20];
  __shared__ float a1s[RR][20];
  const int tile = blockIdx.x;
  const int b = tile / NT;
  const int p0 = (tile % NT) * 16;
  const int t = threadIdx.x;

  {
    const float* xb = x + ((size_t)b * C + t) * NN + p0;
    const float4* xb4 = (const float4*)xb;
    float* row = xs[t];
#pragma unroll
    for (int g = 0; g < 4; ++g) {
      float4 v = xb4[g];
      row[g * 4 + 0] = v.x; row[g * 4 + 1] = v.y;
      row[g * 4 + 2] = v.z; row[g * 4 + 3] = v.w;
    }
  }
  __syncthreads();

  {
    const int r = t & 15, pp = t >> 4;
    float acc = b1[r];
    for (int c = 0; c < C; ++c) acc += w1T[c * 16 + r] * xs[c][pp];
    a1s[r][pp] = fmaxf(acc, 0.f);
  }
  __syncthreads();

  {
    const int o = t;
    float acc[16];
    const float bias = b2[o];
#pragma unroll
    for (int p = 0; p < 16; ++p) acc[p] = bias;
    const float* wr = w2 + o * RR;
    for (int k = 0; k < RR; ++k) {
      const float w = wr[k];
#pragma unroll
      for (int p = 0; p < 16; ++p) acc[p] += w * a1s[k][p];
    }
    float* row = a2s[o];
#pragma unroll
    for (int p = 0; p < 16; ++p) row[p] = fmaxf(acc[p], 0.f);
  }
  __syncthreads();

  {
    const int o = t;
    float acc[16];
    const float bias = badj[o];
#pragma unroll
    for (int p = 0; p < 16; ++p) acc[p] = bias;
    const float* wTa = wadjT + o;            // wadjT[k][o], k in [0,256)
    for (int k = 0; k < C; ++k) {
      const float w = wTa[k * C];
      const float4* ar = (const float4*)a2s[k];
#pragma unroll
      for (int g = 0; g < 4; ++g) {
        float4 v = ar[g];
        acc[g * 4 + 0] += w * v.x; acc[g * 4 + 1] += w * v.y;
        acc[g * 4 + 2] += w * v.z; acc[g * 4 + 3] += w * v.w;
      }
    }
    const float* wTx = wadjT + C * C + o;    // wadjT[256+k][o]
    for (int k = 0; k < C; ++k) {
      const float w = wTx[k * C];
      const float4* xr = (const float4*)xs[k];
#pragma unroll
      for (int g = 0; g < 4; ++g) {
        float4 v = xr[g];
        acc[g * 4 + 0] += w * v.x; acc[g * 4 + 1] += w * v.y;
        acc[g * 4 + 2] += w * v.z; acc[g * 4 + 3] += w * v.w;
      }
    }
    float* op = a_out + ((size_t)b * C + o) * NN + p0;
    float4* op4 = (float4*)op;
#pragma unroll
    for (int g = 0; g < 4; ++g)
      op4[g] = make_float4(acc[g * 4 + 0], acc[g * 4 + 1], acc[g * 4 + 2], acc[g * 4 + 3]);
  }
}

// ---------------------------------------------------------------------------
// 1b. attr weight transposes (fp32)
// ---------------------------------------------------------------------------
__global__ __launch_bounds__(256) void wprep_attr_kernel(
    const float* __restrict__ w1, const float* __restrict__ wadj,
    float* __restrict__ w1T, float* __restrict__ wadjT)
{
  const int i = blockIdx.x * 256 + threadIdx.x;   // 528*256 = 135,168
  if (i < RR * C) {
    const int c = i >> 4, r = i & 15;
    w1T[i] = w1[r * C + c];
  } else {
    const int j = i - RR * C;                     // 2C*C entries
    const int k = j >> 8, o = j & 255;
    wadjT[j] = wadj[(size_t)o * (2 * C) + k];
  }
}

// ---------------------------------------------------------------------------
// 2a. conv weight prep
// ---------------------------------------------------------------------------
__global__ __launch_bounds__(256) void wprep_kernel(
    const float* __restrict__ tw1, const float* __restrict__ tw2,
    _Float16* __restrict__ w1h, _Float16* __restrict__ w2h)
{
  const int i = blockIdx.x * 256 + threadIdx.x;   // over 9*256*256
  const int tap = i >> 16;
  const int rem = i & 65535;
  const int o = rem >> 8;
  const int c = rem & 255;
  w1h[i] = (_Float16)tw1[((size_t)o * C + c) * 9 + tap];
  w2h[i] = (_Float16)tw2[((size_t)o * C + c) * 9 + (8 - tap)];
}

// ---------------------------------------------------------------------------
// 2a'. 1x1 weight prep: 7 C*C fp32 -> fp16 [o][c].  Order: qa,ka,va,qt,kt,vt,ow
// ---------------------------------------------------------------------------
__global__ __launch_bounds__(256) void wprep_qkv_kernel(
    const float* __restrict__ m0, const float* __restrict__ m1,
    const float* __restrict__ m2, const float* __restrict__ m3,
    const float* __restrict__ m4, const float* __restrict__ m5,
    const float* __restrict__ m6, _Float16* __restrict__ Whall)
{
  const int i = blockIdx.x * 256 + threadIdx.x;   // over 7*65536
  const int mat = i >> 16, rem = i & 65535;
  const float* s;
  switch (mat) {
    case 0: s = m0; break; case 1: s = m1; break; case 2: s = m2; break;
    case 3: s = m3; break; case 4: s = m4; break; case 5: s = m5; break;
    default: s = m6; break;
  }
  Whall[i] = (_Float16)s[rem];
}

// ---------------------------------------------------------------------------
// 2b. zero the pad border of both padded-NHWC fp16 buffers
// ---------------------------------------------------------------------------
__global__ __launch_bounds__(256) void padzero_kernel(
    _Float16* __restrict__ buf1, _Float16* __restrict__ buf2)
{
  const int bid = blockIdx.x;                 // 2 * BB * PW
  _Float16* buf = (bid < BB * PW) ? buf1 : buf2;
  const int rb = bid % (BB * PW);
  const int b = rb / PW, r = rb % PW;
  _Float16* row = buf + ((size_t)b * PW + r) * PW * C;
  const float4 z = make_float4(0.f, 0.f, 0.f, 0.f);
  if (r == 0 || r == PW - 1) {
    for (int i = threadIdx.x; i < PW * C / 8; i += 256) ((float4*)row)[i] = z;
  } else {
    const int i = threadIdx.x;
    if (i < 32) ((float4*)row)[i] = z;                       // col 0
    else if (i < 64) ((float4*)(row + (PW - 1) * C))[i - 32] = z;  // col 57
  }
}

// ---------------------------------------------------------------------------
// 2c. hn (fp32 NCHW) -> hnpad (fp16 padded NHWC) interior, via LDS transpose
// ---------------------------------------------------------------------------
__global__ __launch_bounds__(256) void hnprep_kernel(
    const float* __restrict__ hn, _Float16* __restrict__ hnpad)
{
  __shared__ float xs[C][17];
  const int tile = blockIdx.x;
  const int b = tile / NT;
  const int p0 = (tile % NT) * 16;
  const int t = threadIdx.x;
  {
    const float4* sb = (const float4*)(hn + ((size_t)b * C + t) * NN + p0);
    float* row = xs[t];
#pragma unroll
    for (int g = 0; g < 4; ++g) {
      float4 v = sb[g];
      row[g * 4 + 0] = v.x; row[g * 4 + 1] = v.y;
      row[g * 4 + 2] = v.z; row[g * 4 + 3] = v.w;
    }
  }
  __syncthreads();
  const int p = t >> 4, c0 = (t & 15) * 16;
  const int pg = p0 + p;
  const int h = pg / WW, w = pg % WW;
  __align__(16) _Float16 tmp[16];
#pragma unroll
  for (int j = 0; j < 16; ++j) tmp[j] = (_Float16)xs[c0 + j][p];
  _Float16* dst = hnpad + (((size_t)b * PW + h + 1) * PW + w + 1) * C + c0;
  ((uint4*)dst)[0] = ((uint4*)tmp)[0];
  ((uint4*)dst)[1] = ((uint4*)tmp)[1];
}

// ---------------------------------------------------------------------------
// 2d. conv3x3 as 9-tap MFMA GEMM.  XCD-swizzled (b = bid & 7).
// ---------------------------------------------------------------------------
__global__ __launch_bounds__(256) void conv_mfma_kernel(
    const _Float16* __restrict__ inpad, const _Float16* __restrict__ wh,
    const float* __restrict__ bias, const float* __restrict__ amul,
    _Float16* __restrict__ out_h, float* __restrict__ out_f, int mode)
{
  const int bid = blockIdx.x;          // BB*56*2
  const int b = bid & 7;               // XCD-aligned batch
  const int rest = bid >> 3;           // 0..111
  const int ohalf = rest & 1;
  const int h = rest >> 1;
  const int t = threadIdx.x;
  const int wave = t >> 6, lane = t & 63;
  const int col = lane & 15, quad = lane >> 4;
  const int o_base = ohalf * 128 + wave * 32;

  floatx4 acc[2][4];
#pragma unroll
  for (int mt = 0; mt < 2; ++mt)
#pragma unroll
    for (int nt = 0; nt < 4; ++nt) acc[mt][nt] = (floatx4){0.f, 0.f, 0.f, 0.f};

  const _Float16* inb = inpad + (size_t)b * PW * PW * C;

  for (int tap = 0; tap < 9; ++tap) {
    const int dy = tap / 3;
    const int dx = tap - dy * 3;
    const _Float16* wtap = wh + (size_t)tap * C * C + quad * 8;
    const _Float16* inrow = inb + ((size_t)(h + dy) * PW + dx + col) * C + quad * 8;
    for (int kc = 0; kc < 8; ++kc) {
      const int c0 = kc * 32;
      const half8 A0 = *(const half8*)(wtap + (size_t)(o_base + col) * C + c0);
      const half8 A1 = *(const half8*)(wtap + (size_t)(o_base + 16 + col) * C + c0);
#pragma unroll
      for (int nt = 0; nt < 4; ++nt) {
        const half8 Bv = *(const half8*)(inrow + (size_t)(nt * 16) * C + c0);
        acc[0][nt] = __builtin_amdgcn_mfma_f32_16x16x32_f16(A0, Bv, acc[0][nt], 0, 0, 0);
        acc[1][nt] = __builtin_amdgcn_mfma_f32_16x16x32_f16(A1, Bv, acc[1][nt], 0, 0, 0);
      }
    }
  }

#pragma unroll
  for (int mt = 0; mt < 2; ++mt) {
    const int o = o_base + mt * 16 + quad * 4;
    const float* bp = bias + o;
    const float b0 = bp[0], b1_ = bp[1], b2_ = bp[2], b3 = bp[3];
    if (mode == 0) {
#pragma unroll
      for (int nt = 0; nt < 4; ++nt) {
        const int wpx = nt * 16 + col;
        if (wpx < WW) {
          __align__(8) _Float16 hv[4];
          hv[0] = (_Float16)fmaxf(acc[mt][nt][0] + b0, 0.f);
          hv[1] = (_Float16)fmaxf(acc[mt][nt][1] + b1_, 0.f);
          hv[2] = (_Float16)fmaxf(acc[mt][nt][2] + b2_, 0.f);
          hv[3] = (_Float16)fmaxf(acc[mt][nt][3] + b3, 0.f);
          _Float16* dst = out_h + (((size_t)b * PW + h + 1) * PW + wpx + 1) * C + o;
          *(uint2*)dst = *(uint2*)hv;
        }
      }
    } else {
#pragma unroll
      for (int nt = 0; nt < 4; ++nt) {
        const int wpx = nt * 16 + col;
        if (wpx < WW) {
          const int p = h * WW + wpx;
          const float bb[4] = {b0, b1_, b2_, b3};
#pragma unroll
          for (int r = 0; r < 4; ++r) {
            const size_t idx = ((size_t)(b * C + o + r)) * NN + p;
            out_f[idx] = (acc[mt][nt][r] + bb[r]) * amul[idx];
          }
        }
      }
    }
  }
}

// ---------------------------------------------------------------------------
// helper: 16B MFMA fragment from LDS as two ds_read_b64 (8B-aligned layouts)
// ---------------------------------------------------------------------------
__device__ inline half8 ld_frag(const _Float16* p) {
  union { half8 h8; half4v h4[2]; } u;
  u.h4[0] = *(const half4v*)p;
  u.h4[1] = *(const half4v*)(p + 4);
  return u.h8;
}

// ---------------------------------------------------------------------------
// 3. qkv as MFMA GEMM.  A = fp16 weights [s][o][c], B = src tile staged in
//    LDS as fp16 [px][ch], one pass for Q,K,V.
// ---------------------------------------------------------------------------
__global__ __launch_bounds__(256) void qkv_mfma_kernel(
    const float* __restrict__ src, const _Float16* __restrict__ Wh,
    const float* __restrict__ bq, const float* __restrict__ bk,
    const float* __restrict__ bv,
    __half* __restrict__ Q, __half* __restrict__ K, __half* __restrict__ Vt)
{
  __shared__ _Float16 Ss[32][264];     // [px][ch]  16,896 B
  const int bid = blockIdx.x;          // 784
  const int b = bid & 7;
  const int p0 = (bid >> 3) * 32;
  const int t = threadIdx.x;
  const int w = t >> 6, lane = t & 63;
  const int col = lane & 15, quad = lane >> 4;

  // stage src tile: fp32 [C][N] -> fp16 LDS [px][ch] (thread t = channel t)
  {
    const float4* sp = (const float4*)(src + ((size_t)b * C + t) * NN + p0);
    float v[32];
#pragma unroll
    for (int g = 0; g < 8; ++g) {
      const float4 f = sp[g];
      v[g * 4 + 0] = f.x; v[g * 4 + 1] = f.y;
      v[g * 4 + 2] = f.z; v[g * 4 + 3] = f.w;
    }
#pragma unroll
    for (int px = 0; px < 32; ++px) Ss[px][t] = (_Float16)v[px];
  }
  __syncthreads();

  floatx4 acc[12][2];
#pragma unroll
  for (int i = 0; i < 12; ++i)
#pragma unroll
    for (int nt = 0; nt < 2; ++nt) acc[i][nt] = (floatx4){0.f, 0.f, 0.f, 0.f};

  for (int k0 = 0; k0 < 256; k0 += 32) {
    half8 bf[2];
    bf[0] = ld_frag(&Ss[col][k0 + quad * 8]);
    bf[1] = ld_frag(&Ss[16 + col][k0 + quad * 8]);
#pragma unroll
    for (int i = 0; i < 12; ++i) {
      const int mtg = w * 12 + i;      // 0..47: [0,16)=Q, [16,32)=K, [32,48)=V
      const half8 af = *(const half8*)(Wh + (size_t)mtg * 4096 + col * 256 + k0 + quad * 8);
      acc[i][0] = __builtin_amdgcn_mfma_f32_16x16x32_f16(af, bf[0], acc[i][0], 0, 0, 0);
      acc[i][1] = __builtin_amdgcn_mfma_f32_16x16x32_f16(af, bf[1], acc[i][1], 0, 0, 0);
    }
  }

#pragma unroll
  for (int i = 0; i < 12; ++i) {
    const int mtg = w * 12 + i;
    const int s = mtg >> 4;
    const int crow = (mtg & 15) * 16 + quad * 4;    // c_out base of this lane
    const float* bp = (s == 0 ? bq : (s == 1 ? bk : bv)) + crow;
    const float4 b4 = *(const float4*)bp;
    const float bb[4] = {b4.x, b4.y, b4.z, b4.w};
#pragma unroll
    for (int nt = 0; nt < 2; ++nt) {
      const int px = p0 + nt * 16 + col;
      if (s == 2) {
#pragma unroll
        for (int r = 0; r < 4; ++r)
          Vt[((size_t)(b * C) + crow + r) * NN + px] =
              __float2half((acc[i][nt][r] + bb[r]) * 0.5f);
      } else {
        __half* dst = (s == 0 ? Q : K) + ((size_t)(b * NN) + px) * C + crow;
        __align__(8) __half hv[4];
#pragma unroll
        for (int r = 0; r < 4; ++r) hv[r] = __float2half(acc[i][nt][r] + bb[r]);
        *(uint2*)dst = *(uint2*)hv;
      }
    }
  }
}

// ---------------------------------------------------------------------------
// 4. Flash v10: 7 waves x 16 q-rows (QBLK=112) + dbuf DMA staging.
//    R6 post-mortem: flash9 ran at 1 wave/SIMD (150KB LDS -> 1 block/CU of
//    4 waves); per-iter budget MFMA 12% + VALU 21% + LDS ~20% with ~50%
//    exposed latency (shfl/exp chains, P lgkm round-trip, stage drain) that
//    cannot overlap without a second wave per SIMD.  Now: 448 threads =
//    7 waves/CU (~2/SIMD) so VALU/MFMA/LDS/stage overlap across waves
//    (m114); grid 224 (28 x 112 = 3136, no tail); LDS 148KB (dbuf K/V +
//    P[7][16][76]).  T5 setprio around MFMA clusters (wave role diversity
//    now exists).  Same T21 swizzle staging as flash8/9 (proven).
// ---------------------------------------------------------------------------
__global__ __launch_bounds__(448, 2) void flash10_kernel(
    const __half* __restrict__ Qg, const __half* __restrict__ Kg,
    const __half* __restrict__ Vtg, __half* __restrict__ O16, int accumulate)
{
  __shared__ _Float16 Ks[2][64 * 256];   // [buf][key][ch] linear  65,536 B
  __shared__ _Float16 Vs[2][256 * 64];   // [buf][ch][key] linear  65,536 B
  __shared__ _Float16 Pb[7][16][76];     // per-wave P             17,024 B

  const int bid = blockIdx.x;            // 8 * 28 = 224
  const int b = bid & 7;                 // XCD-aligned batch
  const int q0 = (bid >> 3) * 112;       // 28 q-tiles of 112 rows
  const int t = threadIdx.x;             // 0..447
  const int w = t >> 6;                  // wave 0..6
  const int lane = t & 63;
  const int col = lane & 15;
  const int quad = lane >> 4;

  const _Float16* Kb = (const _Float16*)Kg + (size_t)(b * NN) * C;
  const _Float16* Vb = (const _Float16*)Vtg + (size_t)(b * C) * NN;

  // Q fragments for this wave's 16 rows (regs for all 49 iters)
  const _Float16* Qp = (const _Float16*)Qg +
      ((size_t)(b * NN) + q0 + w * 16 + col) * C + quad * 8;
  half8 Qf[8];
#pragma unroll
  for (int s = 0; s < 8; ++s) Qf[s] = *(const half8*)(Qp + s * 32);

  floatx4 Ov[16];
#pragma unroll
  for (int n = 0; n < 16; ++n) Ov[n] = (floatx4){0.f, 0.f, 0.f, 0.f};
  float m[4] = {-1e30f, -1e30f, -1e30f, -1e30f};
  float l[4] = {0.f, 0.f, 0.f, 0.f};

  // ---- DMA stage of one K/V tile into buffer `buf` (T21 swizzle) ----------
  // 2048 16B-chunks per tile; wave-uniform guarded strides of 448 threads.
  auto stage = [&](int buf, int key0) {
#pragma unroll
    for (int i = 0; i < 5; ++i) {
      const int cb = i * 448 + w * 64;
      if (cb < 2048) {
        const int c = cb + lane;
        const int krow = c >> 5, kcir = c & 31;
        gload16(Kb + (size_t)(key0 + krow) * C + ((kcir ^ (krow & 7)) * 8),
                &Ks[buf][(size_t)cb * 8]);
      }
    }
#pragma unroll
    for (int i = 0; i < 5; ++i) {
      const int cb = i * 448 + w * 64;
      if (cb < 2048) {
        const int c = cb + lane;
        const int vch = c >> 3, vcir = c & 7;
        gload16(Vb + (size_t)vch * NN + key0 + ((vcir ^ (vch & 7)) * 8),
                &Vs[buf][(size_t)cb * 8]);
      }
    }
  };

  // prologue: stage tile 0 into buf 0
  stage(0, 0);
  asm volatile("s_waitcnt vmcnt(0)" ::: "memory");
  __syncthreads();

  for (int kb = 0; kb < 49; ++kb) {
    const int cur = kb & 1;
    if (kb + 1 < 49) stage(cur ^ 1, (kb + 1) * 64);   // overlap with compute

    const _Float16* Kc = Ks[cur];
    const _Float16* Vc = Vs[cur];

    // ---- S = Q K^T * scale, 16q x 64k (K from LDS, swizzled read) ---------
    floatx4 Sv[4];
    __builtin_amdgcn_s_setprio(1);
#pragma unroll
    for (int nt = 0; nt < 4; ++nt) {
      floatx4 acc = (floatx4){0.f, 0.f, 0.f, 0.f};
      const int krow = nt * 16 + col;
      const char* kbase = (const char*)Kc + krow * 512;
      const int kx = (krow & 7) << 4;
#pragma unroll
      for (int s = 0; s < 8; ++s) {
        const half8 bf = *(const half8*)(kbase + ((s * 64 + quad * 16) ^ kx));
        acc = __builtin_amdgcn_mfma_f32_16x16x32_f16(Qf[s], bf, acc, 0, 0, 0);
      }
      Sv[nt] = acc * 0.0625f;   // 1/sqrt(256)
    }
    __builtin_amdgcn_s_setprio(0);

    // ---- online softmax ---------------------------------------------------
    float f[4];
    bool grow = false;
#pragma unroll
    for (int r = 0; r < 4; ++r) {
      float v = fmaxf(fmaxf(Sv[0][r], Sv[1][r]), fmaxf(Sv[2][r], Sv[3][r]));
      v = fmaxf(v, __shfl_xor(v, 1));
      v = fmaxf(v, __shfl_xor(v, 2));
      v = fmaxf(v, __shfl_xor(v, 4));
      v = fmaxf(v, __shfl_xor(v, 8));
      const float mn = fmaxf(m[r], v);
      f[r] = __expf(m[r] - mn);
      grow = grow || (v > m[r]);
      m[r] = mn;
    }
    float rowsum[4] = {0.f, 0.f, 0.f, 0.f};
#pragma unroll
    for (int nt = 0; nt < 4; ++nt) {
#pragma unroll
      for (int r = 0; r < 4; ++r) {
        const float p = __expf(Sv[nt][r] - m[r]);
        Sv[nt][r] = p;
        rowsum[r] += p;
      }
    }
#pragma unroll
    for (int r = 0; r < 4; ++r) {
      float s = rowsum[r];
      s += __shfl_xor(s, 1);
      s += __shfl_xor(s, 2);
      s += __shfl_xor(s, 4);
      s += __shfl_xor(s, 8);
      l[r] = l[r] * f[r] + s;
    }

    // ---- P -> per-wave LDS scratch -> A-fragment layout --------------------
#pragma unroll
    for (int nt = 0; nt < 4; ++nt)
#pragma unroll
      for (int r = 0; r < 4; ++r)
        Pb[w][quad * 4 + r][nt * 16 + col] = (_Float16)Sv[nt][r];

    if (__any(grow)) {          // T13: skip rescale when max did not grow
      const floatx4 fv = {f[0], f[1], f[2], f[3]};
#pragma unroll
      for (int n = 0; n < 16; ++n) Ov[n] *= fv;
    }

    const half8 pa0 = ld_frag(&Pb[w][col][quad * 8]);
    const half8 pa1 = ld_frag(&Pb[w][col][32 + quad * 8]);

    // ---- O += P V  (V from LDS, swizzled read) ----------------------------
    __builtin_amdgcn_s_setprio(1);
#pragma unroll
    for (int nt2 = 0; nt2 < 16; ++nt2) {
      const int vrow = nt2 * 16 + col;
      const char* vbase = (const char*)Vc + vrow * 128;
      const int vx = (vrow & 7) << 4;
      const half8 bv0 = *(const half8*)(vbase + ((quad * 16) ^ vx));
      const half8 bv1 = *(const half8*)(vbase + ((64 + quad * 16) ^ vx));
      Ov[nt2] = __builtin_amdgcn_mfma_f32_16x16x32_f16(pa0, bv0, Ov[nt2], 0, 0, 0);
      Ov[nt2] = __builtin_amdgcn_mfma_f32_16x16x32_f16(pa1, bv1, Ov[nt2], 0, 0, 0);
    }
    __builtin_amdgcn_s_setprio(0);

    asm volatile("s_waitcnt vmcnt(0)" ::: "memory");  // next tile landed
    __syncthreads();                                   // visible to all waves
  }

  float inv[4];
#pragma unroll
  for (int r = 0; r < 4; ++r) inv[r] = 1.f / l[r];
#pragma unroll
  for (int nt2 = 0; nt2 < 16; ++nt2) {
#pragma unroll
    for (int r = 0; r < 4; ++r) {
      const float val = Ov[nt2][r] * inv[r];
      __half* dst = O16 + ((size_t)(b * NN) + q0 + w * 16 + quad * 4 + r) * C +
                    nt2 * 16 + col;
      if (accumulate) *dst = __float2half(val + __half2float(*dst));
      else *dst = __float2half(val);
    }
  }
}

// ---------------------------------------------------------------------------
// 5. out 1x1 conv + residual as MFMA GEMM.
// ---------------------------------------------------------------------------
__global__ __launch_bounds__(256) void outconv_mfma_kernel(
    const __half* __restrict__ O16, const _Float16* __restrict__ owh,
    const float* __restrict__ ob, const float* __restrict__ x,
    float* __restrict__ o)
{
  const int bid = blockIdx.x;          // 392
  const int b = bid & 7;
  const int p0 = (bid >> 3) * 64;
  const int t = threadIdx.x;
  const int w = t >> 6, lane = t & 63;
  const int col = lane & 15, quad = lane >> 4;

  floatx4 acc[4][4];
#pragma unroll
  for (int mt = 0; mt < 4; ++mt)
#pragma unroll
    for (int nt = 0; nt < 4; ++nt) acc[mt][nt] = (floatx4){0.f, 0.f, 0.f, 0.f};

  const _Float16* Ob = (const _Float16*)O16 + (size_t)(b * NN) * C;

  for (int k0 = 0; k0 < 256; k0 += 32) {
    half8 bf[4];
#pragma unroll
    for (int nt = 0; nt < 4; ++nt)
      bf[nt] = *(const half8*)(Ob + (size_t)(p0 + nt * 16 + col) * C + k0 + quad * 8);
#pragma unroll
    for (int mt = 0; mt < 4; ++mt) {
      const int crow = w * 64 + mt * 16 + col;
      const half8 af = *(const half8*)(owh + (size_t)crow * 256 + k0 + quad * 8);
#pragma unroll
      for (int nt = 0; nt < 4; ++nt)
        acc[mt][nt] = __builtin_amdgcn_mfma_f32_16x16x32_f16(af, bf[nt], acc[mt][nt], 0, 0, 0);
    }
  }

#pragma unroll
  for (int mt = 0; mt < 4; ++mt) {
    const int c0 = w * 64 + mt * 16 + quad * 4;
    const float4 b4 = *(const float4*)(ob + c0);
    const float bb[4] = {b4.x, b4.y, b4.z, b4.w};
#pragma unroll
    for (int nt = 0; nt < 4; ++nt) {
      const int px = p0 + nt * 16 + col;
#pragma unroll
      for (int r = 0; r < 4; ++r) {
        const size_t idx = ((size_t)(b * C) + c0 + r) * NN + px;
        o[idx] = acc[mt][nt][r] + bb[r] + x[idx];
      }
    }
  }
}

// ---------------------------------------------------------------------------
// 6. BN stats
// ---------------------------------------------------------------------------
__global__ __launch_bounds__(256) void stats_kernel(
    const float* __restrict__ o, float* __restrict__ stats)
{
  const int c = blockIdx.x, t = threadIdx.x;
  float s = 0.f, sq = 0.f;
  for (int b = 0; b < BB; ++b) {
    const float* p = o + ((size_t)b * C + c) * NN;
    for (int idx = t; idx < NN; idx += 256) {
      const float v = p[idx];
      s += v; sq += v * v;
    }
  }
#pragma unroll
  for (int off = 32; off >= 1; off >>= 1) {
    s += __shfl_xor(s, off);
    sq += __shfl_xor(sq, off);
  }
  __shared__ float red[8];
  const int wv = t >> 6;
  if ((t & 63) == 0) { red[wv] = s; red[4 + wv] = sq; }
  __syncthreads();
  if (t == 0) {
    s = red[0] + red[1] + red[2] + red[3];
    sq = red[4] + red[5] + red[6] + red[7];
    stats[c] = s;
    stats[C + c] = sq;
  }
}

// ---------------------------------------------------------------------------
// 7. BN normalize -> d_out
// ---------------------------------------------------------------------------
__global__ __launch_bounds__(256) void bn_kernel(
    const float* __restrict__ o, const float* __restrict__ stats,
    const float* __restrict__ g, const float* __restrict__ bta,
    float* __restrict__ out)
{
  const size_t idx = (size_t)blockIdx.x * 256 + threadIdx.x;
  const float inv_n = 1.f / (float)(BB * NN);
  float4 v = ((const float4*)o)[idx];
  const int c = (int)((idx * 4 / NN) % C);
  const float mean = stats[c] * inv_n;
  const float var = stats[C + c] * inv_n - mean * mean;
  const float sc = rsqrtf(var + 1e-5f) * g[c];
  const float sh = bta[c] - mean * sc;
  v.x = v.x * sc + sh; v.y = v.y * sc + sh;
  v.z = v.z * sc + sh; v.w = v.w * sc + sh;
  ((float4*)out)[idx] = v;
}

// ---------------------------------------------------------------------------
extern "C" void kernel_launch(void* const* d_in, const int* in_sizes, int n_in,
                              void* d_out, int out_size, void* d_ws, size_t ws_size,
                              hipStream_t stream)
{
  const float* x    = (const float*)d_in[0];
  const float* hn   = (const float*)d_in[1];
  const float* w1   = (const float*)d_in[2];  const float* b1   = (const float*)d_in[3];
  const float* w2   = (const float*)d_in[4];  const float* b2   = (const float*)d_in[5];
  const float* wadj = (const float*)d_in[6];  const float* badj = (const float*)d_in[7];
  const float* tw1  = (const float*)d_in[8];  const float* tb1  = (const float*)d_in[9];
  const float* tw2  = (const float*)d_in[10]; const float* tb2  = (const float*)d_in[11];
  const float* qaw  = (const float*)d_in[12]; const float* qab  = (const float*)d_in[13];
  const float* kaw  = (const float*)d_in[14]; const float* kab  = (const float*)d_in[15];
  const float* vaw  = (const float*)d_in[16]; const float* vab  = (const float*)d_in[17];
  const float* qtw  = (const float*)d_in[18]; const float* qtb  = (const float*)d_in[19];
  const float* ktw  = (const float*)d_in[20]; const float* ktb  = (const float*)d_in[21];
  const float* vtw  = (const float*)d_in[22]; const float* vtb  = (const float*)d_in[23];
  const float* ow   = (const float*)d_in[24]; const float* obias= (const float*)d_in[25];
  const float* bng  = (const float*)d_in[26]; const float* bnb  = (const float*)d_in[27];

  char* ws = (char*)d_ws;
  const size_t TENS  = (size_t)BB * C * NN * sizeof(float);        // 25,690,112
  const size_t HTENS = (size_t)BB * NN * C * sizeof(__half);       // 12,845,056
  const size_t PADT  = (size_t)BB * PW * PW * C * sizeof(_Float16) // 13,778,944
                       + 16384;                                    // OOB-read slack
  const size_t WT    = (size_t)9 * C * C * sizeof(_Float16);       // 1,179,648
  float*    a     = (float*)(ws);
  float*    tt    = (float*)(ws + TENS);
  _Float16* hnpad = (_Float16*)(ws + 2 * TENS);
  _Float16* t1pad = (_Float16*)(ws + 2 * TENS + PADT);
  _Float16* w1h   = (_Float16*)(ws + 2 * TENS + 2 * PADT);
  _Float16* w2h   = (_Float16*)(ws + 2 * TENS + 2 * PADT + WT);
  __half*   Q     = (__half*)(ws + 2 * TENS);            // aliases hnpad (dead)
  __half*   K     = (__half*)(ws + 2 * TENS + HTENS);
  __half*   Vt    = (__half*)(ws + 2 * TENS + 2 * HTENS);
  float*    stats = (float*)(ws + 2 * TENS + 3 * HTENS);
  _Float16* Whall = (_Float16*)(ws + 2 * TENS + 3 * HTENS + 4096); // 7*65536 fp16
  float*    w1T   = (float*)(ws + 2 * TENS + 3 * HTENS + 4096 + 7 * 65536 * 2);
  float*    wadjT = w1T + RR * C;                        // 2C*C fp32
  __half*   O16   = (__half*)a;    // a dead after qkv#1 reads it

  const int PIX_TILES = BB * NT;           // 1568
  const int CONV_BLKS = BB * HH * 2;       // 896
  const int FLASH_BLKS = BB * 28;          // 224 (7 waves x 16 q-rows, QBLK=112)
  const int QKV_BLKS = BB * (NN / 32);     // 784
  const int OUT_BLKS = BB * (NN / 64);     // 392

  wprep_kernel<<<9 * C * C / 256, 256, 0, stream>>>(tw1, tw2, w1h, w2h);
  wprep_qkv_kernel<<<7 * C * C / 256, 256, 0, stream>>>(
      qaw, kaw, vaw, qtw, ktw, vtw, ow, Whall);
  wprep_attr_kernel<<<(RR * C + 2 * C * C) / 256, 256, 0, stream>>>(
      w1, wadj, w1T, wadjT);
  padzero_kernel<<<2 * BB * PW, 256, 0, stream>>>(hnpad, t1pad);
  hnprep_kernel<<<PIX_TILES, 256, 0, stream>>>(hn, hnpad);
  attr_kernel<<<PIX_TILES, 256, 0, stream>>>(x, w1T, b1, w2, b2, wadjT, badj, a);
  conv_mfma_kernel<<<CONV_BLKS, 256, 0, stream>>>(hnpad, w1h, tb1, nullptr, t1pad, nullptr, 0);
  conv_mfma_kernel<<<CONV_BLKS, 256, 0, stream>>>(t1pad, w2h, tb2, a, nullptr, tt, 1);

  qkv_mfma_kernel<<<QKV_BLKS, 256, 0, stream>>>(a, Whall, qab, kab, vab, Q, K, Vt);
  flash10_kernel<<<FLASH_BLKS, 448, 0, stream>>>(Q, K, Vt, O16, 0);
  qkv_mfma_kernel<<<QKV_BLKS, 256, 0, stream>>>(tt, Whall + 3 * 65536, qtb, ktb, vtb, Q, K, Vt);
  flash10_kernel<<<FLASH_BLKS, 448, 0, stream>>>(Q, K, Vt, O16, 1);

  float* o = tt;      // tt dead after qkv#2
  outconv_mfma_kernel<<<OUT_BLKS, 256, 0, stream>>>(O16, Whall + 6 * 65536, obias, x, o);
  stats_kernel<<<C, 256, 0, stream>>>(o, stats);
  bn_kernel<<<(BB * C * NN / 4) / 256, 256, 0, stream>>>(o, stats, bng, bnb, (float*)d_out);
}

// Round 8
// 932.875 us; speedup vs baseline: 2.0621x; 1.3780x over previous
//
#include <hip/hip_runtime.h>
#include <hip/hip_fp16.h>

#define BB 8
#define C 256
#define HH 56
#define WW 56
#define NN 3136      // HH*WW
#define RR 16
#define NT (NN/16)   // 196 pixel-tiles per image
#define PW 58        // padded spatial width/height

typedef _Float16 half8 __attribute__((ext_vector_type(8)));
typedef _Float16 half4v __attribute__((ext_vector_type(4)));
typedef float floatx4 __attribute__((ext_vector_type(4)));

#define AS1 __attribute__((address_space(1)))
#define AS3 __attribute__((address_space(3)))

// async 16B global->LDS DMA (no VGPR staging, wave-uniform LDS base + lane*16)
__device__ __forceinline__ void gload16(const _Float16* gsrc, _Float16* ldst) {
  __builtin_amdgcn_global_load_lds((const AS1 unsigned int*)(const void*)gsrc,
                                   (AS3 unsigned int*)(void*)ldst, 16, 0, 0);
}

// ---------------------------------------------------------------------------
// 1. attr branch fused: a = adj( concat( relu(W2 relu(W1 x)), x ) )
//    Transposed fp32 weights (w1T[c][r], wadjT[k][o]) -> coalesced reads.
// ---------------------------------------------------------------------------
__global__ __launch_bounds__(256) void attr_kernel(
    const float* __restrict__ x,
    const float* __restrict__ w1T, const float* __restrict__ b1,
    const float* __restrict__ w2, const float* __restrict__ b2,
    const float* __restrict__ wadjT, const float* __restrict__ badj,
    float* __restrict__ a_out)
{
  __shared__ float xs[C][20];
  __shared__ float a2s[C][20];
  __shared__ float a1s[RR][20];
  const int tile = blockIdx.x;
  const int b = tile / NT;
  const int p0 = (tile % NT) * 16;
  const int t = threadIdx.x;

  {
    const float* xb = x + ((size_t)b * C + t) * NN + p0;
    const float4* xb4 = (const float4*)xb;
    float* row = xs[t];
#pragma unroll
    for (int g = 0; g < 4; ++g) {
      float4 v = xb4[g];
      row[g * 4 + 0] = v.x; row[g * 4 + 1] = v.y;
      row[g * 4 + 2] = v.z; row[g * 4 + 3] = v.w;
    }
  }
  __syncthreads();

  {
    const int r = t & 15, pp = t >> 4;
    float acc = b1[r];
    for (int c = 0; c < C; ++c) acc += w1T[c * 16 + r] * xs[c][pp];
    a1s[r][pp] = fmaxf(acc, 0.f);
  }
  __syncthreads();

  {
    const int o = t;
    float acc[16];
    const float bias = b2[o];
#pragma unroll
    for (int p = 0; p < 16; ++p) acc[p] = bias;
    const float* wr = w2 + o * RR;
    for (int k = 0; k < RR; ++k) {
      const float w = wr[k];
#pragma unroll
      for (int p = 0; p < 16; ++p) acc[p] += w * a1s[k][p];
    }
    float* row = a2s[o];
#pragma unroll
    for (int p = 0; p < 16; ++p) row[p] = fmaxf(acc[p], 0.f);
  }
  __syncthreads();

  {
    const int o = t;
    float acc[16];
    const float bias = badj[o];
#pragma unroll
    for (int p = 0; p < 16; ++p) acc[p] = bias;
    const float* wTa = wadjT + o;            // wadjT[k][o], k in [0,256)
    for (int k = 0; k < C; ++k) {
      const float w = wTa[k * C];
      const float4* ar = (const float4*)a2s[k];
#pragma unroll
      for (int g = 0; g < 4; ++g) {
        float4 v = ar[g];
        acc[g * 4 + 0] += w * v.x; acc[g * 4 + 1] += w * v.y;
        acc[g * 4 + 2] += w * v.z; acc[g * 4 + 3] += w * v.w;
      }
    }
    const float* wTx = wadjT + C * C + o;    // wadjT[256+k][o]
    for (int k = 0; k < C; ++k) {
      const float w = wTx[k * C];
      const float4* xr = (const float4*)xs[k];
#pragma unroll
      for (int g = 0; g < 4; ++g) {
        float4 v = xr[g];
        acc[g * 4 + 0] += w * v.x; acc[g * 4 + 1] += w * v.y;
        acc[g * 4 + 2] += w * v.z; acc[g * 4 + 3] += w * v.w;
      }
    }
    float* op = a_out + ((size_t)b * C + o) * NN + p0;
    float4* op4 = (float4*)op;
#pragma unroll
    for (int g = 0; g < 4; ++g)
      op4[g] = make_float4(acc[g * 4 + 0], acc[g * 4 + 1], acc[g * 4 + 2], acc[g * 4 + 3]);
  }
}

// ---------------------------------------------------------------------------
// 1b. attr weight transposes (fp32)
// ---------------------------------------------------------------------------
__global__ __launch_bounds__(256) void wprep_attr_kernel(
    const float* __restrict__ w1, const float* __restrict__ wadj,
    float* __restrict__ w1T, float* __restrict__ wadjT)
{
  const int i = blockIdx.x * 256 + threadIdx.x;   // 528*256 = 135,168
  if (i < RR * C) {
    const int c = i >> 4, r = i & 15;
    w1T[i] = w1[r * C + c];
  } else {
    const int j = i - RR * C;                     // 2C*C entries
    const int k = j >> 8, o = j & 255;
    wadjT[j] = wadj[(size_t)o * (2 * C) + k];
  }
}

// ---------------------------------------------------------------------------
// 2a. conv weight prep
// ---------------------------------------------------------------------------
__global__ __launch_bounds__(256) void wprep_kernel(
    const float* __restrict__ tw1, const float* __restrict__ tw2,
    _Float16* __restrict__ w1h, _Float16* __restrict__ w2h)
{
  const int i = blockIdx.x * 256 + threadIdx.x;   // over 9*256*256
  const int tap = i >> 16;
  const int rem = i & 65535;
  const int o = rem >> 8;
  const int c = rem & 255;
  w1h[i] = (_Float16)tw1[((size_t)o * C + c) * 9 + tap];
  w2h[i] = (_Float16)tw2[((size_t)o * C + c) * 9 + (8 - tap)];
}

// ---------------------------------------------------------------------------
// 2a'. 1x1 weight prep: 7 C*C fp32 -> fp16 [o][c].  Order: qa,ka,va,qt,kt,vt,ow
// ---------------------------------------------------------------------------
__global__ __launch_bounds__(256) void wprep_qkv_kernel(
    const float* __restrict__ m0, const float* __restrict__ m1,
    const float* __restrict__ m2, const float* __restrict__ m3,
    const float* __restrict__ m4, const float* __restrict__ m5,
    const float* __restrict__ m6, _Float16* __restrict__ Whall)
{
  const int i = blockIdx.x * 256 + threadIdx.x;   // over 7*65536
  const int mat = i >> 16, rem = i & 65535;
  const float* s;
  switch (mat) {
    case 0: s = m0; break; case 1: s = m1; break; case 2: s = m2; break;
    case 3: s = m3; break; case 4: s = m4; break; case 5: s = m5; break;
    default: s = m6; break;
  }
  Whall[i] = (_Float16)s[rem];
}

// ---------------------------------------------------------------------------
// 2b. zero the pad border of both padded-NHWC fp16 buffers
// ---------------------------------------------------------------------------
__global__ __launch_bounds__(256) void padzero_kernel(
    _Float16* __restrict__ buf1, _Float16* __restrict__ buf2)
{
  const int bid = blockIdx.x;                 // 2 * BB * PW
  _Float16* buf = (bid < BB * PW) ? buf1 : buf2;
  const int rb = bid % (BB * PW);
  const int b = rb / PW, r = rb % PW;
  _Float16* row = buf + ((size_t)b * PW + r) * PW * C;
  const float4 z = make_float4(0.f, 0.f, 0.f, 0.f);
  if (r == 0 || r == PW - 1) {
    for (int i = threadIdx.x; i < PW * C / 8; i += 256) ((float4*)row)[i] = z;
  } else {
    const int i = threadIdx.x;
    if (i < 32) ((float4*)row)[i] = z;                       // col 0
    else if (i < 64) ((float4*)(row + (PW - 1) * C))[i - 32] = z;  // col 57
  }
}

// ---------------------------------------------------------------------------
// 2c. hn (fp32 NCHW) -> hnpad (fp16 padded NHWC) interior, via LDS transpose
// ---------------------------------------------------------------------------
__global__ __launch_bounds__(256) void hnprep_kernel(
    const float* __restrict__ hn, _Float16* __restrict__ hnpad)
{
  __shared__ float xs[C][17];
  const int tile = blockIdx.x;
  const int b = tile / NT;
  const int p0 = (tile % NT) * 16;
  const int t = threadIdx.x;
  {
    const float4* sb = (const float4*)(hn + ((size_t)b * C + t) * NN + p0);
    float* row = xs[t];
#pragma unroll
    for (int g = 0; g < 4; ++g) {
      float4 v = sb[g];
      row[g * 4 + 0] = v.x; row[g * 4 + 1] = v.y;
      row[g * 4 + 2] = v.z; row[g * 4 + 3] = v.w;
    }
  }
  __syncthreads();
  const int p = t >> 4, c0 = (t & 15) * 16;
  const int pg = p0 + p;
  const int h = pg / WW, w = pg % WW;
  __align__(16) _Float16 tmp[16];
#pragma unroll
  for (int j = 0; j < 16; ++j) tmp[j] = (_Float16)xs[c0 + j][p];
  _Float16* dst = hnpad + (((size_t)b * PW + h + 1) * PW + w + 1) * C + c0;
  ((uint4*)dst)[0] = ((uint4*)tmp)[0];
  ((uint4*)dst)[1] = ((uint4*)tmp)[1];
}

// ---------------------------------------------------------------------------
// 2d. conv3x3 as 9-tap MFMA GEMM, v2.
//    R7 post-mortem: old conv had LDS=0 -- every wave streamed weights AND
//    input privately from L2 (1.73 MB/block, 4x redundant B loads) -> per-CU
//    L1-miss ceiling (~24 GB/s/CU), 248 us at MfmaUtil 5.3%.
//    Now: block = 8 waves (512 thr) = 256 oc x 112 px (2 output rows);
//    4-row input strip (4x58x256 fp16 = 119 KB) DMA-staged once (T21
//    swizzle), shared by all waves/taps; weights streamed (1.18 MB/block for
//    4x the outputs).  Grid 8b x 28 = 224 XCD-pinned blocks, no px waste.
// ---------------------------------------------------------------------------
__global__ __launch_bounds__(512, 1) void conv_mfma_kernel(
    const _Float16* __restrict__ inpad, const _Float16* __restrict__ wh,
    const float* __restrict__ bias, const float* __restrict__ amul,
    _Float16* __restrict__ out_h, float* __restrict__ out_f, int mode)
{
  __shared__ _Float16 Is[4 * 58 * 256];   // input strip, 118,784 B

  const int bid = blockIdx.x;          // 8 * 28 = 224
  const int b = bid & 7;               // XCD-aligned batch
  const int h0 = (bid >> 3) * 2;       // output rows h0, h0+1
  const int t = threadIdx.x;           // 0..511
  const int w = t >> 6;                // wave 0..7
  const int lane = t & 63;
  const int col = lane & 15, quad = lane >> 4;
  const int q16 = quad * 16;

  const _Float16* inb = inpad + (size_t)b * PW * PW * C;

  // ---- DMA-stage strip rows h0..h0+3 (padded coords), T21 chunk swizzle ---
  // 7424 chunks of 16B; LDS slot (pp, c) holds global chunk (pp, c^(pp&7)).
  {
    const _Float16* strip = inb + (size_t)h0 * PW * C;  // 4 contiguous rows
    for (int i = w; i < 116; i += 8) {
      const int cb = i * 64;
      const int chunk = cb + lane;
      const int pp = chunk >> 5, cc = chunk & 31;
      gload16(strip + ((size_t)pp * 32 + (cc ^ (pp & 7))) * 8,
              Is + (size_t)cb * 8);
    }
  }
  asm volatile("s_waitcnt vmcnt(0)" ::: "memory");
  __syncthreads();

  // per-lane pixel index (within strip) for each of the 7 n-tiles
  int ppb[7];
#pragma unroll
  for (int nt = 0; nt < 7; ++nt) {
    const int opx = nt * 16 + col;              // 0..111
    const int ro = (opx >= 56) ? 1 : 0;
    ppb[nt] = ro * 58 + (opx - ro * 56);
  }

  floatx4 acc[2][7];
#pragma unroll
  for (int mt = 0; mt < 2; ++mt)
#pragma unroll
    for (int nt = 0; nt < 7; ++nt) acc[mt][nt] = (floatx4){0.f, 0.f, 0.f, 0.f};

  for (int tap = 0; tap < 9; ++tap) {
    const int dy = tap / 3, dx = tap - dy * 3;
    const int pd = dy * 58 + dx;
    int bb[7], xx[7];
#pragma unroll
    for (int nt = 0; nt < 7; ++nt) {
      const int pp = ppb[nt] + pd;
      bb[nt] = pp * 512;                        // byte base of pixel row
      xx[nt] = (pp & 7) << 4;                   // swizzle XOR
    }
    const _Float16* wr0 = wh + (size_t)tap * C * C +
                          (size_t)(w * 32 + col) * C + quad * 8;
#pragma unroll
    for (int kc = 0; kc < 8; ++kc) {
      const half8 A0 = *(const half8*)(wr0 + kc * 32);
      const half8 A1 = *(const half8*)(wr0 + 16 * C + kc * 32);
#pragma unroll
      for (int nt = 0; nt < 7; ++nt) {
        const half8 Bv = *(const half8*)((const char*)Is + bb[nt] +
                                         ((kc * 64 + q16) ^ xx[nt]));
        acc[0][nt] = __builtin_amdgcn_mfma_f32_16x16x32_f16(A0, Bv, acc[0][nt], 0, 0, 0);
        acc[1][nt] = __builtin_amdgcn_mfma_f32_16x16x32_f16(A1, Bv, acc[1][nt], 0, 0, 0);
      }
    }
  }

#pragma unroll
  for (int mt = 0; mt < 2; ++mt) {
    const int o = w * 32 + mt * 16 + quad * 4;
    const float* bp = bias + o;
    const float b0 = bp[0], b1_ = bp[1], b2_ = bp[2], b3_ = bp[3];
    if (mode == 0) {
#pragma unroll
      for (int nt = 0; nt < 7; ++nt) {
        const int opx = nt * 16 + col;
        const int ro = (opx >= 56) ? 1 : 0;
        const int wpx = opx - ro * 56;
        __align__(8) _Float16 hv[4];
        hv[0] = (_Float16)fmaxf(acc[mt][nt][0] + b0, 0.f);
        hv[1] = (_Float16)fmaxf(acc[mt][nt][1] + b1_, 0.f);
        hv[2] = (_Float16)fmaxf(acc[mt][nt][2] + b2_, 0.f);
        hv[3] = (_Float16)fmaxf(acc[mt][nt][3] + b3_, 0.f);
        _Float16* dst = out_h +
            (((size_t)b * PW + h0 + ro + 1) * PW + wpx + 1) * C + o;
        *(uint2*)dst = *(uint2*)hv;
      }
    } else {
      const float bbv[4] = {b0, b1_, b2_, b3_};
#pragma unroll
      for (int nt = 0; nt < 7; ++nt) {
        const int opx = nt * 16 + col;
        const int ro = (opx >= 56) ? 1 : 0;
        const int wpx = opx - ro * 56;
        const int p = (h0 + ro) * WW + wpx;
#pragma unroll
        for (int r = 0; r < 4; ++r) {
          const size_t idx = ((size_t)(b * C + o + r)) * NN + p;
          out_f[idx] = (acc[mt][nt][r] + bbv[r]) * amul[idx];
        }
      }
    }
  }
}

// ---------------------------------------------------------------------------
// helper: 16B MFMA fragment from LDS as two ds_read_b64 (8B-aligned layouts)
// ---------------------------------------------------------------------------
__device__ inline half8 ld_frag(const _Float16* p) {
  union { half8 h8; half4v h4[2]; } u;
  u.h4[0] = *(const half4v*)p;
  u.h4[1] = *(const half4v*)(p + 4);
  return u.h8;
}

// ---------------------------------------------------------------------------
// 3. qkv as MFMA GEMM.  A = fp16 weights [s][o][c], B = src tile staged in
//    LDS as fp16 [px][ch], one pass for Q,K,V.
// ---------------------------------------------------------------------------
__global__ __launch_bounds__(256) void qkv_mfma_kernel(
    const float* __restrict__ src, const _Float16* __restrict__ Wh,
    const float* __restrict__ bq, const float* __restrict__ bk,
    const float* __restrict__ bv,
    __half* __restrict__ Q, __half* __restrict__ K, __half* __restrict__ Vt)
{
  __shared__ _Float16 Ss[32][264];     // [px][ch]  16,896 B
  const int bid = blockIdx.x;          // 784
  const int b = bid & 7;
  const int p0 = (bid >> 3) * 32;
  const int t = threadIdx.x;
  const int w = t >> 6, lane = t & 63;
  const int col = lane & 15, quad = lane >> 4;

  // stage src tile: fp32 [C][N] -> fp16 LDS [px][ch] (thread t = channel t)
  {
    const float4* sp = (const float4*)(src + ((size_t)b * C + t) * NN + p0);
    float v[32];
#pragma unroll
    for (int g = 0; g < 8; ++g) {
      const float4 f = sp[g];
      v[g * 4 + 0] = f.x; v[g * 4 + 1] = f.y;
      v[g * 4 + 2] = f.z; v[g * 4 + 3] = f.w;
    }
#pragma unroll
    for (int px = 0; px < 32; ++px) Ss[px][t] = (_Float16)v[px];
  }
  __syncthreads();

  floatx4 acc[12][2];
#pragma unroll
  for (int i = 0; i < 12; ++i)
#pragma unroll
    for (int nt = 0; nt < 2; ++nt) acc[i][nt] = (floatx4){0.f, 0.f, 0.f, 0.f};

  for (int k0 = 0; k0 < 256; k0 += 32) {
    half8 bf[2];
    bf[0] = ld_frag(&Ss[col][k0 + quad * 8]);
    bf[1] = ld_frag(&Ss[16 + col][k0 + quad * 8]);
#pragma unroll
    for (int i = 0; i < 12; ++i) {
      const int mtg = w * 12 + i;      // 0..47: [0,16)=Q, [16,32)=K, [32,48)=V
      const half8 af = *(const half8*)(Wh + (size_t)mtg * 4096 + col * 256 + k0 + quad * 8);
      acc[i][0] = __builtin_amdgcn_mfma_f32_16x16x32_f16(af, bf[0], acc[i][0], 0, 0, 0);
      acc[i][1] = __builtin_amdgcn_mfma_f32_16x16x32_f16(af, bf[1], acc[i][1], 0, 0, 0);
    }
  }

#pragma unroll
  for (int i = 0; i < 12; ++i) {
    const int mtg = w * 12 + i;
    const int s = mtg >> 4;
    const int crow = (mtg & 15) * 16 + quad * 4;    // c_out base of this lane
    const float* bp = (s == 0 ? bq : (s == 1 ? bk : bv)) + crow;
    const float4 b4 = *(const float4*)bp;
    const float bb[4] = {b4.x, b4.y, b4.z, b4.w};
#pragma unroll
    for (int nt = 0; nt < 2; ++nt) {
      const int px = p0 + nt * 16 + col;
      if (s == 2) {
#pragma unroll
        for (int r = 0; r < 4; ++r)
          Vt[((size_t)(b * C) + crow + r) * NN + px] =
              __float2half((acc[i][nt][r] + bb[r]) * 0.5f);
      } else {
        __half* dst = (s == 0 ? Q : K) + ((size_t)(b * NN) + px) * C + crow;
        __align__(8) __half hv[4];
#pragma unroll
        for (int r = 0; r < 4; ++r) hv[r] = __float2half(acc[i][nt][r] + bb[r]);
        *(uint2*)dst = *(uint2*)hv;
      }
    }
  }
}

// ---------------------------------------------------------------------------
// 4. Flash v10: 7 waves x 16 q-rows (QBLK=112) + dbuf DMA staging.
//    (unchanged from R7 -- dropped out of top-5 at 2 waves/SIMD)
// ---------------------------------------------------------------------------
__global__ __launch_bounds__(448, 2) void flash10_kernel(
    const __half* __restrict__ Qg, const __half* __restrict__ Kg,
    const __half* __restrict__ Vtg, __half* __restrict__ O16, int accumulate)
{
  __shared__ _Float16 Ks[2][64 * 256];   // [buf][key][ch] linear  65,536 B
  __shared__ _Float16 Vs[2][256 * 64];   // [buf][ch][key] linear  65,536 B
  __shared__ _Float16 Pb[7][16][76];     // per-wave P             17,024 B

  const int bid = blockIdx.x;            // 8 * 28 = 224
  const int b = bid & 7;                 // XCD-aligned batch
  const int q0 = (bid >> 3) * 112;       // 28 q-tiles of 112 rows
  const int t = threadIdx.x;             // 0..447
  const int w = t >> 6;                  // wave 0..6
  const int lane = t & 63;
  const int col = lane & 15;
  const int quad = lane >> 4;

  const _Float16* Kb = (const _Float16*)Kg + (size_t)(b * NN) * C;
  const _Float16* Vb = (const _Float16*)Vtg + (size_t)(b * C) * NN;

  // Q fragments for this wave's 16 rows (regs for all 49 iters)
  const _Float16* Qp = (const _Float16*)Qg +
      ((size_t)(b * NN) + q0 + w * 16 + col) * C + quad * 8;
  half8 Qf[8];
#pragma unroll
  for (int s = 0; s < 8; ++s) Qf[s] = *(const half8*)(Qp + s * 32);

  floatx4 Ov[16];
#pragma unroll
  for (int n = 0; n < 16; ++n) Ov[n] = (floatx4){0.f, 0.f, 0.f, 0.f};
  float m[4] = {-1e30f, -1e30f, -1e30f, -1e30f};
  float l[4] = {0.f, 0.f, 0.f, 0.f};

  // ---- DMA stage of one K/V tile into buffer `buf` (T21 swizzle) ----------
  auto stage = [&](int buf, int key0) {
#pragma unroll
    for (int i = 0; i < 5; ++i) {
      const int cb = i * 448 + w * 64;
      if (cb < 2048) {
        const int c = cb + lane;
        const int krow = c >> 5, kcir = c & 31;
        gload16(Kb + (size_t)(key0 + krow) * C + ((kcir ^ (krow & 7)) * 8),
                &Ks[buf][(size_t)cb * 8]);
      }
    }
#pragma unroll
    for (int i = 0; i < 5; ++i) {
      const int cb = i * 448 + w * 64;
      if (cb < 2048) {
        const int c = cb + lane;
        const int vch = c >> 3, vcir = c & 7;
        gload16(Vb + (size_t)vch * NN + key0 + ((vcir ^ (vch & 7)) * 8),
                &Vs[buf][(size_t)cb * 8]);
      }
    }
  };

  // prologue: stage tile 0 into buf 0
  stage(0, 0);
  asm volatile("s_waitcnt vmcnt(0)" ::: "memory");
  __syncthreads();

  for (int kb = 0; kb < 49; ++kb) {
    const int cur = kb & 1;
    if (kb + 1 < 49) stage(cur ^ 1, (kb + 1) * 64);   // overlap with compute

    const _Float16* Kc = Ks[cur];
    const _Float16* Vc = Vs[cur];

    // ---- S = Q K^T * scale, 16q x 64k (K from LDS, swizzled read) ---------
    floatx4 Sv[4];
    __builtin_amdgcn_s_setprio(1);
#pragma unroll
    for (int nt = 0; nt < 4; ++nt) {
      floatx4 acc = (floatx4){0.f, 0.f, 0.f, 0.f};
      const int krow = nt * 16 + col;
      const char* kbase = (const char*)Kc + krow * 512;
      const int kx = (krow & 7) << 4;
#pragma unroll
      for (int s = 0; s < 8; ++s) {
        const half8 bf = *(const half8*)(kbase + ((s * 64 + quad * 16) ^ kx));
        acc = __builtin_amdgcn_mfma_f32_16x16x32_f16(Qf[s], bf, acc, 0, 0, 0);
      }
      Sv[nt] = acc * 0.0625f;   // 1/sqrt(256)
    }
    __builtin_amdgcn_s_setprio(0);

    // ---- online softmax ---------------------------------------------------
    float f[4];
    bool grow = false;
#pragma unroll
    for (int r = 0; r < 4; ++r) {
      float v = fmaxf(fmaxf(Sv[0][r], Sv[1][r]), fmaxf(Sv[2][r], Sv[3][r]));
      v = fmaxf(v, __shfl_xor(v, 1));
      v = fmaxf(v, __shfl_xor(v, 2));
      v = fmaxf(v, __shfl_xor(v, 4));
      v = fmaxf(v, __shfl_xor(v, 8));
      const float mn = fmaxf(m[r], v);
      f[r] = __expf(m[r] - mn);
      grow = grow || (v > m[r]);
      m[r] = mn;
    }
    float rowsum[4] = {0.f, 0.f, 0.f, 0.f};
#pragma unroll
    for (int nt = 0; nt < 4; ++nt) {
#pragma unroll
      for (int r = 0; r < 4; ++r) {
        const float p = __expf(Sv[nt][r] - m[r]);
        Sv[nt][r] = p;
        rowsum[r] += p;
      }
    }
#pragma unroll
    for (int r = 0; r < 4; ++r) {
      float s = rowsum[r];
      s += __shfl_xor(s, 1);
      s += __shfl_xor(s, 2);
      s += __shfl_xor(s, 4);
      s += __shfl_xor(s, 8);
      l[r] = l[r] * f[r] + s;
    }

    // ---- P -> per-wave LDS scratch -> A-fragment layout --------------------
#pragma unroll
    for (int nt = 0; nt < 4; ++nt)
#pragma unroll
      for (int r = 0; r < 4; ++r)
        Pb[w][quad * 4 + r][nt * 16 + col] = (_Float16)Sv[nt][r];

    if (__any(grow)) {          // T13: skip rescale when max did not grow
      const floatx4 fv = {f[0], f[1], f[2], f[3]};
#pragma unroll
      for (int n = 0; n < 16; ++n) Ov[n] *= fv;
    }

    const half8 pa0 = ld_frag(&Pb[w][col][quad * 8]);
    const half8 pa1 = ld_frag(&Pb[w][col][32 + quad * 8]);

    // ---- O += P V  (V from LDS, swizzled read) ----------------------------
    __builtin_amdgcn_s_setprio(1);
#pragma unroll
    for (int nt2 = 0; nt2 < 16; ++nt2) {
      const int vrow = nt2 * 16 + col;
      const char* vbase = (const char*)Vc + vrow * 128;
      const int vx = (vrow & 7) << 4;
      const half8 bv0 = *(const half8*)(vbase + ((quad * 16) ^ vx));
      const half8 bv1 = *(const half8*)(vbase + ((64 + quad * 16) ^ vx));
      Ov[nt2] = __builtin_amdgcn_mfma_f32_16x16x32_f16(pa0, bv0, Ov[nt2], 0, 0, 0);
      Ov[nt2] = __builtin_amdgcn_mfma_f32_16x16x32_f16(pa1, bv1, Ov[nt2], 0, 0, 0);
    }
    __builtin_amdgcn_s_setprio(0);

    asm volatile("s_waitcnt vmcnt(0)" ::: "memory");  // next tile landed
    __syncthreads();                                   // visible to all waves
  }

  float inv[4];
#pragma unroll
  for (int r = 0; r < 4; ++r) inv[r] = 1.f / l[r];
#pragma unroll
  for (int nt2 = 0; nt2 < 16; ++nt2) {
#pragma unroll
    for (int r = 0; r < 4; ++r) {
      const float val = Ov[nt2][r] * inv[r];
      __half* dst = O16 + ((size_t)(b * NN) + q0 + w * 16 + quad * 4 + r) * C +
                    nt2 * 16 + col;
      if (accumulate) *dst = __float2half(val + __half2float(*dst));
      else *dst = __float2half(val);
    }
  }
}

// ---------------------------------------------------------------------------
// 5. out 1x1 conv + residual as MFMA GEMM.
// ---------------------------------------------------------------------------
__global__ __launch_bounds__(256) void outconv_mfma_kernel(
    const __half* __restrict__ O16, const _Float16* __restrict__ owh,
    const float* __restrict__ ob, const float* __restrict__ x,
    float* __restrict__ o)
{
  const int bid = blockIdx.x;          // 392
  const int b = bid & 7;
  const int p0 = (bid >> 3) * 64;
  const int t = threadIdx.x;
  const int w = t >> 6, lane = t & 63;
  const int col = lane & 15, quad = lane >> 4;

  floatx4 acc[4][4];
#pragma unroll
  for (int mt = 0; mt < 4; ++mt)
#pragma unroll
    for (int nt = 0; nt < 4; ++nt) acc[mt][nt] = (floatx4){0.f, 0.f, 0.f, 0.f};

  const _Float16* Ob = (const _Float16*)O16 + (size_t)(b * NN) * C;

  for (int k0 = 0; k0 < 256; k0 += 32) {
    half8 bf[4];
#pragma unroll
    for (int nt = 0; nt < 4; ++nt)
      bf[nt] = *(const half8*)(Ob + (size_t)(p0 + nt * 16 + col) * C + k0 + quad * 8);
#pragma unroll
    for (int mt = 0; mt < 4; ++mt) {
      const int crow = w * 64 + mt * 16 + col;
      const half8 af = *(const half8*)(owh + (size_t)crow * 256 + k0 + quad * 8);
#pragma unroll
      for (int nt = 0; nt < 4; ++nt)
        acc[mt][nt] = __builtin_amdgcn_mfma_f32_16x16x32_f16(af, bf[nt], acc[mt][nt], 0, 0, 0);
    }
  }

#pragma unroll
  for (int mt = 0; mt < 4; ++mt) {
    const int c0 = w * 64 + mt * 16 + quad * 4;
    const float4 b4 = *(const float4*)(ob + c0);
    const float bb[4] = {b4.x, b4.y, b4.z, b4.w};
#pragma unroll
    for (int nt = 0; nt < 4; ++nt) {
      const int px = p0 + nt * 16 + col;
#pragma unroll
      for (int r = 0; r < 4; ++r) {
        const size_t idx = ((size_t)(b * C) + c0 + r) * NN + px;
        o[idx] = acc[mt][nt][r] + bb[r] + x[idx];
      }
    }
  }
}

// ---------------------------------------------------------------------------
// 6. BN stats
// ---------------------------------------------------------------------------
__global__ __launch_bounds__(256) void stats_kernel(
    const float* __restrict__ o, float* __restrict__ stats)
{
  const int c = blockIdx.x, t = threadIdx.x;
  float s = 0.f, sq = 0.f;
  for (int b = 0; b < BB; ++b) {
    const float* p = o + ((size_t)b * C + c) * NN;
    for (int idx = t; idx < NN; idx += 256) {
      const float v = p[idx];
      s += v; sq += v * v;
    }
  }
#pragma unroll
  for (int off = 32; off >= 1; off >>= 1) {
    s += __shfl_xor(s, off);
    sq += __shfl_xor(sq, off);
  }
  __shared__ float red[8];
  const int wv = t >> 6;
  if ((t & 63) == 0) { red[wv] = s; red[4 + wv] = sq; }
  __syncthreads();
  if (t == 0) {
    s = red[0] + red[1] + red[2] + red[3];
    sq = red[4] + red[5] + red[6] + red[7];
    stats[c] = s;
    stats[C + c] = sq;
  }
}

// ---------------------------------------------------------------------------
// 7. BN normalize -> d_out
// ---------------------------------------------------------------------------
__global__ __launch_bounds__(256) void bn_kernel(
    const float* __restrict__ o, const float* __restrict__ stats,
    const float* __restrict__ g, const float* __restrict__ bta,
    float* __restrict__ out)
{
  const size_t idx = (size_t)blockIdx.x * 256 + threadIdx.x;
  const float inv_n = 1.f / (float)(BB * NN);
  float4 v = ((const float4*)o)[idx];
  const int c = (int)((idx * 4 / NN) % C);
  const float mean = stats[c] * inv_n;
  const float var = stats[C + c] * inv_n - mean * mean;
  const float sc = rsqrtf(var + 1e-5f) * g[c];
  const float sh = bta[c] - mean * sc;
  v.x = v.x * sc + sh; v.y = v.y * sc + sh;
  v.z = v.z * sc + sh; v.w = v.w * sc + sh;
  ((float4*)out)[idx] = v;
}

// ---------------------------------------------------------------------------
extern "C" void kernel_launch(void* const* d_in, const int* in_sizes, int n_in,
                              void* d_out, int out_size, void* d_ws, size_t ws_size,
                              hipStream_t stream)
{
  const float* x    = (const float*)d_in[0];
  const float* hn   = (const float*)d_in[1];
  const float* w1   = (const float*)d_in[2];  const float* b1   = (const float*)d_in[3];
  const float* w2   = (const float*)d_in[4];  const float* b2   = (const float*)d_in[5];
  const float* wadj = (const float*)d_in[6];  const float* badj = (const float*)d_in[7];
  const float* tw1  = (const float*)d_in[8];  const float* tb1  = (const float*)d_in[9];
  const float* tw2  = (const float*)d_in[10]; const float* tb2  = (const float*)d_in[11];
  const float* qaw  = (const float*)d_in[12]; const float* qab  = (const float*)d_in[13];
  const float* kaw  = (const float*)d_in[14]; const float* kab  = (const float*)d_in[15];
  const float* vaw  = (const float*)d_in[16]; const float* vab  = (const float*)d_in[17];
  const float* qtw  = (const float*)d_in[18]; const float* qtb  = (const float*)d_in[19];
  const float* ktw  = (const float*)d_in[20]; const float* ktb  = (const float*)d_in[21];
  const float* vtw  = (const float*)d_in[22]; const float* vtb  = (const float*)d_in[23];
  const float* ow   = (const float*)d_in[24]; const float* obias= (const float*)d_in[25];
  const float* bng  = (const float*)d_in[26]; const float* bnb  = (const float*)d_in[27];

  char* ws = (char*)d_ws;
  const size_t TENS  = (size_t)BB * C * NN * sizeof(float);        // 25,690,112
  const size_t HTENS = (size_t)BB * NN * C * sizeof(__half);       // 12,845,056
  const size_t PADT  = (size_t)BB * PW * PW * C * sizeof(_Float16) // 13,778,944
                       + 16384;                                    // OOB-read slack
  const size_t WT    = (size_t)9 * C * C * sizeof(_Float16);       // 1,179,648
  float*    a     = (float*)(ws);
  float*    tt    = (float*)(ws + TENS);
  _Float16* hnpad = (_Float16*)(ws + 2 * TENS);
  _Float16* t1pad = (_Float16*)(ws + 2 * TENS + PADT);
  _Float16* w1h   = (_Float16*)(ws + 2 * TENS + 2 * PADT);
  _Float16* w2h   = (_Float16*)(ws + 2 * TENS + 2 * PADT + WT);
  __half*   Q     = (__half*)(ws + 2 * TENS);            // aliases hnpad (dead)
  __half*   K     = (__half*)(ws + 2 * TENS + HTENS);
  __half*   Vt    = (__half*)(ws + 2 * TENS + 2 * HTENS);
  float*    stats = (float*)(ws + 2 * TENS + 3 * HTENS);
  _Float16* Whall = (_Float16*)(ws + 2 * TENS + 3 * HTENS + 4096); // 7*65536 fp16
  float*    w1T   = (float*)(ws + 2 * TENS + 3 * HTENS + 4096 + 7 * 65536 * 2);
  float*    wadjT = w1T + RR * C;                        // 2C*C fp32
  __half*   O16   = (__half*)a;    // a dead after qkv#1 reads it

  const int PIX_TILES = BB * NT;           // 1568
  const int CONV_BLKS = BB * 28;           // 224 (8 waves, 256 oc x 112 px)
  const int FLASH_BLKS = BB * 28;          // 224 (7 waves x 16 q-rows, QBLK=112)
  const int QKV_BLKS = BB * (NN / 32);     // 784
  const int OUT_BLKS = BB * (NN / 64);     // 392

  wprep_kernel<<<9 * C * C / 256, 256, 0, stream>>>(tw1, tw2, w1h, w2h);
  wprep_qkv_kernel<<<7 * C * C / 256, 256, 0, stream>>>(
      qaw, kaw, vaw, qtw, ktw, vtw, ow, Whall);
  wprep_attr_kernel<<<(RR * C + 2 * C * C) / 256, 256, 0, stream>>>(
      w1, wadj, w1T, wadjT);
  padzero_kernel<<<2 * BB * PW, 256, 0, stream>>>(hnpad, t1pad);
  hnprep_kernel<<<PIX_TILES, 256, 0, stream>>>(hn, hnpad);
  attr_kernel<<<PIX_TILES, 256, 0, stream>>>(x, w1T, b1, w2, b2, wadjT, badj, a);
  conv_mfma_kernel<<<CONV_BLKS, 512, 0, stream>>>(hnpad, w1h, tb1, nullptr, t1pad, nullptr, 0);
  conv_mfma_kernel<<<CONV_BLKS, 512, 0, stream>>>(t1pad, w2h, tb2, a, nullptr, tt, 1);

  qkv_mfma_kernel<<<QKV_BLKS, 256, 0, stream>>>(a, Whall, qab, kab, vab, Q, K, Vt);
  flash10_kernel<<<FLASH_BLKS, 448, 0, stream>>>(Q, K, Vt, O16, 0);
  qkv_mfma_kernel<<<QKV_BLKS, 256, 0, stream>>>(tt, Whall + 3 * 65536, qtb, ktb, vtb, Q, K, Vt);
  flash10_kernel<<<FLASH_BLKS, 448, 0, stream>>>(Q, K, Vt, O16, 1);

  float* o = tt;      // tt dead after qkv#2
  outconv_mfma_kernel<<<OUT_BLKS, 256, 0, stream>>>(O16, Whall + 6 * 65536, obias, x, o);
  stats_kernel<<<C, 256, 0, stream>>>(o, stats);
  bn_kernel<<<(BB * C * NN / 4) / 256, 256, 0, stream>>>(o, stats, bng, bnb, (float*)d_out);
}

// Round 9
// 923.665 us; speedup vs baseline: 2.0827x; 1.0100x over previous
//
#include <hip/hip_runtime.h>
#include <hip/hip_fp16.h>

#define BB 8
#define C 256
#define HH 56
#define WW 56
#define NN 3136      // HH*WW
#define RR 16
#define NT (NN/16)   // 196 pixel-tiles per image
#define PW 58        // padded spatial width/height

typedef _Float16 half8 __attribute__((ext_vector_type(8)));
typedef _Float16 half4v __attribute__((ext_vector_type(4)));
typedef float floatx4 __attribute__((ext_vector_type(4)));

#define AS1 __attribute__((address_space(1)))
#define AS3 __attribute__((address_space(3)))

// async 16B global->LDS DMA (no VGPR staging, wave-uniform LDS base + lane*16)
__device__ __forceinline__ void gload16(const _Float16* gsrc, _Float16* ldst) {
  __builtin_amdgcn_global_load_lds((const AS1 unsigned int*)(const void*)gsrc,
                                   (AS3 unsigned int*)(void*)ldst, 16, 0, 0);
}

// ---------------------------------------------------------------------------
// 1. attr branch fused: a = adj( concat( relu(W2 relu(W1 x)), x ) )
//    Transposed fp32 weights (w1T[c][r], wadjT[k][o]) -> coalesced reads.
// ---------------------------------------------------------------------------
__global__ __launch_bounds__(256) void attr_kernel(
    const float* __restrict__ x,
    const float* __restrict__ w1T, const float* __restrict__ b1,
    const float* __restrict__ w2, const float* __restrict__ b2,
    const float* __restrict__ wadjT, const float* __restrict__ badj,
    float* __restrict__ a_out)
{
  __shared__ float xs[C][20];
  __shared__ float a2s[C][20];
  __shared__ float a1s[RR][20];
  const int tile = blockIdx.x;
  const int b = tile / NT;
  const int p0 = (tile % NT) * 16;
  const int t = threadIdx.x;

  {
    const float* xb = x + ((size_t)b * C + t) * NN + p0;
    const float4* xb4 = (const float4*)xb;
    float* row = xs[t];
#pragma unroll
    for (int g = 0; g < 4; ++g) {
      float4 v = xb4[g];
      row[g * 4 + 0] = v.x; row[g * 4 + 1] = v.y;
      row[g * 4 + 2] = v.z; row[g * 4 + 3] = v.w;
    }
  }
  __syncthreads();

  {
    const int r = t & 15, pp = t >> 4;
    float acc = b1[r];
    for (int c = 0; c < C; ++c) acc += w1T[c * 16 + r] * xs[c][pp];
    a1s[r][pp] = fmaxf(acc, 0.f);
  }
  __syncthreads();

  {
    const int o = t;
    float acc[16];
    const float bias = b2[o];
#pragma unroll
    for (int p = 0; p < 16; ++p) acc[p] = bias;
    const float* wr = w2 + o * RR;
    for (int k = 0; k < RR; ++k) {
      const float w = wr[k];
#pragma unroll
      for (int p = 0; p < 16; ++p) acc[p] += w * a1s[k][p];
    }
    float* row = a2s[o];
#pragma unroll
    for (int p = 0; p < 16; ++p) row[p] = fmaxf(acc[p], 0.f);
  }
  __syncthreads();

  {
    const int o = t;
    float acc[16];
    const float bias = badj[o];
#pragma unroll
    for (int p = 0; p < 16; ++p) acc[p] = bias;
    const float* wTa = wadjT + o;            // wadjT[k][o], k in [0,256)
    for (int k = 0; k < C; ++k) {
      const float w = wTa[k * C];
      const float4* ar = (const float4*)a2s[k];
#pragma unroll
      for (int g = 0; g < 4; ++g) {
        float4 v = ar[g];
        acc[g * 4 + 0] += w * v.x; acc[g * 4 + 1] += w * v.y;
        acc[g * 4 + 2] += w * v.z; acc[g * 4 + 3] += w * v.w;
      }
    }
    const float* wTx = wadjT + C * C + o;    // wadjT[256+k][o]
    for (int k = 0; k < C; ++k) {
      const float w = wTx[k * C];
      const float4* xr = (const float4*)xs[k];
#pragma unroll
      for (int g = 0; g < 4; ++g) {
        float4 v = xr[g];
        acc[g * 4 + 0] += w * v.x; acc[g * 4 + 1] += w * v.y;
        acc[g * 4 + 2] += w * v.z; acc[g * 4 + 3] += w * v.w;
      }
    }
    float* op = a_out + ((size_t)b * C + o) * NN + p0;
    float4* op4 = (float4*)op;
#pragma unroll
    for (int g = 0; g < 4; ++g)
      op4[g] = make_float4(acc[g * 4 + 0], acc[g * 4 + 1], acc[g * 4 + 2], acc[g * 4 + 3]);
  }
}

// ---------------------------------------------------------------------------
// 1b. attr weight transposes (fp32)
// ---------------------------------------------------------------------------
__global__ __launch_bounds__(256) void wprep_attr_kernel(
    const float* __restrict__ w1, const float* __restrict__ wadj,
    float* __restrict__ w1T, float* __restrict__ wadjT)
{
  const int i = blockIdx.x * 256 + threadIdx.x;   // 528*256 = 135,168
  if (i < RR * C) {
    const int c = i >> 4, r = i & 15;
    w1T[i] = w1[r * C + c];
  } else {
    const int j = i - RR * C;                     // 2C*C entries
    const int k = j >> 8, o = j & 255;
    wadjT[j] = wadj[(size_t)o * (2 * C) + k];
  }
}

// ---------------------------------------------------------------------------
// 2a. conv weight prep
// ---------------------------------------------------------------------------
__global__ __launch_bounds__(256) void wprep_kernel(
    const float* __restrict__ tw1, const float* __restrict__ tw2,
    _Float16* __restrict__ w1h, _Float16* __restrict__ w2h)
{
  const int i = blockIdx.x * 256 + threadIdx.x;   // over 9*256*256
  const int tap = i >> 16;
  const int rem = i & 65535;
  const int o = rem >> 8;
  const int c = rem & 255;
  w1h[i] = (_Float16)tw1[((size_t)o * C + c) * 9 + tap];
  w2h[i] = (_Float16)tw2[((size_t)o * C + c) * 9 + (8 - tap)];
}

// ---------------------------------------------------------------------------
// 2a'. 1x1 weight prep: 7 C*C fp32 -> fp16 [o][c].  Order: qa,ka,va,qt,kt,vt,ow
// ---------------------------------------------------------------------------
__global__ __launch_bounds__(256) void wprep_qkv_kernel(
    const float* __restrict__ m0, const float* __restrict__ m1,
    const float* __restrict__ m2, const float* __restrict__ m3,
    const float* __restrict__ m4, const float* __restrict__ m5,
    const float* __restrict__ m6, _Float16* __restrict__ Whall)
{
  const int i = blockIdx.x * 256 + threadIdx.x;   // over 7*65536
  const int mat = i >> 16, rem = i & 65535;
  const float* s;
  switch (mat) {
    case 0: s = m0; break; case 1: s = m1; break; case 2: s = m2; break;
    case 3: s = m3; break; case 4: s = m4; break; case 5: s = m5; break;
    default: s = m6; break;
  }
  Whall[i] = (_Float16)s[rem];
}

// ---------------------------------------------------------------------------
// 2b. zero the pad border of both padded-NHWC fp16 buffers
// ---------------------------------------------------------------------------
__global__ __launch_bounds__(256) void padzero_kernel(
    _Float16* __restrict__ buf1, _Float16* __restrict__ buf2)
{
  const int bid = blockIdx.x;                 // 2 * BB * PW
  _Float16* buf = (bid < BB * PW) ? buf1 : buf2;
  const int rb = bid % (BB * PW);
  const int b = rb / PW, r = rb % PW;
  _Float16* row = buf + ((size_t)b * PW + r) * PW * C;
  const float4 z = make_float4(0.f, 0.f, 0.f, 0.f);
  if (r == 0 || r == PW - 1) {
    for (int i = threadIdx.x; i < PW * C / 8; i += 256) ((float4*)row)[i] = z;
  } else {
    const int i = threadIdx.x;
    if (i < 32) ((float4*)row)[i] = z;                       // col 0
    else if (i < 64) ((float4*)(row + (PW - 1) * C))[i - 32] = z;  // col 57
  }
}

// ---------------------------------------------------------------------------
// 2c. hn (fp32 NCHW) -> hnpad (fp16 padded NHWC) interior, via LDS transpose
// ---------------------------------------------------------------------------
__global__ __launch_bounds__(256) void hnprep_kernel(
    const float* __restrict__ hn, _Float16* __restrict__ hnpad)
{
  __shared__ float xs[C][17];
  const int tile = blockIdx.x;
  const int b = tile / NT;
  const int p0 = (tile % NT) * 16;
  const int t = threadIdx.x;
  {
    const float4* sb = (const float4*)(hn + ((size_t)b * C + t) * NN + p0);
    float* row = xs[t];
#pragma unroll
    for (int g = 0; g < 4; ++g) {
      float4 v = sb[g];
      row[g * 4 + 0] = v.x; row[g * 4 + 1] = v.y;
      row[g * 4 + 2] = v.z; row[g * 4 + 3] = v.w;
    }
  }
  __syncthreads();
  const int p = t >> 4, c0 = (t & 15) * 16;
  const int pg = p0 + p;
  const int h = pg / WW, w = pg % WW;
  __align__(16) _Float16 tmp[16];
#pragma unroll
  for (int j = 0; j < 16; ++j) tmp[j] = (_Float16)xs[c0 + j][p];
  _Float16* dst = hnpad + (((size_t)b * PW + h + 1) * PW + w + 1) * C + c0;
  ((uint4*)dst)[0] = ((uint4*)tmp)[0];
  ((uint4*)dst)[1] = ((uint4*)tmp)[1];
}

// ---------------------------------------------------------------------------
// 2d. conv3x3 as 9-tap MFMA GEMM, v2 (R8: 248 -> <199 us each).
//    8 waves (512 thr) = 256 oc x 112 px; 4-row input strip DMA-staged once
//    (T21 swizzle) and shared by all waves/taps; weights streamed from L2.
// ---------------------------------------------------------------------------
__global__ __launch_bounds__(512, 1) void conv_mfma_kernel(
    const _Float16* __restrict__ inpad, const _Float16* __restrict__ wh,
    const float* __restrict__ bias, const float* __restrict__ amul,
    _Float16* __restrict__ out_h, float* __restrict__ out_f, int mode)
{
  __shared__ _Float16 Is[4 * 58 * 256];   // input strip, 118,784 B

  const int bid = blockIdx.x;          // 8 * 28 = 224
  const int b = bid & 7;               // XCD-aligned batch
  const int h0 = (bid >> 3) * 2;       // output rows h0, h0+1
  const int t = threadIdx.x;           // 0..511
  const int w = t >> 6;                // wave 0..7
  const int lane = t & 63;
  const int col = lane & 15, quad = lane >> 4;
  const int q16 = quad * 16;

  const _Float16* inb = inpad + (size_t)b * PW * PW * C;

  // ---- DMA-stage strip rows h0..h0+3 (padded coords), T21 chunk swizzle ---
  {
    const _Float16* strip = inb + (size_t)h0 * PW * C;  // 4 contiguous rows
    for (int i = w; i < 116; i += 8) {
      const int cb = i * 64;
      const int chunk = cb + lane;
      const int pp = chunk >> 5, cc = chunk & 31;
      gload16(strip + ((size_t)pp * 32 + (cc ^ (pp & 7))) * 8,
              Is + (size_t)cb * 8);
    }
  }
  asm volatile("s_waitcnt vmcnt(0)" ::: "memory");
  __syncthreads();

  // per-lane pixel index (within strip) for each of the 7 n-tiles
  int ppb[7];
#pragma unroll
  for (int nt = 0; nt < 7; ++nt) {
    const int opx = nt * 16 + col;              // 0..111
    const int ro = (opx >= 56) ? 1 : 0;
    ppb[nt] = ro * 58 + (opx - ro * 56);
  }

  floatx4 acc[2][7];
#pragma unroll
  for (int mt = 0; mt < 2; ++mt)
#pragma unroll
    for (int nt = 0; nt < 7; ++nt) acc[mt][nt] = (floatx4){0.f, 0.f, 0.f, 0.f};

  for (int tap = 0; tap < 9; ++tap) {
    const int dy = tap / 3, dx = tap - dy * 3;
    const int pd = dy * 58 + dx;
    int bb[7], xx[7];
#pragma unroll
    for (int nt = 0; nt < 7; ++nt) {
      const int pp = ppb[nt] + pd;
      bb[nt] = pp * 512;                        // byte base of pixel row
      xx[nt] = (pp & 7) << 4;                   // swizzle XOR
    }
    const _Float16* wr0 = wh + (size_t)tap * C * C +
                          (size_t)(w * 32 + col) * C + quad * 8;
#pragma unroll
    for (int kc = 0; kc < 8; ++kc) {
      const half8 A0 = *(const half8*)(wr0 + kc * 32);
      const half8 A1 = *(const half8*)(wr0 + 16 * C + kc * 32);
#pragma unroll
      for (int nt = 0; nt < 7; ++nt) {
        const half8 Bv = *(const half8*)((const char*)Is + bb[nt] +
                                         ((kc * 64 + q16) ^ xx[nt]));
        acc[0][nt] = __builtin_amdgcn_mfma_f32_16x16x32_f16(A0, Bv, acc[0][nt], 0, 0, 0);
        acc[1][nt] = __builtin_amdgcn_mfma_f32_16x16x32_f16(A1, Bv, acc[1][nt], 0, 0, 0);
      }
    }
  }

#pragma unroll
  for (int mt = 0; mt < 2; ++mt) {
    const int o = w * 32 + mt * 16 + quad * 4;
    const float* bp = bias + o;
    const float b0 = bp[0], b1_ = bp[1], b2_ = bp[2], b3_ = bp[3];
    if (mode == 0) {
#pragma unroll
      for (int nt = 0; nt < 7; ++nt) {
        const int opx = nt * 16 + col;
        const int ro = (opx >= 56) ? 1 : 0;
        const int wpx = opx - ro * 56;
        __align__(8) _Float16 hv[4];
        hv[0] = (_Float16)fmaxf(acc[mt][nt][0] + b0, 0.f);
        hv[1] = (_Float16)fmaxf(acc[mt][nt][1] + b1_, 0.f);
        hv[2] = (_Float16)fmaxf(acc[mt][nt][2] + b2_, 0.f);
        hv[3] = (_Float16)fmaxf(acc[mt][nt][3] + b3_, 0.f);
        _Float16* dst = out_h +
            (((size_t)b * PW + h0 + ro + 1) * PW + wpx + 1) * C + o;
        *(uint2*)dst = *(uint2*)hv;
      }
    } else {
      const float bbv[4] = {b0, b1_, b2_, b3_};
#pragma unroll
      for (int nt = 0; nt < 7; ++nt) {
        const int opx = nt * 16 + col;
        const int ro = (opx >= 56) ? 1 : 0;
        const int wpx = opx - ro * 56;
        const int p = (h0 + ro) * WW + wpx;
#pragma unroll
        for (int r = 0; r < 4; ++r) {
          const size_t idx = ((size_t)(b * C + o + r)) * NN + p;
          out_f[idx] = (acc[mt][nt][r] + bbv[r]) * amul[idx];
        }
      }
    }
  }
}

// ---------------------------------------------------------------------------
// helper: 16B MFMA fragment from LDS as two ds_read_b64 (8B-aligned layouts)
// ---------------------------------------------------------------------------
__device__ inline half8 ld_frag(const _Float16* p) {
  union { half8 h8; half4v h4[2]; } u;
  u.h4[0] = *(const half4v*)p;
  u.h4[1] = *(const half4v*)(p + 4);
  return u.h8;
}

// ---------------------------------------------------------------------------
// 3. qkv as MFMA GEMM.  A = fp16 weights [s][o][c], B = src tile staged in
//    LDS as fp16 [px][ch], one pass for Q,K,V.
//    R9: Q is pre-scaled by 1/sqrt(C)=0.0625 here (removes 16 v_mul/iter
//    from the flash inner loop); V carries the 0.5 alpha fold as before.
// ---------------------------------------------------------------------------
__global__ __launch_bounds__(256) void qkv_mfma_kernel(
    const float* __restrict__ src, const _Float16* __restrict__ Wh,
    const float* __restrict__ bq, const float* __restrict__ bk,
    const float* __restrict__ bv,
    __half* __restrict__ Q, __half* __restrict__ K, __half* __restrict__ Vt)
{
  __shared__ _Float16 Ss[32][264];     // [px][ch]  16,896 B
  const int bid = blockIdx.x;          // 784
  const int b = bid & 7;
  const int p0 = (bid >> 3) * 32;
  const int t = threadIdx.x;
  const int w = t >> 6, lane = t & 63;
  const int col = lane & 15, quad = lane >> 4;

  // stage src tile: fp32 [C][N] -> fp16 LDS [px][ch] (thread t = channel t)
  {
    const float4* sp = (const float4*)(src + ((size_t)b * C + t) * NN + p0);
    float v[32];
#pragma unroll
    for (int g = 0; g < 8; ++g) {
      const float4 f = sp[g];
      v[g * 4 + 0] = f.x; v[g * 4 + 1] = f.y;
      v[g * 4 + 2] = f.z; v[g * 4 + 3] = f.w;
    }
#pragma unroll
    for (int px = 0; px < 32; ++px) Ss[px][t] = (_Float16)v[px];
  }
  __syncthreads();

  floatx4 acc[12][2];
#pragma unroll
  for (int i = 0; i < 12; ++i)
#pragma unroll
    for (int nt = 0; nt < 2; ++nt) acc[i][nt] = (floatx4){0.f, 0.f, 0.f, 0.f};

  for (int k0 = 0; k0 < 256; k0 += 32) {
    half8 bf[2];
    bf[0] = ld_frag(&Ss[col][k0 + quad * 8]);
    bf[1] = ld_frag(&Ss[16 + col][k0 + quad * 8]);
#pragma unroll
    for (int i = 0; i < 12; ++i) {
      const int mtg = w * 12 + i;      // 0..47: [0,16)=Q, [16,32)=K, [32,48)=V
      const half8 af = *(const half8*)(Wh + (size_t)mtg * 4096 + col * 256 + k0 + quad * 8);
      acc[i][0] = __builtin_amdgcn_mfma_f32_16x16x32_f16(af, bf[0], acc[i][0], 0, 0, 0);
      acc[i][1] = __builtin_amdgcn_mfma_f32_16x16x32_f16(af, bf[1], acc[i][1], 0, 0, 0);
    }
  }

#pragma unroll
  for (int i = 0; i < 12; ++i) {
    const int mtg = w * 12 + i;
    const int s = mtg >> 4;
    const int crow = (mtg & 15) * 16 + quad * 4;    // c_out base of this lane
    const float* bp = (s == 0 ? bq : (s == 1 ? bk : bv)) + crow;
    const float4 b4 = *(const float4*)bp;
    const float bb[4] = {b4.x, b4.y, b4.z, b4.w};
#pragma unroll
    for (int nt = 0; nt < 2; ++nt) {
      const int px = p0 + nt * 16 + col;
      if (s == 2) {
#pragma unroll
        for (int r = 0; r < 4; ++r)
          Vt[((size_t)(b * C) + crow + r) * NN + px] =
              __float2half((acc[i][nt][r] + bb[r]) * 0.5f);
      } else if (s == 0) {
        __half* dst = Q + ((size_t)(b * NN) + px) * C + crow;
        __align__(8) __half hv[4];
#pragma unroll
        for (int r = 0; r < 4; ++r)
          hv[r] = __float2half((acc[i][nt][r] + bb[r]) * 0.0625f);
        *(uint2*)dst = *(uint2*)hv;
      } else {
        __half* dst = K + ((size_t)(b * NN) + px) * C + crow;
        __align__(8) __half hv[4];
#pragma unroll
        for (int r = 0; r < 4; ++r) hv[r] = __float2half(acc[i][nt][r] + bb[r]);
        *(uint2*)dst = *(uint2*)hv;
      }
    }
  }
}

// ---------------------------------------------------------------------------
// 4. Flash v11: flash10 + deferred row-sum + pre-scaled Q.
//    R8 post-mortem: per-iter LDS-pipe budget ~78% (5.4k cyc b128 data reads
//    [structural min at 16 rows/wave] + 1.3k shuffle ops + 0.8k P traffic).
//    The per-iter SUM reduce (16 shfl) is linear -> deferred: per-lane
//    partial lp[r] = lp[r]*f + local_rowsum (f is uniform across the 16
//    col-lanes since m is reduced), one cross-lane reduce after the k-loop.
//    S-scale folded into Q at qkv (16 v_mul/iter removed).
// ---------------------------------------------------------------------------
__global__ __launch_bounds__(448, 2) void flash11_kernel(
    const __half* __restrict__ Qg, const __half* __restrict__ Kg,
    const __half* __restrict__ Vtg, __half* __restrict__ O16, int accumulate)
{
  __shared__ _Float16 Ks[2][64 * 256];   // [buf][key][ch] linear  65,536 B
  __shared__ _Float16 Vs[2][256 * 64];   // [buf][ch][key] linear  65,536 B
  __shared__ _Float16 Pb[7][16][76];     // per-wave P             17,024 B

  const int bid = blockIdx.x;            // 8 * 28 = 224
  const int b = bid & 7;                 // XCD-aligned batch
  const int q0 = (bid >> 3) * 112;       // 28 q-tiles of 112 rows
  const int t = threadIdx.x;             // 0..447
  const int w = t >> 6;                  // wave 0..6
  const int lane = t & 63;
  const int col = lane & 15;
  const int quad = lane >> 4;

  const _Float16* Kb = (const _Float16*)Kg + (size_t)(b * NN) * C;
  const _Float16* Vb = (const _Float16*)Vtg + (size_t)(b * C) * NN;

  // Q fragments for this wave's 16 rows (regs for all 49 iters)
  const _Float16* Qp = (const _Float16*)Qg +
      ((size_t)(b * NN) + q0 + w * 16 + col) * C + quad * 8;
  half8 Qf[8];
#pragma unroll
  for (int s = 0; s < 8; ++s) Qf[s] = *(const half8*)(Qp + s * 32);

  floatx4 Ov[16];
#pragma unroll
  for (int n = 0; n < 16; ++n) Ov[n] = (floatx4){0.f, 0.f, 0.f, 0.f};
  float m[4] = {-1e30f, -1e30f, -1e30f, -1e30f};
  float lp[4] = {0.f, 0.f, 0.f, 0.f};    // per-lane partial row-sum

  // ---- DMA stage of one K/V tile into buffer `buf` (T21 swizzle) ----------
  auto stage = [&](int buf, int key0) {
#pragma unroll
    for (int i = 0; i < 5; ++i) {
      const int cb = i * 448 + w * 64;
      if (cb < 2048) {
        const int c = cb + lane;
        const int krow = c >> 5, kcir = c & 31;
        gload16(Kb + (size_t)(key0 + krow) * C + ((kcir ^ (krow & 7)) * 8),
                &Ks[buf][(size_t)cb * 8]);
      }
    }
#pragma unroll
    for (int i = 0; i < 5; ++i) {
      const int cb = i * 448 + w * 64;
      if (cb < 2048) {
        const int c = cb + lane;
        const int vch = c >> 3, vcir = c & 7;
        gload16(Vb + (size_t)vch * NN + key0 + ((vcir ^ (vch & 7)) * 8),
                &Vs[buf][(size_t)cb * 8]);
      }
    }
  };

  // prologue: stage tile 0 into buf 0
  stage(0, 0);
  asm volatile("s_waitcnt vmcnt(0)" ::: "memory");
  __syncthreads();

  for (int kb = 0; kb < 49; ++kb) {
    const int cur = kb & 1;
    if (kb + 1 < 49) stage(cur ^ 1, (kb + 1) * 64);   // overlap with compute

    const _Float16* Kc = Ks[cur];
    const _Float16* Vc = Vs[cur];

    // ---- S = (Q/16) K^T, 16q x 64k (K from LDS, swizzled read) ------------
    floatx4 Sv[4];
    __builtin_amdgcn_s_setprio(1);
#pragma unroll
    for (int nt = 0; nt < 4; ++nt) {
      floatx4 acc = (floatx4){0.f, 0.f, 0.f, 0.f};
      const int krow = nt * 16 + col;
      const char* kbase = (const char*)Kc + krow * 512;
      const int kx = (krow & 7) << 4;
#pragma unroll
      for (int s = 0; s < 8; ++s) {
        const half8 bf = *(const half8*)(kbase + ((s * 64 + quad * 16) ^ kx));
        acc = __builtin_amdgcn_mfma_f32_16x16x32_f16(Qf[s], bf, acc, 0, 0, 0);
      }
      Sv[nt] = acc;                      // scale pre-folded into Q
    }
    __builtin_amdgcn_s_setprio(0);

    // ---- online softmax (max reduce only; sum deferred) -------------------
    float f[4];
    bool grow = false;
#pragma unroll
    for (int r = 0; r < 4; ++r) {
      float v = fmaxf(fmaxf(Sv[0][r], Sv[1][r]), fmaxf(Sv[2][r], Sv[3][r]));
      v = fmaxf(v, __shfl_xor(v, 1));
      v = fmaxf(v, __shfl_xor(v, 2));
      v = fmaxf(v, __shfl_xor(v, 4));
      v = fmaxf(v, __shfl_xor(v, 8));
      const float mn = fmaxf(m[r], v);
      f[r] = __expf(m[r] - mn);
      grow = grow || (v > m[r]);
      m[r] = mn;
    }
#pragma unroll
    for (int r = 0; r < 4; ++r) {
      float rs = 0.f;
#pragma unroll
      for (int nt = 0; nt < 4; ++nt) {
        const float p = __expf(Sv[nt][r] - m[r]);
        Sv[nt][r] = p;
        rs += p;
      }
      lp[r] = lp[r] * f[r] + rs;         // per-lane partial (f wave-uniform)
    }

    // ---- P -> per-wave LDS scratch -> A-fragment layout --------------------
#pragma unroll
    for (int nt = 0; nt < 4; ++nt)
#pragma unroll
      for (int r = 0; r < 4; ++r)
        Pb[w][quad * 4 + r][nt * 16 + col] = (_Float16)Sv[nt][r];

    if (__any(grow)) {          // T13: skip rescale when max did not grow
      const floatx4 fv = {f[0], f[1], f[2], f[3]};
#pragma unroll
      for (int n = 0; n < 16; ++n) Ov[n] *= fv;
    }

    const half8 pa0 = ld_frag(&Pb[w][col][quad * 8]);
    const half8 pa1 = ld_frag(&Pb[w][col][32 + quad * 8]);

    // ---- O += P V  (V from LDS, swizzled read) ----------------------------
    __builtin_amdgcn_s_setprio(1);
#pragma unroll
    for (int nt2 = 0; nt2 < 16; ++nt2) {
      const int vrow = nt2 * 16 + col;
      const char* vbase = (const char*)Vc + vrow * 128;
      const int vx = (vrow & 7) << 4;
      const half8 bv0 = *(const half8*)(vbase + ((quad * 16) ^ vx));
      const half8 bv1 = *(const half8*)(vbase + ((64 + quad * 16) ^ vx));
      Ov[nt2] = __builtin_amdgcn_mfma_f32_16x16x32_f16(pa0, bv0, Ov[nt2], 0, 0, 0);
      Ov[nt2] = __builtin_amdgcn_mfma_f32_16x16x32_f16(pa1, bv1, Ov[nt2], 0, 0, 0);
    }
    __builtin_amdgcn_s_setprio(0);

    asm volatile("s_waitcnt vmcnt(0)" ::: "memory");  // next tile landed
    __syncthreads();                                   // visible to all waves
  }

  // ---- final cross-lane sum reduce (once, was per-iter) -------------------
  float inv[4];
#pragma unroll
  for (int r = 0; r < 4; ++r) {
    float s = lp[r];
    s += __shfl_xor(s, 1);
    s += __shfl_xor(s, 2);
    s += __shfl_xor(s, 4);
    s += __shfl_xor(s, 8);
    inv[r] = 1.f / s;
  }
#pragma unroll
  for (int nt2 = 0; nt2 < 16; ++nt2) {
#pragma unroll
    for (int r = 0; r < 4; ++r) {
      const float val = Ov[nt2][r] * inv[r];
      __half* dst = O16 + ((size_t)(b * NN) + q0 + w * 16 + quad * 4 + r) * C +
                    nt2 * 16 + col;
      if (accumulate) *dst = __float2half(val + __half2float(*dst));
      else *dst = __float2half(val);
    }
  }
}

// ---------------------------------------------------------------------------
// 5. out 1x1 conv + residual as MFMA GEMM.
// ---------------------------------------------------------------------------
__global__ __launch_bounds__(256) void outconv_mfma_kernel(
    const __half* __restrict__ O16, const _Float16* __restrict__ owh,
    const float* __restrict__ ob, const float* __restrict__ x,
    float* __restrict__ o)
{
  const int bid = blockIdx.x;          // 392
  const int b = bid & 7;
  const int p0 = (bid >> 3) * 64;
  const int t = threadIdx.x;
  const int w = t >> 6, lane = t & 63;
  const int col = lane & 15, quad = lane >> 4;

  floatx4 acc[4][4];
#pragma unroll
  for (int mt = 0; mt < 4; ++mt)
#pragma unroll
    for (int nt = 0; nt < 4; ++nt) acc[mt][nt] = (floatx4){0.f, 0.f, 0.f, 0.f};

  const _Float16* Ob = (const _Float16*)O16 + (size_t)(b * NN) * C;

  for (int k0 = 0; k0 < 256; k0 += 32) {
    half8 bf[4];
#pragma unroll
    for (int nt = 0; nt < 4; ++nt)
      bf[nt] = *(const half8*)(Ob + (size_t)(p0 + nt * 16 + col) * C + k0 + quad * 8);
#pragma unroll
    for (int mt = 0; mt < 4; ++mt) {
      const int crow = w * 64 + mt * 16 + col;
      const half8 af = *(const half8*)(owh + (size_t)crow * 256 + k0 + quad * 8);
#pragma unroll
      for (int nt = 0; nt < 4; ++nt)
        acc[mt][nt] = __builtin_amdgcn_mfma_f32_16x16x32_f16(af, bf[nt], acc[mt][nt], 0, 0, 0);
    }
  }

#pragma unroll
  for (int mt = 0; mt < 4; ++mt) {
    const int c0 = w * 64 + mt * 16 + quad * 4;
    const float4 b4 = *(const float4*)(ob + c0);
    const float bb[4] = {b4.x, b4.y, b4.z, b4.w};
#pragma unroll
    for (int nt = 0; nt < 4; ++nt) {
      const int px = p0 + nt * 16 + col;
#pragma unroll
      for (int r = 0; r < 4; ++r) {
        const size_t idx = ((size_t)(b * C) + c0 + r) * NN + px;
        o[idx] = acc[mt][nt][r] + bb[r] + x[idx];
      }
    }
  }
}

// ---------------------------------------------------------------------------
// 6. BN stats
// ---------------------------------------------------------------------------
__global__ __launch_bounds__(256) void stats_kernel(
    const float* __restrict__ o, float* __restrict__ stats)
{
  const int c = blockIdx.x, t = threadIdx.x;
  float s = 0.f, sq = 0.f;
  for (int b = 0; b < BB; ++b) {
    const float* p = o + ((size_t)b * C + c) * NN;
    for (int idx = t; idx < NN; idx += 256) {
      const float v = p[idx];
      s += v; sq += v * v;
    }
  }
#pragma unroll
  for (int off = 32; off >= 1; off >>= 1) {
    s += __shfl_xor(s, off);
    sq += __shfl_xor(sq, off);
  }
  __shared__ float red[8];
  const int wv = t >> 6;
  if ((t & 63) == 0) { red[wv] = s; red[4 + wv] = sq; }
  __syncthreads();
  if (t == 0) {
    s = red[0] + red[1] + red[2] + red[3];
    sq = red[4] + red[5] + red[6] + red[7];
    stats[c] = s;
    stats[C + c] = sq;
  }
}

// ---------------------------------------------------------------------------
// 7. BN normalize -> d_out
// ---------------------------------------------------------------------------
__global__ __launch_bounds__(256) void bn_kernel(
    const float* __restrict__ o, const float* __restrict__ stats,
    const float* __restrict__ g, const float* __restrict__ bta,
    float* __restrict__ out)
{
  const size_t idx = (size_t)blockIdx.x * 256 + threadIdx.x;
  const float inv_n = 1.f / (float)(BB * NN);
  float4 v = ((const float4*)o)[idx];
  const int c = (int)((idx * 4 / NN) % C);
  const float mean = stats[c] * inv_n;
  const float var = stats[C + c] * inv_n - mean * mean;
  const float sc = rsqrtf(var + 1e-5f) * g[c];
  const float sh = bta[c] - mean * sc;
  v.x = v.x * sc + sh; v.y = v.y * sc + sh;
  v.z = v.z * sc + sh; v.w = v.w * sc + sh;
  ((float4*)out)[idx] = v;
}

// ---------------------------------------------------------------------------
extern "C" void kernel_launch(void* const* d_in, const int* in_sizes, int n_in,
                              void* d_out, int out_size, void* d_ws, size_t ws_size,
                              hipStream_t stream)
{
  const float* x    = (const float*)d_in[0];
  const float* hn   = (const float*)d_in[1];
  const float* w1   = (const float*)d_in[2];  const float* b1   = (const float*)d_in[3];
  const float* w2   = (const float*)d_in[4];  const float* b2   = (const float*)d_in[5];
  const float* wadj = (const float*)d_in[6];  const float* badj = (const float*)d_in[7];
  const float* tw1  = (const float*)d_in[8];  const float* tb1  = (const float*)d_in[9];
  const float* tw2  = (const float*)d_in[10]; const float* tb2  = (const float*)d_in[11];
  const float* qaw  = (const float*)d_in[12]; const float* qab  = (const float*)d_in[13];
  const float* kaw  = (const float*)d_in[14]; const float* kab  = (const float*)d_in[15];
  const float* vaw  = (const float*)d_in[16]; const float* vab  = (const float*)d_in[17];
  const float* qtw  = (const float*)d_in[18]; const float* qtb  = (const float*)d_in[19];
  const float* ktw  = (const float*)d_in[20]; const float* ktb  = (const float*)d_in[21];
  const float* vtw  = (const float*)d_in[22]; const float* vtb  = (const float*)d_in[23];
  const float* ow   = (const float*)d_in[24]; const float* obias= (const float*)d_in[25];
  const float* bng  = (const float*)d_in[26]; const float* bnb  = (const float*)d_in[27];

  char* ws = (char*)d_ws;
  const size_t TENS  = (size_t)BB * C * NN * sizeof(float);        // 25,690,112
  const size_t HTENS = (size_t)BB * NN * C * sizeof(__half);       // 12,845,056
  const size_t PADT  = (size_t)BB * PW * PW * C * sizeof(_Float16) // 13,778,944
                       + 16384;                                    // OOB-read slack
  const size_t WT    = (size_t)9 * C * C * sizeof(_Float16);       // 1,179,648
  float*    a     = (float*)(ws);
  float*    tt    = (float*)(ws + TENS);
  _Float16* hnpad = (_Float16*)(ws + 2 * TENS);
  _Float16* t1pad = (_Float16*)(ws + 2 * TENS + PADT);
  _Float16* w1h   = (_Float16*)(ws + 2 * TENS + 2 * PADT);
  _Float16* w2h   = (_Float16*)(ws + 2 * TENS + 2 * PADT + WT);
  __half*   Q     = (__half*)(ws + 2 * TENS);            // aliases hnpad (dead)
  __half*   K     = (__half*)(ws + 2 * TENS + HTENS);
  __half*   Vt    = (__half*)(ws + 2 * TENS + 2 * HTENS);
  float*    stats = (float*)(ws + 2 * TENS + 3 * HTENS);
  _Float16* Whall = (_Float16*)(ws + 2 * TENS + 3 * HTENS + 4096); // 7*65536 fp16
  float*    w1T   = (float*)(ws + 2 * TENS + 3 * HTENS + 4096 + 7 * 65536 * 2);
  float*    wadjT = w1T + RR * C;                        // 2C*C fp32
  __half*   O16   = (__half*)a;    // a dead after qkv#1 reads it

  const int PIX_TILES = BB * NT;           // 1568
  const int CONV_BLKS = BB * 28;           // 224 (8 waves, 256 oc x 112 px)
  const int FLASH_BLKS = BB * 28;          // 224 (7 waves x 16 q-rows, QBLK=112)
  const int QKV_BLKS = BB * (NN / 32);     // 784
  const int OUT_BLKS = BB * (NN / 64);     // 392

  wprep_kernel<<<9 * C * C / 256, 256, 0, stream>>>(tw1, tw2, w1h, w2h);
  wprep_qkv_kernel<<<7 * C * C / 256, 256, 0, stream>>>(
      qaw, kaw, vaw, qtw, ktw, vtw, ow, Whall);
  wprep_attr_kernel<<<(RR * C + 2 * C * C) / 256, 256, 0, stream>>>(
      w1, wadj, w1T, wadjT);
  padzero_kernel<<<2 * BB * PW, 256, 0, stream>>>(hnpad, t1pad);
  hnprep_kernel<<<PIX_TILES, 256, 0, stream>>>(hn, hnpad);
  attr_kernel<<<PIX_TILES, 256, 0, stream>>>(x, w1T, b1, w2, b2, wadjT, badj, a);
  conv_mfma_kernel<<<CONV_BLKS, 512, 0, stream>>>(hnpad, w1h, tb1, nullptr, t1pad, nullptr, 0);
  conv_mfma_kernel<<<CONV_BLKS, 512, 0, stream>>>(t1pad, w2h, tb2, a, nullptr, tt, 1);

  qkv_mfma_kernel<<<QKV_BLKS, 256, 0, stream>>>(a, Whall, qab, kab, vab, Q, K, Vt);
  flash11_kernel<<<FLASH_BLKS, 448, 0, stream>>>(Q, K, Vt, O16, 0);
  qkv_mfma_kernel<<<QKV_BLKS, 256, 0, stream>>>(tt, Whall + 3 * 65536, qtb, ktb, vtb, Q, K, Vt);
  flash11_kernel<<<FLASH_BLKS, 448, 0, stream>>>(Q, K, Vt, O16, 1);

  float* o = tt;      // tt dead after qkv#2
  outconv_mfma_kernel<<<OUT_BLKS, 256, 0, stream>>>(O16, Whall + 6 * 65536, obias, x, o);
  stats_kernel<<<C, 256, 0, stream>>>(o, stats);
  bn_kernel<<<(BB * C * NN / 4) / 256, 256, 0, stream>>>(o, stats, bng, bnb, (float*)d_out);
}